// Round 11
// baseline (351.389 us; speedup 1.0000x reference)
//
#include <hip/hip_runtime.h>
#include <hip/hip_bf16.h>

typedef __attribute__((ext_vector_type(8))) short bf16x8;
typedef __attribute__((ext_vector_type(4))) float f32x4;

#define Hdim 256
#define NM 32      // N2 modes
#define NB 16      // batch
#define LL 4096    // seq len
#define PCH 256    // chunk length
#define NCH 16     // chunks = LL/PCH
#define KBIG 384   // conv GEMM K: 256 u + 64 zf + 64 zb

// ---- workspace layout (bytes), total 186,122,240 ----
#define OFF_ABIG ((size_t)0)
#define OFF_WPM  ((size_t)50331648)
#define OFF_UT   ((size_t)67108864)    // U_T bf16 [B][H][L] 33554432
#define OFF_ZG   ((size_t)100663296)   // Zg fp32 [h][bc][128] ; then Yt bf16
#define OFF_M    ((size_t)67108864)    // M bf16 (spans UT+ZG, alive gemm2->gemm3)
#define OFF_ZP   ((size_t)134217728)   // Zpacked bf16 [h][bc][128]
#define OFF_G    ((size_t)150994944)   // G bf16 (b,l,h) ; reused as T2
#define OFF_WTAB ((size_t)185073664)
#define OFF_WPT  ((size_t)185139200)
#define OFF_CE   ((size_t)185204736)
#define OFF_W1T  ((size_t)185335808)
#define OFF_W2T  ((size_t)185597952)
#define OFF_W3T  ((size_t)185860096)

typedef const __attribute__((address_space(1))) void* gas_p;
typedef __attribute__((address_space(3))) void* las_p;

__device__ __forceinline__ float gelu_f(float v) {
    return 0.5f * v * (1.0f + erff(v * 0.70710678118654752f));
}
__device__ __forceinline__ unsigned short f2bf(float f) {  // RNE f32->bf16
    unsigned int u = __float_as_uint(f);
    u += 0x7fffu + ((u >> 16) & 1u);
    return (unsigned short)(u >> 16);
}

// swizzled fragment read from a [R][64] tile: XOR 16B-block index with (row&7).
__device__ __forceinline__ bf16x8 fr(const unsigned short* lds, int row, int kcol) {
    return *(const bf16x8*)(lds + row * 64 + ((((kcol >> 3) ^ (row & 7)) << 3)));
}

// stage ROWS x 64 bf16 tile (row-major, ld elems) into LDS [ROWS][64] (linear dest,
// inverse-swizzled source: LDS block b of row r holds global k-block b^(r&7))
template<int ROWS, int THREADS>
__device__ __forceinline__ void stage64(const unsigned short* __restrict__ src, int ld, int k0,
                                        unsigned short* lds, int t) {
    constexpr int EPI = THREADS * 8;   // elems per iter
#pragma unroll
    for (int i = 0; i < (ROWS * 64) / EPI; i++) {
        int e = i * EPI + t * 8;
        int r = e >> 6;
        int k = (((e >> 3) & 7) ^ (r & 7)) << 3;
        const unsigned short* g = src + (size_t)r * ld + (k0 + k);
        unsigned short* l = lds + i * EPI + (t >> 6) * 512;   // wave-uniform base
        __builtin_amdgcn_global_load_lds((gas_p)g, (las_p)l, 16, 0, 0);
    }
}

// stage ROWS x 64 tile of UT (bc-rows) for head h, same swizzle
template<int ROWS, int THREADS>
__device__ __forceinline__ void stageUT(const unsigned short* __restrict__ UT, int h, int rbase,
                                        int k0, unsigned short* lds, int t) {
    constexpr int EPI = THREADS * 8;
#pragma unroll
    for (int i = 0; i < (ROWS * 64) / EPI; i++) {
        int e = i * EPI + t * 8;
        int r = e >> 6;
        int k = (((e >> 3) & 7) ^ (r & 7)) << 3;
        int row = rbase + r;
        const unsigned short* g = UT + ((size_t)((row >> 4) * Hdim + h)) * LL
                                  + (row & 15) * PCH + (k0 + k);
        unsigned short* l = lds + i * EPI + (t >> 6) * 512;
        __builtin_amdgcn_global_load_lds((gas_p)g, (las_p)l, 16, 0, 0);
    }
}

// ---------------- tables ----------------
__global__ void k_tab(const float* __restrict__ logdt, const float* __restrict__ Are,
                      const float* __restrict__ Aim, const float* __restrict__ Cre,
                      const float* __restrict__ Cim, float2* __restrict__ wtab,
                      float2* __restrict__ wptab, float2* __restrict__ ceff) {
    int idx = blockIdx.x * blockDim.x + threadIdx.x;
    if (idx >= Hdim * NM) return;
    int h = idx >> 5;
    float dt = expf(logdt[h]);
    double dar = (double)dt * (double)Are[idx];
    double dai = (double)dt * (double)Aim[idx];
    double wm = exp(dar);
    double wr = wm * cos(dai), wi = wm * sin(dai);
    wtab[idx] = make_float2((float)wr, (float)wi);
    double pm = exp(dar * (double)PCH);
    double pai = dai * (double)PCH;
    wptab[idx] = make_float2((float)(pm * cos(pai)), (float)(pm * sin(pai)));
    double are = (double)Are[idx], aim = (double)Aim[idx];
    double den = are * are + aim * aim;
    double nr = wr - 1.0, ni = wi;
    double qr = (nr * are + ni * aim) / den;
    double qi = (ni * are - nr * aim) / den;
    for (int ch = 0; ch < 2; ch++) {
        double cr = (double)Cre[ch * Hdim * NM + idx];
        double ci = (double)Cim[ch * Hdim * NM + idx];
        ceff[ch * Hdim * NM + idx] = make_float2((float)(cr * qr - ci * qi),
                                                 (float)(cr * qi + ci * qr));
    }
}

// ---------------- weight transpose + bf16 cast ----------------
__global__ void k_wt(const float* __restrict__ W1, const float* __restrict__ W2,
                     const float* __restrict__ W3, unsigned short* __restrict__ W1T,
                     unsigned short* __restrict__ W2T, unsigned short* __restrict__ W3T) {
    int t = blockIdx.x * 256 + threadIdx.x;  // 131072 threads
    int k = t >> 9, n = t & 511;             // W1,W2: [256][512]
    W1T[n * 256 + k] = f2bf(W1[t]);
    W2T[n * 256 + k] = f2bf(W2[t]);
    int k3 = t >> 8, n3 = t & 255;           // W3: [512][256]
    W3T[n3 * 512 + k3] = f2bf(W3[t]);
}

// ---------------- merged: wpow table -> kf/kb -> Abig rows -> Wp rows ----------------
__global__ __launch_bounds__(256) void k_abw(const float* __restrict__ logdt,
                                             const float* __restrict__ Are,
                                             const float* __restrict__ Aim,
                                             const float2* __restrict__ CE,
                                             const float* __restrict__ Dsk,
                                             unsigned short* __restrict__ AB,
                                             unsigned short* __restrict__ Wp) {
    __shared__ float2 wpow[32][257];   // w^j, j=0..256
    __shared__ float kf[256], kb[256];
    __shared__ float2 ce_s[64];        // [0..31] fwd, [32..63] bwd
    int h = blockIdx.x;
    int t = threadIdx.x;
    if (t < 64) ce_s[t] = CE[(t >> 5) * (Hdim * NM) + h * NM + (t & 31)];
    {   // build wpow: thread = n*8+seg, 32-step recurrence from w^(32*seg)
        int n = t >> 3, seg = t & 7;
        float dt = expf(logdt[h]);
        float dar = dt * Are[h * NM + n], dai = dt * Aim[h * NM + n];
        float em = expf(dar);
        float wr = em * cosf(dai), wi = em * sinf(dai);
        int j0 = seg * 32;
        float m = expf((float)j0 * dar), ang = (float)j0 * dai;
        float vr = m * cosf(ang), vi = m * sinf(ang);
        for (int q = 0; q < 32; q++) {
            wpow[n][j0 + q] = make_float2(vr, vi);
            float nr2 = vr * wr - vi * wi;
            float ni2 = vr * wi + vi * wr;
            vr = nr2; vi = ni2;
        }
        if (seg == 7) wpow[n][256] = make_float2(vr, vi);
    }
    __syncthreads();
    {   // conv kernels kf[d], kb[d] (lane = d)
        float kfv = 0.f, kbv = 0.f;
#pragma unroll
        for (int n = 0; n < NM; n++) {
            float2 wv = wpow[n][t];
            float2 cf = ce_s[n], cb = ce_s[32 + n];
            kfv = fmaf(cf.x, wv.x, fmaf(-cf.y, wv.y, kfv));
            kbv = fmaf(cb.x, wv.x, fmaf(-cb.y, wv.y, kbv));
        }
        kf[t] = 2.f * kfv;
        kb[t] = 2.f * kbv;
    }
    __syncthreads();
    float dsk = Dsk[h];
    for (int j = 0; j < 256; j++) {
        unsigned short* out = AB + ((size_t)h * 256 + j) * KBIG;
        float v = (t <= j) ? kf[j - t] : kb[t - j - 1];
        if (t == j) v += dsk;
        out[t] = f2bf(v);
        if (t < 128) {
            int n = (t & 63) >> 1, reim = t & 1;
            float2 c = (t < 64) ? ce_s[n] : ce_s[32 + n];
            float2 wv = (t < 64) ? wpow[n][j + 1] : wpow[n][255 - j];
            float re = c.x * wv.x - c.y * wv.y;
            float im = c.x * wv.y + c.y * wv.x;
            out[256 + t] = f2bf(reim ? -2.f * im : 2.f * re);
        }
    }
    for (int r = 0; r < 128; r++) {
        int n = (r & 63) >> 1, reim = r & 1, dir = r >> 6;
        float2 wv = wpow[n][dir ? t : 255 - t];
        Wp[((size_t)h * 128 + r) * 256 + t] = f2bf(reim ? wv.y : wv.x);
    }
}

// ---------------- fused layernorm + transpose: x (b,l,h) fp32 -> UT (b,h,l) bf16 ----------------
__global__ __launch_bounds__(256) void k_lntr(const float* __restrict__ x,
                                              const float* __restrict__ g,
                                              const float* __restrict__ bt,
                                              unsigned short* __restrict__ UT) {
    __shared__ unsigned short lds[256][65];
    int lt = blockIdx.x, b = blockIdx.y;
    int t = threadIdx.x;
    int lane = t & 63, w = t >> 6;
    float4 gg = ((const float4*)g)[lane];
    float4 bb = ((const float4*)bt)[lane];
#pragma unroll
    for (int q = 0; q < 16; q++) {
        int l = q * 4 + w;
        float4 v = ((const float4*)(x + ((size_t)(b * LL + lt * 64 + l)) * Hdim))[lane];
        float s = v.x + v.y + v.z + v.w;
        float ss = v.x * v.x + v.y * v.y + v.z * v.z + v.w * v.w;
#pragma unroll
        for (int o = 1; o < 64; o <<= 1) { s += __shfl_xor(s, o, 64); ss += __shfl_xor(ss, o, 64); }
        float mean = s * (1.0f / Hdim);
        float var = ss * (1.0f / Hdim) - mean * mean;
        float rstd = rsqrtf(var + 1e-5f);
        lds[lane * 4 + 0][l] = f2bf((v.x - mean) * rstd * gg.x + bb.x);
        lds[lane * 4 + 1][l] = f2bf((v.y - mean) * rstd * gg.y + bb.y);
        lds[lane * 4 + 2][l] = f2bf((v.z - mean) * rstd * gg.z + bb.z);
        lds[lane * 4 + 3][l] = f2bf((v.w - mean) * rstd * gg.w + bb.w);
    }
    __syncthreads();
    for (int q = 0; q < 64; q++) {
        int idx = q * 256 + t;
        int hh = idx >> 6, ll = idx & 63;
        UT[((size_t)(b * Hdim + hh)) * LL + lt * 64 + ll] = lds[hh][ll];
    }
}

// ---------------- layernorm bf16 out (second LN) ----------------
__global__ void k_ln_bf(const float* __restrict__ x, const float* __restrict__ g,
                        const float* __restrict__ bt, unsigned short* __restrict__ out) {
    int row = blockIdx.x * 4 + (threadIdx.x >> 6);
    int lane = threadIdx.x & 63;
    float4 v = ((const float4*)(x + (size_t)row * Hdim))[lane];
    float s = v.x + v.y + v.z + v.w;
    float ss = v.x * v.x + v.y * v.y + v.z * v.z + v.w * v.w;
#pragma unroll
    for (int o = 1; o < 64; o <<= 1) { s += __shfl_xor(s, o, 64); ss += __shfl_xor(ss, o, 64); }
    float mean = s * (1.0f / Hdim);
    float var = ss * (1.0f / Hdim) - mean * mean;
    float rstd = rsqrtf(var + 1e-5f);
    float4 gg = ((const float4*)g)[lane];
    float4 bb = ((const float4*)bt)[lane];
    ushort4 o;
    o.x = f2bf((v.x - mean) * rstd * gg.x + bb.x);
    o.y = f2bf((v.y - mean) * rstd * gg.y + bb.y);
    o.z = f2bf((v.z - mean) * rstd * gg.z + bb.z);
    o.w = f2bf((v.w - mean) * rstd * gg.w + bb.w);
    ((ushort4*)(out + (size_t)row * Hdim))[lane] = o;
}

// ---------------- state GEMM (dbuf, static-unrolled): Zg[h][bc][r], 128x128 tiles ----------------
__global__ __launch_bounds__(256) void k_zgemm(const unsigned short* __restrict__ UT,
                                               const unsigned short* __restrict__ Wp,
                                               float* __restrict__ Zg) {
    __shared__ unsigned short As[2][128 * 64];
    __shared__ unsigned short Bs[2][128 * 64];
    int h = blockIdx.x;
    int mbase = blockIdx.y * 128;
    int t = threadIdx.x;
    int w = t >> 6, lane = t & 63;
    int m0 = (w & 1) * 64, nb = (w >> 1) * 64;
    int lr = lane & 15, lk = (lane >> 4) * 8;
    const unsigned short* Wph = Wp + (size_t)h * 128 * 256;
    f32x4 acc[4][4];
#pragma unroll
    for (int i = 0; i < 4; i++)
#pragma unroll
        for (int jx = 0; jx < 4; jx++) acc[i][jx] = (f32x4){0.f, 0.f, 0.f, 0.f};
    stageUT<128, 256>(UT, h, mbase, 0, As[0], t);
    stage64<128, 256>(Wph, 256, 0, Bs[0], t);
    __syncthreads();
#pragma unroll
    for (int s = 0; s < 4; s++) {
        const int cur = s & 1;
        if (s < 3) {
            stageUT<128, 256>(UT, h, mbase, (s + 1) * 64, As[cur ^ 1], t);
            stage64<128, 256>(Wph, 256, (s + 1) * 64, Bs[cur ^ 1], t);
        }
#pragma unroll
        for (int kk = 0; kk < 64; kk += 32) {
            bf16x8 a[4], b[4];
#pragma unroll
            for (int mi = 0; mi < 4; mi++) a[mi] = fr(As[cur], m0 + mi * 16 + lr, kk + lk);
#pragma unroll
            for (int nf = 0; nf < 4; nf++) b[nf] = fr(Bs[cur], nb + nf * 16 + lr, kk + lk);
#pragma unroll
            for (int mi = 0; mi < 4; mi++)
#pragma unroll
                for (int nf = 0; nf < 4; nf++)
                    acc[mi][nf] = __builtin_amdgcn_mfma_f32_16x16x32_bf16(a[mi], b[nf], acc[mi][nf], 0, 0, 0);
        }
        __syncthreads();
    }
#pragma unroll
    for (int mi = 0; mi < 4; mi++)
#pragma unroll
        for (int nf = 0; nf < 4; nf++) {
            int col = nb + nf * 16 + lr;
#pragma unroll
            for (int r = 0; r < 4; r++) {
                int row = mbase + m0 + mi * 16 + (lane >> 4) * 4 + r;
                Zg[((size_t)h * 256 + row) * 128 + col] = acc[mi][nf][r];
            }
        }
}

// ---------------- prefix over chunks -> Zpacked bf16 [h][bc][128] ----------------
__global__ void k_prefix2(const float* __restrict__ Zg, const float2* __restrict__ wptab,
                          unsigned short* __restrict__ ZP) {
    int t = blockIdx.x * 256 + threadIdx.x;
    int n = t & 31;
    int h = (t >> 5) & 255;
    int b = (t >> 13) & 15;
    int dir = (t >> 17) & 1;
    float2 wp = wptab[h * NM + n];
    float sr = 0.f, si = 0.f;
    int ro = dir ? 64 + 2 * n : 2 * n;
    if (dir == 0) {
        for (int c = 0; c < NCH; c++) {
            size_t base = ((size_t)h * 256 + b * NCH + c) * 128;
            ZP[base + ro] = f2bf(sr);
            ZP[base + ro + 1] = f2bf(si);
            float zr = Zg[base + ro], zi = Zg[base + ro + 1];
            float nr = fmaf(wp.x, sr, fmaf(-wp.y, si, zr));
            float ni = fmaf(wp.y, sr, fmaf(wp.x, si, zi));
            sr = nr; si = ni;
        }
    } else {
        for (int c = NCH - 1; c >= 0; c--) {
            size_t base = ((size_t)h * 256 + b * NCH + c) * 128;
            ZP[base + ro] = f2bf(sr);
            ZP[base + ro + 1] = f2bf(si);
            float zr = Zg[base + ro], zi = Zg[base + ro + 1];
            float nr = fmaf(wp.x, sr, fmaf(-wp.y, si, zr));
            float ni = fmaf(wp.y, sr, fmaf(wp.x, si, zi));
            sr = nr; si = ni;
        }
    }
}

// ---------------- conv GEMM (dbuf, static-unrolled): Yt[h][bc][j], 128x128 tiles ----------------
__global__ __launch_bounds__(256) void k_conv(const unsigned short* __restrict__ UT,
                                              const unsigned short* __restrict__ ZP,
                                              const unsigned short* __restrict__ AB,
                                              unsigned short* __restrict__ Yt) {
    __shared__ unsigned short As[2][128 * 64];
    __shared__ unsigned short Bs[2][128 * 64];
    // XCD-chunked swizzle (1024 blocks, %8==0 -> bijective): 4 subtiles of one h share an XCD
    int wgid = ((int)blockIdx.x % 8) * 128 + (int)blockIdx.x / 8;
    int h = wgid >> 2;
    int sub = wgid & 3;
    int mbase = (sub >> 1) * 128;
    int jbase = (sub & 1) * 128;
    int t = threadIdx.x;
    int w = t >> 6, lane = t & 63;
    int m0 = (w & 1) * 64, nb = (w >> 1) * 64;
    int lr = lane & 15, lk = (lane >> 4) * 8;
    const unsigned short* ABj = AB + ((size_t)h * 256 + jbase) * KBIG;
    const unsigned short* ZPm = ZP + ((size_t)h * 256 + mbase) * 128;
    f32x4 acc[4][4];
#pragma unroll
    for (int i = 0; i < 4; i++)
#pragma unroll
        for (int jx = 0; jx < 4; jx++) acc[i][jx] = (f32x4){0.f, 0.f, 0.f, 0.f};
    // 6 steps: s=0..3 u-part (K=256), s=4..5 z-part (K=128 from ZP, AB cols 256+)
    stageUT<128, 256>(UT, h, mbase, 0, As[0], t);
    stage64<128, 256>(ABj, KBIG, 0, Bs[0], t);
    __syncthreads();
#pragma unroll
    for (int s = 0; s < 6; s++) {
        const int cur = s & 1;
        const int nx = s + 1;
        if (nx < 4) {
            stageUT<128, 256>(UT, h, mbase, nx * 64, As[cur ^ 1], t);
            stage64<128, 256>(ABj, KBIG, nx * 64, Bs[cur ^ 1], t);
        } else if (nx < 6) {
            stage64<128, 256>(ZPm, 128, (nx - 4) * 64, As[cur ^ 1], t);
            stage64<128, 256>(ABj + 256, KBIG, (nx - 4) * 64, Bs[cur ^ 1], t);
        }
#pragma unroll
        for (int kk = 0; kk < 64; kk += 32) {
            bf16x8 a[4], b[4];
#pragma unroll
            for (int mi = 0; mi < 4; mi++) a[mi] = fr(As[cur], m0 + mi * 16 + lr, kk + lk);
#pragma unroll
            for (int nf = 0; nf < 4; nf++) b[nf] = fr(Bs[cur], nb + nf * 16 + lr, kk + lk);
#pragma unroll
            for (int mi = 0; mi < 4; mi++)
#pragma unroll
                for (int nf = 0; nf < 4; nf++)
                    acc[mi][nf] = __builtin_amdgcn_mfma_f32_16x16x32_bf16(a[mi], b[nf], acc[mi][nf], 0, 0, 0);
        }
        __syncthreads();
    }
#pragma unroll
    for (int mi = 0; mi < 4; mi++)
#pragma unroll
        for (int nf = 0; nf < 4; nf++) {
            int col = jbase + nb + nf * 16 + lr;
#pragma unroll
            for (int r = 0; r < 4; r++) {
                int row = mbase + m0 + mi * 16 + (lane >> 4) * 4 + r;
                Yt[(size_t)h * 65536 + row * 256 + col] = f2bf(gelu_f(acc[mi][nf][r]));
            }
        }
}

// ---------------- transpose Yt [h][bc][j] -> G (b, c*P+j, h) bf16 ----------------
__global__ void k_trg(const unsigned short* __restrict__ Yt, unsigned short* __restrict__ G) {
    __shared__ unsigned short lds[64][65];
    int bc = blockIdx.x;
    int h0 = blockIdx.y * 64, j0 = blockIdx.z * 64;
    int t = threadIdx.x;
#pragma unroll
    for (int q = 0; q < 16; q++) {
        int idx = q * 256 + t;
        int hh = idx >> 6, jj = idx & 63;
        lds[hh][jj] = Yt[(size_t)(h0 + hh) * 65536 + bc * 256 + j0 + jj];
    }
    __syncthreads();
    int b = bc >> 4, c = bc & 15;
#pragma unroll
    for (int q = 0; q < 16; q++) {
        int idx = q * 256 + t;
        int jj = idx >> 6, hh = idx & 63;
        G[((size_t)(b * LL + c * PCH + j0 + jj)) * Hdim + h0 + hh] = lds[hh][jj];
    }
}

// ---------------- GEMM1 (dbuf, static-unrolled): X2 = x + glu(G@Wout + bo) ----------------
__global__ __launch_bounds__(256) void k_gemm1(const unsigned short* __restrict__ Gm,
                                               const unsigned short* __restrict__ W1T,
                                               const float* __restrict__ bo,
                                               const float* __restrict__ xin,
                                               float* __restrict__ X2) {
    __shared__ unsigned short As[2][128 * 64];
    __shared__ unsigned short BsA[2][64 * 64];
    __shared__ unsigned short BsB[2][64 * 64];
    int t = threadIdx.x;
    int w = t >> 6, lane = t & 63;
    int m0w = (w & 1) * 64, n0w = (w >> 1) * 32;
    int lr = lane & 15, lk = (lane >> 4) * 8;
    int mblk = blockIdx.x * 128, nblk = blockIdx.y * 64;
    const unsigned short* Ab  = Gm + (size_t)mblk * 256;
    const unsigned short* BbA = W1T + (size_t)nblk * 256;
    const unsigned short* BbB = W1T + (size_t)(nblk + 256) * 256;
    f32x4 acc[4][4];
#pragma unroll
    for (int i = 0; i < 4; i++)
#pragma unroll
        for (int j = 0; j < 4; j++) acc[i][j] = (f32x4){0.f, 0.f, 0.f, 0.f};
    stage64<128, 256>(Ab, 256, 0, As[0], t);
    stage64<64, 256>(BbA, 256, 0, BsA[0], t);
    stage64<64, 256>(BbB, 256, 0, BsB[0], t);
    __syncthreads();
#pragma unroll
    for (int s = 0; s < 4; s++) {
        const int cur = s & 1;
        if (s < 3) {
            stage64<128, 256>(Ab, 256, (s + 1) * 64, As[cur ^ 1], t);
            stage64<64, 256>(BbA, 256, (s + 1) * 64, BsA[cur ^ 1], t);
            stage64<64, 256>(BbB, 256, (s + 1) * 64, BsB[cur ^ 1], t);
        }
#pragma unroll
        for (int kk = 0; kk < 64; kk += 32) {
            bf16x8 a[4], bA[2], bB[2];
#pragma unroll
            for (int mi = 0; mi < 4; mi++)
                a[mi] = fr(As[cur], m0w + mi * 16 + lr, kk + lk);
#pragma unroll
            for (int nf = 0; nf < 2; nf++) {
                bA[nf] = fr(BsA[cur], n0w + nf * 16 + lr, kk + lk);
                bB[nf] = fr(BsB[cur], n0w + nf * 16 + lr, kk + lk);
            }
#pragma unroll
            for (int mi = 0; mi < 4; mi++)
#pragma unroll
                for (int nf = 0; nf < 2; nf++) {
                    acc[mi][nf] = __builtin_amdgcn_mfma_f32_16x16x32_bf16(a[mi], bA[nf], acc[mi][nf], 0, 0, 0);
                    acc[mi][nf + 2] = __builtin_amdgcn_mfma_f32_16x16x32_bf16(a[mi], bB[nf], acc[mi][nf + 2], 0, 0, 0);
                }
        }
        __syncthreads();
    }
#pragma unroll
    for (int mi = 0; mi < 4; mi++)
#pragma unroll
        for (int nf = 0; nf < 2; nf++) {
            int col = nblk + n0w + nf * 16 + lr;
            float biasA = bo[col], biasB = bo[col + 256];
#pragma unroll
            for (int r = 0; r < 4; r++) {
                int row = mblk + m0w + mi * 16 + (lane >> 4) * 4 + r;
                float zzA = acc[mi][nf][r] + biasA;
                float zzB = acc[mi][nf + 2][r] + biasB;
                float v = zzA / (1.0f + expf(-zzB));
                size_t idx = (size_t)row * 256 + col;
                X2[idx] = xin[idx] + v;
            }
        }
}

// ---------------- GEMM2 (dbuf, static-unrolled): M = gelu(T2@W2 + b2) bf16 ----------------
__global__ __launch_bounds__(256) void k_gemm2(const unsigned short* __restrict__ T2,
                                               const unsigned short* __restrict__ W2T,
                                               const float* __restrict__ b2,
                                               unsigned short* __restrict__ Mo) {
    __shared__ unsigned short As[2][128 * 64];
    __shared__ unsigned short Bs[2][128 * 64];
    int t = threadIdx.x;
    int w = t >> 6, lane = t & 63;
    int m0w = (w & 1) * 64, n0w = (w >> 1) * 64;
    int lr = lane & 15, lk = (lane >> 4) * 8;
    int mblk = blockIdx.x * 128, nblk = blockIdx.y * 128;
    const unsigned short* Ab = T2 + (size_t)mblk * 256;
    const unsigned short* Bb = W2T + (size_t)nblk * 256;
    f32x4 acc[4][4];
#pragma unroll
    for (int i = 0; i < 4; i++)
#pragma unroll
        for (int j = 0; j < 4; j++) acc[i][j] = (f32x4){0.f, 0.f, 0.f, 0.f};
    stage64<128, 256>(Ab, 256, 0, As[0], t);
    stage64<128, 256>(Bb, 256, 0, Bs[0], t);
    __syncthreads();
#pragma unroll
    for (int s = 0; s < 4; s++) {
        const int cur = s & 1;
        if (s < 3) {
            stage64<128, 256>(Ab, 256, (s + 1) * 64, As[cur ^ 1], t);
            stage64<128, 256>(Bb, 256, (s + 1) * 64, Bs[cur ^ 1], t);
        }
#pragma unroll
        for (int kk = 0; kk < 64; kk += 32) {
            bf16x8 a[4], b[4];
#pragma unroll
            for (int mi = 0; mi < 4; mi++)
                a[mi] = fr(As[cur], m0w + mi * 16 + lr, kk + lk);
#pragma unroll
            for (int nf = 0; nf < 4; nf++)
                b[nf] = fr(Bs[cur], n0w + nf * 16 + lr, kk + lk);
#pragma unroll
            for (int mi = 0; mi < 4; mi++)
#pragma unroll
                for (int nf = 0; nf < 4; nf++)
                    acc[mi][nf] = __builtin_amdgcn_mfma_f32_16x16x32_bf16(a[mi], b[nf], acc[mi][nf], 0, 0, 0);
        }
        __syncthreads();
    }
#pragma unroll
    for (int mi = 0; mi < 4; mi++)
#pragma unroll
        for (int nf = 0; nf < 4; nf++) {
            int col = nblk + n0w + nf * 16 + lr;
            float bias = b2[col];
#pragma unroll
            for (int r = 0; r < 4; r++) {
                int row = mblk + m0w + mi * 16 + (lane >> 4) * 4 + r;
                Mo[(size_t)row * 512 + col] = f2bf(gelu_f(acc[mi][nf][r] + bias));
            }
        }
}

// ---------------- GEMM3 (dbuf, static-unrolled): out = X2 + M@W3 + b3 ----------------
__global__ __launch_bounds__(256) void k_gemm3(const unsigned short* __restrict__ Mb,
                                               const unsigned short* __restrict__ W3T,
                                               const float* __restrict__ b3,
                                               const float* __restrict__ X2,
                                               float* __restrict__ out) {
    __shared__ unsigned short As[2][128 * 64];
    __shared__ unsigned short Bs[2][128 * 64];
    int t = threadIdx.x;
    int w = t >> 6, lane = t & 63;
    int m0w = (w & 1) * 64, n0w = (w >> 1) * 64;
    int lr = lane & 15, lk = (lane >> 4) * 8;
    int mblk = blockIdx.x * 128, nblk = blockIdx.y * 128;
    const unsigned short* Ab = Mb + (size_t)mblk * 512;
    const unsigned short* Bb = W3T + (size_t)nblk * 512;
    f32x4 acc[4][4];
#pragma unroll
    for (int i = 0; i < 4; i++)
#pragma unroll
        for (int j = 0; j < 4; j++) acc[i][j] = (f32x4){0.f, 0.f, 0.f, 0.f};
    stage64<128, 256>(Ab, 512, 0, As[0], t);
    stage64<128, 256>(Bb, 512, 0, Bs[0], t);
    __syncthreads();
#pragma unroll
    for (int s = 0; s < 8; s++) {
        const int cur = s & 1;
        if (s < 7) {
            stage64<128, 256>(Ab, 512, (s + 1) * 64, As[cur ^ 1], t);
            stage64<128, 256>(Bb, 512, (s + 1) * 64, Bs[cur ^ 1], t);
        }
#pragma unroll
        for (int kk = 0; kk < 64; kk += 32) {
            bf16x8 a[4], b[4];
#pragma unroll
            for (int mi = 0; mi < 4; mi++)
                a[mi] = fr(As[cur], m0w + mi * 16 + lr, kk + lk);
#pragma unroll
            for (int nf = 0; nf < 4; nf++)
                b[nf] = fr(Bs[cur], n0w + nf * 16 + lr, kk + lk);
#pragma unroll
            for (int mi = 0; mi < 4; mi++)
#pragma unroll
                for (int nf = 0; nf < 4; nf++)
                    acc[mi][nf] = __builtin_amdgcn_mfma_f32_16x16x32_bf16(a[mi], b[nf], acc[mi][nf], 0, 0, 0);
        }
        __syncthreads();
    }
#pragma unroll
    for (int mi = 0; mi < 4; mi++)
#pragma unroll
        for (int nf = 0; nf < 4; nf++) {
            int col = nblk + n0w + nf * 16 + lr;
            float bias = b3[col];
#pragma unroll
            for (int r = 0; r < 4; r++) {
                int row = mblk + m0w + mi * 16 + (lane >> 4) * 4 + r;
                size_t idx = (size_t)row * 256 + col;
                out[idx] = X2[idx] + acc[mi][nf][r] + bias;
            }
        }
}

extern "C" void kernel_launch(void* const* d_in, const int* in_sizes, int n_in,
                              void* d_out, int out_size, void* d_ws, size_t ws_size,
                              hipStream_t stream) {
    const float* x     = (const float*)d_in[0];
    const float* ln1g  = (const float*)d_in[1];
    const float* ln1b  = (const float*)d_in[2];
    const float* ln2g  = (const float*)d_in[3];
    const float* ln2b  = (const float*)d_in[4];
    const float* logdt = (const float*)d_in[5];
    const float* Are   = (const float*)d_in[6];
    const float* Aim   = (const float*)d_in[7];
    const float* Cre   = (const float*)d_in[8];
    const float* Cim   = (const float*)d_in[9];
    const float* Dsk   = (const float*)d_in[10];
    const float* Wout  = (const float*)d_in[11];
    const float* bo    = (const float*)d_in[12];
    const float* W2    = (const float*)d_in[13];
    const float* b2    = (const float*)d_in[14];
    const float* W3    = (const float*)d_in[15];
    const float* b3    = (const float*)d_in[16];

    char* ws = (char*)d_ws;
    unsigned short* AB   = (unsigned short*)(ws + OFF_ABIG);
    unsigned short* Wp   = (unsigned short*)(ws + OFF_WPM);
    float*          X2   = (float*)(ws + OFF_ABIG);
    unsigned short* UT   = (unsigned short*)(ws + OFF_UT);
    float*          Zg   = (float*)(ws + OFF_ZG);
    unsigned short* Yt   = (unsigned short*)(ws + OFF_ZG);
    unsigned short* Mb   = (unsigned short*)(ws + OFF_M);
    unsigned short* ZP   = (unsigned short*)(ws + OFF_ZP);
    unsigned short* G    = (unsigned short*)(ws + OFF_G);
    float2*         WT   = (float2*)(ws + OFF_WTAB);
    float2*         WPT  = (float2*)(ws + OFF_WPT);
    float2*         CE   = (float2*)(ws + OFF_CE);
    unsigned short* W1T  = (unsigned short*)(ws + OFF_W1T);
    unsigned short* W2T  = (unsigned short*)(ws + OFF_W2T);
    unsigned short* W3T  = (unsigned short*)(ws + OFF_W3T);

    k_tab<<<32, 256, 0, stream>>>(logdt, Are, Aim, Cre, Cim, WT, WPT, CE);
    k_wt<<<512, 256, 0, stream>>>(Wout, W2, W3, W1T, W2T, W3T);
    k_lntr<<<dim3(64, 16), 256, 0, stream>>>(x, ln1g, ln1b, UT);
    k_abw<<<256, 256, 0, stream>>>(logdt, Are, Aim, CE, Dsk, AB, Wp);
    k_zgemm<<<dim3(256, 2), 256, 0, stream>>>(UT, Wp, Zg);
    k_prefix2<<<1024, 256, 0, stream>>>(Zg, WPT, ZP);
    k_conv<<<1024, 256, 0, stream>>>(UT, ZP, AB, Yt);
    k_trg<<<dim3(256, 4, 4), 256, 0, stream>>>(Yt, G);
    k_gemm1<<<dim3(512, 4), 256, 0, stream>>>(G, W1T, bo, x, X2);
    k_ln_bf<<<NB * LL / 4, 256, 0, stream>>>(X2, ln2g, ln2b, G);
    k_gemm2<<<dim3(512, 4), 256, 0, stream>>>(G, W2T, b2, Mb);
    k_gemm3<<<dim3(512, 2), 256, 0, stream>>>(Mb, W3T, b3, X2, (float*)d_out);
}

// Round 12
// 292.781 us; speedup vs baseline: 1.2002x; 1.2002x over previous
//
#include <hip/hip_runtime.h>
#include <hip/hip_bf16.h>

typedef __attribute__((ext_vector_type(8))) short bf16x8;
typedef __attribute__((ext_vector_type(4))) float f32x4;

#define Hdim 256
#define NM 32      // N2 modes
#define NB 16      // batch
#define LL 4096    // seq len
#define PCH 256    // chunk length
#define NCH 16     // chunks = LL/PCH
#define KBIG 384   // conv GEMM K: 256 u + 64 zf + 64 zb

// ---- workspace layout (bytes), total 186,122,240 ----
#define OFF_ABIG ((size_t)0)
#define OFF_WPM  ((size_t)50331648)
#define OFF_UT   ((size_t)67108864)    // U_T bf16 [B][H][L] 33554432
#define OFF_ZG   ((size_t)100663296)   // Zg fp32 [h][bc][128] ; then Yt bf16
#define OFF_M    ((size_t)67108864)    // M bf16 (spans UT+ZG, alive gemm2->gemm3)
#define OFF_ZP   ((size_t)134217728)   // Zpacked bf16 [h][bc][128]
#define OFF_G    ((size_t)150994944)   // G bf16 (b,l,h) ; reused as T2
#define OFF_WTAB ((size_t)185073664)
#define OFF_WPT  ((size_t)185139200)
#define OFF_CE   ((size_t)185204736)
#define OFF_W1T  ((size_t)185335808)
#define OFF_W2T  ((size_t)185597952)
#define OFF_W3T  ((size_t)185860096)

typedef const __attribute__((address_space(1))) void* gas_p;
typedef __attribute__((address_space(3))) void* las_p;

// fast gelu: tanh form via hardware exp + rcp (max abs err ~1e-3 vs erf form)
__device__ __forceinline__ float gelu_f(float v) {
    float u = 0.7978845608028654f * fmaf(0.044715f * v * v, v, v);
    float uc = fminf(fmaxf(u, -15.f), 15.f);
    float e = __expf(2.f * uc);
    return 0.5f * v * (1.f + (e - 1.f) * __builtin_amdgcn_rcpf(e + 1.f));
}
__device__ __forceinline__ unsigned short f2bf(float f) {  // RNE f32->bf16
    unsigned int u = __float_as_uint(f);
    u += 0x7fffu + ((u >> 16) & 1u);
    return (unsigned short)(u >> 16);
}
__device__ __forceinline__ float bf2f(unsigned short u) {
    return __uint_as_float((unsigned int)u << 16);
}

// swizzled fragment read from a [R][64] tile: XOR 16B-block index with (row&7).
__device__ __forceinline__ bf16x8 fr(const unsigned short* lds, int row, int kcol) {
    return *(const bf16x8*)(lds + row * 64 + ((((kcol >> 3) ^ (row & 7)) << 3)));
}

// stage ROWS x 64 bf16 tile (row-major, ld elems) into LDS [ROWS][64] (linear dest,
// inverse-swizzled source)
template<int ROWS, int THREADS>
__device__ __forceinline__ void stage64(const unsigned short* __restrict__ src, int ld, int k0,
                                        unsigned short* lds, int t) {
    constexpr int EPI = THREADS * 8;   // elems per iter
#pragma unroll
    for (int i = 0; i < (ROWS * 64) / EPI; i++) {
        int e = i * EPI + t * 8;
        int r = e >> 6;
        int k = (((e >> 3) & 7) ^ (r & 7)) << 3;
        const unsigned short* g = src + (size_t)r * ld + (k0 + k);
        unsigned short* l = lds + i * EPI + (t >> 6) * 512;   // wave-uniform base
        __builtin_amdgcn_global_load_lds((gas_p)g, (las_p)l, 16, 0, 0);
    }
}

// stage ROWS x 64 tile of UT (bc-rows) for head h, same swizzle
template<int ROWS, int THREADS>
__device__ __forceinline__ void stageUT(const unsigned short* __restrict__ UT, int h, int rbase,
                                        int k0, unsigned short* lds, int t) {
    constexpr int EPI = THREADS * 8;
#pragma unroll
    for (int i = 0; i < (ROWS * 64) / EPI; i++) {
        int e = i * EPI + t * 8;
        int r = e >> 6;
        int k = (((e >> 3) & 7) ^ (r & 7)) << 3;
        int row = rbase + r;
        const unsigned short* g = UT + ((size_t)((row >> 4) * Hdim + h)) * LL
                                  + (row & 15) * PCH + (k0 + k);
        unsigned short* l = lds + i * EPI + (t >> 6) * 512;
        __builtin_amdgcn_global_load_lds((gas_p)g, (las_p)l, 16, 0, 0);
    }
}

// ---------------- tables ----------------
__global__ void k_tab(const float* __restrict__ logdt, const float* __restrict__ Are,
                      const float* __restrict__ Aim, const float* __restrict__ Cre,
                      const float* __restrict__ Cim, float2* __restrict__ wtab,
                      float2* __restrict__ wptab, float2* __restrict__ ceff) {
    int idx = blockIdx.x * blockDim.x + threadIdx.x;
    if (idx >= Hdim * NM) return;
    int h = idx >> 5;
    float dt = expf(logdt[h]);
    double dar = (double)dt * (double)Are[idx];
    double dai = (double)dt * (double)Aim[idx];
    double wm = exp(dar);
    double wr = wm * cos(dai), wi = wm * sin(dai);
    wtab[idx] = make_float2((float)wr, (float)wi);
    double pm = exp(dar * (double)PCH);
    double pai = dai * (double)PCH;
    wptab[idx] = make_float2((float)(pm * cos(pai)), (float)(pm * sin(pai)));
    double are = (double)Are[idx], aim = (double)Aim[idx];
    double den = are * are + aim * aim;
    double nr = wr - 1.0, ni = wi;
    double qr = (nr * are + ni * aim) / den;
    double qi = (ni * are - nr * aim) / den;
    for (int ch = 0; ch < 2; ch++) {
        double cr = (double)Cre[ch * Hdim * NM + idx];
        double ci = (double)Cim[ch * Hdim * NM + idx];
        ceff[ch * Hdim * NM + idx] = make_float2((float)(cr * qr - ci * qi),
                                                 (float)(cr * qi + ci * qr));
    }
}

// ---------------- weight transpose + bf16 cast ----------------
__global__ void k_wt(const float* __restrict__ W1, const float* __restrict__ W2,
                     const float* __restrict__ W3, unsigned short* __restrict__ W1T,
                     unsigned short* __restrict__ W2T, unsigned short* __restrict__ W3T) {
    int t = blockIdx.x * 256 + threadIdx.x;  // 131072 threads
    int k = t >> 9, n = t & 511;             // W1,W2: [256][512]
    W1T[n * 256 + k] = f2bf(W1[t]);
    W2T[n * 256 + k] = f2bf(W2[t]);
    int k3 = t >> 8, n3 = t & 255;           // W3: [512][256]
    W3T[n3 * 512 + k3] = f2bf(W3[t]);
}

// ---------------- merged: wpow table -> kf/kb -> Abig rows -> Wp rows ----------------
__global__ __launch_bounds__(256) void k_abw(const float* __restrict__ logdt,
                                             const float* __restrict__ Are,
                                             const float* __restrict__ Aim,
                                             const float2* __restrict__ CE,
                                             const float* __restrict__ Dsk,
                                             unsigned short* __restrict__ AB,
                                             unsigned short* __restrict__ Wp) {
    __shared__ float2 wpow[32][257];   // w^j, j=0..256
    __shared__ float kf[256], kb[256];
    __shared__ float2 ce_s[64];        // [0..31] fwd, [32..63] bwd
    int h = blockIdx.x;
    int t = threadIdx.x;
    if (t < 64) ce_s[t] = CE[(t >> 5) * (Hdim * NM) + h * NM + (t & 31)];
    {   // build wpow: thread = n*8+seg, 32-step recurrence from w^(32*seg)
        int n = t >> 3, seg = t & 7;
        float dt = expf(logdt[h]);
        float dar = dt * Are[h * NM + n], dai = dt * Aim[h * NM + n];
        float em = expf(dar);
        float wr = em * cosf(dai), wi = em * sinf(dai);
        int j0 = seg * 32;
        float m = expf((float)j0 * dar), ang = (float)j0 * dai;
        float vr = m * cosf(ang), vi = m * sinf(ang);
        for (int q = 0; q < 32; q++) {
            wpow[n][j0 + q] = make_float2(vr, vi);
            float nr2 = vr * wr - vi * wi;
            float ni2 = vr * wi + vi * wr;
            vr = nr2; vi = ni2;
        }
        if (seg == 7) wpow[n][256] = make_float2(vr, vi);
    }
    __syncthreads();
    {   // conv kernels kf[d], kb[d] (lane = d)
        float kfv = 0.f, kbv = 0.f;
#pragma unroll
        for (int n = 0; n < NM; n++) {
            float2 wv = wpow[n][t];
            float2 cf = ce_s[n], cb = ce_s[32 + n];
            kfv = fmaf(cf.x, wv.x, fmaf(-cf.y, wv.y, kfv));
            kbv = fmaf(cb.x, wv.x, fmaf(-cb.y, wv.y, kbv));
        }
        kf[t] = 2.f * kfv;
        kb[t] = 2.f * kbv;
    }
    __syncthreads();
    float dsk = Dsk[h];
    for (int j = 0; j < 256; j++) {
        unsigned short* out = AB + ((size_t)h * 256 + j) * KBIG;
        float v = (t <= j) ? kf[j - t] : kb[t - j - 1];
        if (t == j) v += dsk;
        out[t] = f2bf(v);
        if (t < 128) {
            int n = (t & 63) >> 1, reim = t & 1;
            float2 c = (t < 64) ? ce_s[n] : ce_s[32 + n];
            float2 wv = (t < 64) ? wpow[n][j + 1] : wpow[n][255 - j];
            float re = c.x * wv.x - c.y * wv.y;
            float im = c.x * wv.y + c.y * wv.x;
            out[256 + t] = f2bf(reim ? -2.f * im : 2.f * re);
        }
    }
    for (int r = 0; r < 128; r++) {
        int n = (r & 63) >> 1, reim = r & 1, dir = r >> 6;
        float2 wv = wpow[n][dir ? t : 255 - t];
        Wp[((size_t)h * 128 + r) * 256 + t] = f2bf(reim ? wv.y : wv.x);
    }
}

// ---------------- fused layernorm + transpose: x (b,l,h) fp32 -> UT (b,h,l) bf16 ----------------
__global__ __launch_bounds__(256) void k_lntr(const float* __restrict__ x,
                                              const float* __restrict__ g,
                                              const float* __restrict__ bt,
                                              unsigned short* __restrict__ UT) {
    __shared__ unsigned short lds[256][65];
    int lt = blockIdx.x, b = blockIdx.y;
    int t = threadIdx.x;
    int lane = t & 63, w = t >> 6;
    float4 gg = ((const float4*)g)[lane];
    float4 bb = ((const float4*)bt)[lane];
#pragma unroll
    for (int q = 0; q < 16; q++) {
        int l = q * 4 + w;
        float4 v = ((const float4*)(x + ((size_t)(b * LL + lt * 64 + l)) * Hdim))[lane];
        float s = v.x + v.y + v.z + v.w;
        float ss = v.x * v.x + v.y * v.y + v.z * v.z + v.w * v.w;
#pragma unroll
        for (int o = 1; o < 64; o <<= 1) { s += __shfl_xor(s, o, 64); ss += __shfl_xor(ss, o, 64); }
        float mean = s * (1.0f / Hdim);
        float var = ss * (1.0f / Hdim) - mean * mean;
        float rstd = rsqrtf(var + 1e-5f);
        lds[lane * 4 + 0][l] = f2bf((v.x - mean) * rstd * gg.x + bb.x);
        lds[lane * 4 + 1][l] = f2bf((v.y - mean) * rstd * gg.y + bb.y);
        lds[lane * 4 + 2][l] = f2bf((v.z - mean) * rstd * gg.z + bb.z);
        lds[lane * 4 + 3][l] = f2bf((v.w - mean) * rstd * gg.w + bb.w);
    }
    __syncthreads();
    for (int q = 0; q < 64; q++) {
        int idx = q * 256 + t;
        int hh = idx >> 6, ll = idx & 63;
        UT[((size_t)(b * Hdim + hh)) * LL + lt * 64 + ll] = lds[hh][ll];
    }
}

// ---------------- layernorm (bf16 in, bf16 out): T2 = LN(X2) ----------------
__global__ void k_ln_bf(const unsigned short* __restrict__ x, const float* __restrict__ g,
                        const float* __restrict__ bt, unsigned short* __restrict__ out) {
    int row = blockIdx.x * 4 + (threadIdx.x >> 6);
    int lane = threadIdx.x & 63;
    ushort4 u4 = ((const ushort4*)(x + (size_t)row * Hdim))[lane];
    float vx = bf2f(u4.x), vy = bf2f(u4.y), vz = bf2f(u4.z), vw = bf2f(u4.w);
    float s = vx + vy + vz + vw;
    float ss = vx * vx + vy * vy + vz * vz + vw * vw;
#pragma unroll
    for (int o = 1; o < 64; o <<= 1) { s += __shfl_xor(s, o, 64); ss += __shfl_xor(ss, o, 64); }
    float mean = s * (1.0f / Hdim);
    float var = ss * (1.0f / Hdim) - mean * mean;
    float rstd = rsqrtf(var + 1e-5f);
    float4 gg = ((const float4*)g)[lane];
    float4 bb = ((const float4*)bt)[lane];
    ushort4 o;
    o.x = f2bf((vx - mean) * rstd * gg.x + bb.x);
    o.y = f2bf((vy - mean) * rstd * gg.y + bb.y);
    o.z = f2bf((vz - mean) * rstd * gg.z + bb.z);
    o.w = f2bf((vw - mean) * rstd * gg.w + bb.w);
    ((ushort4*)(out + (size_t)row * Hdim))[lane] = o;
}

// ---------------- state GEMM (LDS-staged, swizzled): Zg[h][bc][r], 256x128 per h ----------------
__global__ __launch_bounds__(512) void k_zgemm(const unsigned short* __restrict__ UT,
                                               const unsigned short* __restrict__ Wp,
                                               float* __restrict__ Zg) {
    __shared__ unsigned short As[256 * 64];
    __shared__ unsigned short Bs[128 * 64];
    int h = blockIdx.x;
    int t = threadIdx.x;
    int w = t >> 6, lane = t & 63;
    int m0 = (w & 3) * 64;     // 4 row groups
    int nb = (w >> 2) * 64;    // 2 col groups
    int lr = lane & 15, lk = (lane >> 4) * 8;
    f32x4 acc[4][4];
#pragma unroll
    for (int i = 0; i < 4; i++)
#pragma unroll
        for (int jx = 0; jx < 4; jx++) acc[i][jx] = (f32x4){0.f, 0.f, 0.f, 0.f};
    for (int k0 = 0; k0 < 256; k0 += 64) {
        stageUT<256, 512>(UT, h, 0, k0, As, t);
        stage64<128, 512>(Wp + (size_t)h * 128 * 256, 256, k0, Bs, t);
        __syncthreads();
#pragma unroll
        for (int kk = 0; kk < 64; kk += 32) {
            bf16x8 a[4], b[4];
#pragma unroll
            for (int mi = 0; mi < 4; mi++) a[mi] = fr(As, m0 + mi * 16 + lr, kk + lk);
#pragma unroll
            for (int nf = 0; nf < 4; nf++) b[nf] = fr(Bs, nb + nf * 16 + lr, kk + lk);
#pragma unroll
            for (int mi = 0; mi < 4; mi++)
#pragma unroll
                for (int nf = 0; nf < 4; nf++)
                    acc[mi][nf] = __builtin_amdgcn_mfma_f32_16x16x32_bf16(a[mi], b[nf], acc[mi][nf], 0, 0, 0);
        }
        __syncthreads();
    }
#pragma unroll
    for (int mi = 0; mi < 4; mi++)
#pragma unroll
        for (int nf = 0; nf < 4; nf++) {
            int col = nb + nf * 16 + lr;
#pragma unroll
            for (int r = 0; r < 4; r++) {
                int row = m0 + mi * 16 + (lane >> 4) * 4 + r;
                Zg[((size_t)h * 256 + row) * 128 + col] = acc[mi][nf][r];
            }
        }
}

// ---------------- prefix over chunks -> Zpacked bf16 [h][bc][128] ----------------
__global__ void k_prefix2(const float* __restrict__ Zg, const float2* __restrict__ wptab,
                          unsigned short* __restrict__ ZP) {
    int t = blockIdx.x * 256 + threadIdx.x;
    int n = t & 31;
    int h = (t >> 5) & 255;
    int b = (t >> 13) & 15;
    int dir = (t >> 17) & 1;
    float2 wp = wptab[h * NM + n];
    float sr = 0.f, si = 0.f;
    int ro = dir ? 64 + 2 * n : 2 * n;
    if (dir == 0) {
        for (int c = 0; c < NCH; c++) {
            size_t base = ((size_t)h * 256 + b * NCH + c) * 128;
            ZP[base + ro] = f2bf(sr);
            ZP[base + ro + 1] = f2bf(si);
            float zr = Zg[base + ro], zi = Zg[base + ro + 1];
            float nr = fmaf(wp.x, sr, fmaf(-wp.y, si, zr));
            float ni = fmaf(wp.y, sr, fmaf(wp.x, si, zi));
            sr = nr; si = ni;
        }
    } else {
        for (int c = NCH - 1; c >= 0; c--) {
            size_t base = ((size_t)h * 256 + b * NCH + c) * 128;
            ZP[base + ro] = f2bf(sr);
            ZP[base + ro + 1] = f2bf(si);
            float zr = Zg[base + ro], zi = Zg[base + ro + 1];
            float nr = fmaf(wp.x, sr, fmaf(-wp.y, si, zr));
            float ni = fmaf(wp.y, sr, fmaf(wp.x, si, zi));
            sr = nr; si = ni;
        }
    }
}

// ---------------- conv GEMM (LDS-staged, swizzled): Yt[h][bc][j], tile 128bc x 256j ----------------
__global__ __launch_bounds__(512) void k_conv(const unsigned short* __restrict__ UT,
                                              const unsigned short* __restrict__ ZP,
                                              const unsigned short* __restrict__ AB,
                                              unsigned short* __restrict__ Yt) {
    __shared__ unsigned short As[128 * 64];
    __shared__ unsigned short Bs[256 * 64];
    // XCD-chunked swizzle (512 blocks, 512%8==0 -> bijective)
    int wgid = ((int)blockIdx.x % 8) * 64 + (int)blockIdx.x / 8;
    int h = wgid >> 1;
    int mbase = (wgid & 1) * 128;
    int t = threadIdx.x;
    int w = t >> 6, lane = t & 63;
    int m0 = (w & 1) * 64;     // 2 row groups
    int nb = (w >> 1) * 64;    // 4 col groups (full 256 j)
    int lr = lane & 15, lk = (lane >> 4) * 8;
    const unsigned short* ABh = AB + (size_t)h * 256 * KBIG;
    f32x4 acc[4][4];
#pragma unroll
    for (int i = 0; i < 4; i++)
#pragma unroll
        for (int jx = 0; jx < 4; jx++) acc[i][jx] = (f32x4){0.f, 0.f, 0.f, 0.f};
    // u-part: K = 256
    for (int k0 = 0; k0 < 256; k0 += 64) {
        stageUT<128, 512>(UT, h, mbase, k0, As, t);
        stage64<256, 512>(ABh, KBIG, k0, Bs, t);
        __syncthreads();
#pragma unroll
        for (int kk = 0; kk < 64; kk += 32) {
            bf16x8 a[4], b[4];
#pragma unroll
            for (int mi = 0; mi < 4; mi++) a[mi] = fr(As, m0 + mi * 16 + lr, kk + lk);
#pragma unroll
            for (int nf = 0; nf < 4; nf++) b[nf] = fr(Bs, nb + nf * 16 + lr, kk + lk);
#pragma unroll
            for (int mi = 0; mi < 4; mi++)
#pragma unroll
                for (int nf = 0; nf < 4; nf++)
                    acc[mi][nf] = __builtin_amdgcn_mfma_f32_16x16x32_bf16(a[mi], b[nf], acc[mi][nf], 0, 0, 0);
        }
        __syncthreads();
    }
    // z-part: K = 128 from ZP, AB cols 256..383
    for (int k0 = 0; k0 < 128; k0 += 64) {
        stage64<128, 512>(ZP + ((size_t)h * 256 + mbase) * 128, 128, k0, As, t);
        stage64<256, 512>(ABh + 256, KBIG, k0, Bs, t);
        __syncthreads();
#pragma unroll
        for (int kk = 0; kk < 64; kk += 32) {
            bf16x8 a[4], b[4];
#pragma unroll
            for (int mi = 0; mi < 4; mi++) a[mi] = fr(As, m0 + mi * 16 + lr, kk + lk);
#pragma unroll
            for (int nf = 0; nf < 4; nf++) b[nf] = fr(Bs, nb + nf * 16 + lr, kk + lk);
#pragma unroll
            for (int mi = 0; mi < 4; mi++)
#pragma unroll
                for (int nf = 0; nf < 4; nf++)
                    acc[mi][nf] = __builtin_amdgcn_mfma_f32_16x16x32_bf16(a[mi], b[nf], acc[mi][nf], 0, 0, 0);
        }
        __syncthreads();
    }
#pragma unroll
    for (int mi = 0; mi < 4; mi++)
#pragma unroll
        for (int nf = 0; nf < 4; nf++) {
            int col = nb + nf * 16 + lr;
#pragma unroll
            for (int r = 0; r < 4; r++) {
                int row = mbase + m0 + mi * 16 + (lane >> 4) * 4 + r;
                Yt[(size_t)h * 65536 + row * 256 + col] = f2bf(gelu_f(acc[mi][nf][r]));
            }
        }
}

// ---------------- transpose Yt [h][bc][j] -> G (b, c*P+j, h) bf16 ----------------
__global__ void k_trg(const unsigned short* __restrict__ Yt, unsigned short* __restrict__ G) {
    __shared__ unsigned short lds[64][65];
    int bc = blockIdx.x;
    int h0 = blockIdx.y * 64, j0 = blockIdx.z * 64;
    int t = threadIdx.x;
#pragma unroll
    for (int q = 0; q < 16; q++) {
        int idx = q * 256 + t;
        int hh = idx >> 6, jj = idx & 63;
        lds[hh][jj] = Yt[(size_t)(h0 + hh) * 65536 + bc * 256 + j0 + jj];
    }
    __syncthreads();
    int b = bc >> 4, c = bc & 15;
#pragma unroll
    for (int q = 0; q < 16; q++) {
        int idx = q * 256 + t;
        int jj = idx >> 6, hh = idx & 63;
        G[((size_t)(b * LL + c * PCH + j0 + jj)) * Hdim + h0 + hh] = lds[hh][jj];
    }
}

// ---------------- GEMM1 (LDS-staged, swizzled): X2 = bf16(x + glu(G@Wout + bo)) ----------------
__global__ __launch_bounds__(256) void k_gemm1(const unsigned short* __restrict__ Gm,
                                               const unsigned short* __restrict__ W1T,
                                               const float* __restrict__ bo,
                                               const float* __restrict__ xin,
                                               unsigned short* __restrict__ X2) {
    __shared__ unsigned short As[128 * 64];
    __shared__ unsigned short BsA[64 * 64];
    __shared__ unsigned short BsB[64 * 64];
    int t = threadIdx.x;
    int w = t >> 6, lane = t & 63;
    int m0w = (w & 1) * 64, n0w = (w >> 1) * 32;
    int lr = lane & 15, lk = (lane >> 4) * 8;
    int mblk = blockIdx.x * 128, nblk = blockIdx.y * 64;
    const unsigned short* Ab  = Gm + (size_t)mblk * 256;
    const unsigned short* BbA = W1T + (size_t)nblk * 256;
    const unsigned short* BbB = W1T + (size_t)(nblk + 256) * 256;
    f32x4 acc[4][4];
#pragma unroll
    for (int i = 0; i < 4; i++)
#pragma unroll
        for (int j = 0; j < 4; j++) acc[i][j] = (f32x4){0.f, 0.f, 0.f, 0.f};
    for (int k0 = 0; k0 < 256; k0 += 64) {
        stage64<128, 256>(Ab, 256, k0, As, t);
        stage64<64, 256>(BbA, 256, k0, BsA, t);
        stage64<64, 256>(BbB, 256, k0, BsB, t);
        __syncthreads();
#pragma unroll
        for (int kk = 0; kk < 64; kk += 32) {
            bf16x8 a[4], bA[2], bB[2];
#pragma unroll
            for (int mi = 0; mi < 4; mi++)
                a[mi] = fr(As, m0w + mi * 16 + lr, kk + lk);
#pragma unroll
            for (int nf = 0; nf < 2; nf++) {
                bA[nf] = fr(BsA, n0w + nf * 16 + lr, kk + lk);
                bB[nf] = fr(BsB, n0w + nf * 16 + lr, kk + lk);
            }
#pragma unroll
            for (int mi = 0; mi < 4; mi++)
#pragma unroll
                for (int nf = 0; nf < 2; nf++) {
                    acc[mi][nf] = __builtin_amdgcn_mfma_f32_16x16x32_bf16(a[mi], bA[nf], acc[mi][nf], 0, 0, 0);
                    acc[mi][nf + 2] = __builtin_amdgcn_mfma_f32_16x16x32_bf16(a[mi], bB[nf], acc[mi][nf + 2], 0, 0, 0);
                }
        }
        __syncthreads();
    }
#pragma unroll
    for (int mi = 0; mi < 4; mi++)
#pragma unroll
        for (int nf = 0; nf < 2; nf++) {
            int col = nblk + n0w + nf * 16 + lr;
            float biasA = bo[col], biasB = bo[col + 256];
#pragma unroll
            for (int r = 0; r < 4; r++) {
                int row = mblk + m0w + mi * 16 + (lane >> 4) * 4 + r;
                float zzA = acc[mi][nf][r] + biasA;
                float zzB = acc[mi][nf + 2][r] + biasB;
                float v = zzA * __builtin_amdgcn_rcpf(1.0f + __expf(-zzB));
                size_t idx = (size_t)row * 256 + col;
                X2[idx] = f2bf(xin[idx] + v);
            }
        }
}

// ---------------- GEMM2 (LDS-staged, swizzled): M = gelu(T2@W2 + b2) bf16 ----------------
__global__ __launch_bounds__(256) void k_gemm2(const unsigned short* __restrict__ T2,
                                               const unsigned short* __restrict__ W2T,
                                               const float* __restrict__ b2,
                                               unsigned short* __restrict__ Mo) {
    __shared__ unsigned short As[128 * 64];
    __shared__ unsigned short Bs[128 * 64];
    int t = threadIdx.x;
    int w = t >> 6, lane = t & 63;
    int m0w = (w & 1) * 64, n0w = (w >> 1) * 64;
    int lr = lane & 15, lk = (lane >> 4) * 8;
    int mblk = blockIdx.x * 128, nblk = blockIdx.y * 128;
    const unsigned short* Ab = T2 + (size_t)mblk * 256;
    const unsigned short* Bb = W2T + (size_t)nblk * 256;
    f32x4 acc[4][4];
#pragma unroll
    for (int i = 0; i < 4; i++)
#pragma unroll
        for (int j = 0; j < 4; j++) acc[i][j] = (f32x4){0.f, 0.f, 0.f, 0.f};
    for (int k0 = 0; k0 < 256; k0 += 64) {
        stage64<128, 256>(Ab, 256, k0, As, t);
        stage64<128, 256>(Bb, 256, k0, Bs, t);
        __syncthreads();
#pragma unroll
        for (int kk = 0; kk < 64; kk += 32) {
            bf16x8 a[4], b[4];
#pragma unroll
            for (int mi = 0; mi < 4; mi++)
                a[mi] = fr(As, m0w + mi * 16 + lr, kk + lk);
#pragma unroll
            for (int nf = 0; nf < 4; nf++)
                b[nf] = fr(Bs, n0w + nf * 16 + lr, kk + lk);
#pragma unroll
            for (int mi = 0; mi < 4; mi++)
#pragma unroll
                for (int nf = 0; nf < 4; nf++)
                    acc[mi][nf] = __builtin_amdgcn_mfma_f32_16x16x32_bf16(a[mi], b[nf], acc[mi][nf], 0, 0, 0);
        }
        __syncthreads();
    }
#pragma unroll
    for (int mi = 0; mi < 4; mi++)
#pragma unroll
        for (int nf = 0; nf < 4; nf++) {
            int col = nblk + n0w + nf * 16 + lr;
            float bias = b2[col];
#pragma unroll
            for (int r = 0; r < 4; r++) {
                int row = mblk + m0w + mi * 16 + (lane >> 4) * 4 + r;
                Mo[(size_t)row * 512 + col] = f2bf(gelu_f(acc[mi][nf][r] + bias));
            }
        }
}

// ---------------- GEMM3 (LDS-staged, swizzled): out = X2 + M@W3 + b3 ----------------
__global__ __launch_bounds__(256) void k_gemm3(const unsigned short* __restrict__ Mb,
                                               const unsigned short* __restrict__ W3T,
                                               const float* __restrict__ b3,
                                               const unsigned short* __restrict__ X2,
                                               float* __restrict__ out) {
    __shared__ unsigned short As[128 * 64];
    __shared__ unsigned short Bs[128 * 64];
    int t = threadIdx.x;
    int w = t >> 6, lane = t & 63;
    int m0w = (w & 1) * 64, n0w = (w >> 1) * 64;
    int lr = lane & 15, lk = (lane >> 4) * 8;
    int mblk = blockIdx.x * 128, nblk = blockIdx.y * 128;
    const unsigned short* Ab = Mb + (size_t)mblk * 512;
    const unsigned short* Bb = W3T + (size_t)nblk * 512;
    f32x4 acc[4][4];
#pragma unroll
    for (int i = 0; i < 4; i++)
#pragma unroll
        for (int j = 0; j < 4; j++) acc[i][j] = (f32x4){0.f, 0.f, 0.f, 0.f};
    for (int k0 = 0; k0 < 512; k0 += 64) {
        stage64<128, 256>(Ab, 512, k0, As, t);
        stage64<128, 256>(Bb, 512, k0, Bs, t);
        __syncthreads();
#pragma unroll
        for (int kk = 0; kk < 64; kk += 32) {
            bf16x8 a[4], b[4];
#pragma unroll
            for (int mi = 0; mi < 4; mi++)
                a[mi] = fr(As, m0w + mi * 16 + lr, kk + lk);
#pragma unroll
            for (int nf = 0; nf < 4; nf++)
                b[nf] = fr(Bs, n0w + nf * 16 + lr, kk + lk);
#pragma unroll
            for (int mi = 0; mi < 4; mi++)
#pragma unroll
                for (int nf = 0; nf < 4; nf++)
                    acc[mi][nf] = __builtin_amdgcn_mfma_f32_16x16x32_bf16(a[mi], b[nf], acc[mi][nf], 0, 0, 0);
        }
        __syncthreads();
    }
#pragma unroll
    for (int mi = 0; mi < 4; mi++)
#pragma unroll
        for (int nf = 0; nf < 4; nf++) {
            int col = nblk + n0w + nf * 16 + lr;
            float bias = b3[col];
#pragma unroll
            for (int r = 0; r < 4; r++) {
                int row = mblk + m0w + mi * 16 + (lane >> 4) * 4 + r;
                size_t idx = (size_t)row * 256 + col;
                out[idx] = bf2f(X2[idx]) + acc[mi][nf][r] + bias;
            }
        }
}

extern "C" void kernel_launch(void* const* d_in, const int* in_sizes, int n_in,
                              void* d_out, int out_size, void* d_ws, size_t ws_size,
                              hipStream_t stream) {
    const float* x     = (const float*)d_in[0];
    const float* ln1g  = (const float*)d_in[1];
    const float* ln1b  = (const float*)d_in[2];
    const float* ln2g  = (const float*)d_in[3];
    const float* ln2b  = (const float*)d_in[4];
    const float* logdt = (const float*)d_in[5];
    const float* Are   = (const float*)d_in[6];
    const float* Aim   = (const float*)d_in[7];
    const float* Cre   = (const float*)d_in[8];
    const float* Cim   = (const float*)d_in[9];
    const float* Dsk   = (const float*)d_in[10];
    const float* Wout  = (const float*)d_in[11];
    const float* bo    = (const float*)d_in[12];
    const float* W2    = (const float*)d_in[13];
    const float* b2    = (const float*)d_in[14];
    const float* W3    = (const float*)d_in[15];
    const float* b3    = (const float*)d_in[16];

    char* ws = (char*)d_ws;
    unsigned short* AB   = (unsigned short*)(ws + OFF_ABIG);
    unsigned short* Wp   = (unsigned short*)(ws + OFF_WPM);
    unsigned short* X2   = (unsigned short*)(ws + OFF_ABIG);   // bf16, after AB is dead
    unsigned short* UT   = (unsigned short*)(ws + OFF_UT);
    float*          Zg   = (float*)(ws + OFF_ZG);
    unsigned short* Yt   = (unsigned short*)(ws + OFF_ZG);
    unsigned short* Mb   = (unsigned short*)(ws + OFF_M);
    unsigned short* ZP   = (unsigned short*)(ws + OFF_ZP);
    unsigned short* G    = (unsigned short*)(ws + OFF_G);
    float2*         WT   = (float2*)(ws + OFF_WTAB);
    float2*         WPT  = (float2*)(ws + OFF_WPT);
    float2*         CE   = (float2*)(ws + OFF_CE);
    unsigned short* W1T  = (unsigned short*)(ws + OFF_W1T);
    unsigned short* W2T  = (unsigned short*)(ws + OFF_W2T);
    unsigned short* W3T  = (unsigned short*)(ws + OFF_W3T);

    k_tab<<<32, 256, 0, stream>>>(logdt, Are, Aim, Cre, Cim, WT, WPT, CE);
    k_wt<<<512, 256, 0, stream>>>(Wout, W2, W3, W1T, W2T, W3T);
    k_lntr<<<dim3(64, 16), 256, 0, stream>>>(x, ln1g, ln1b, UT);
    k_abw<<<256, 256, 0, stream>>>(logdt, Are, Aim, CE, Dsk, AB, Wp);
    k_zgemm<<<256, 512, 0, stream>>>(UT, Wp, Zg);
    k_prefix2<<<1024, 256, 0, stream>>>(Zg, WPT, ZP);
    k_conv<<<512, 512, 0, stream>>>(UT, ZP, AB, Yt);
    k_trg<<<dim3(256, 4, 4), 256, 0, stream>>>(Yt, G);
    k_gemm1<<<dim3(512, 4), 256, 0, stream>>>(G, W1T, bo, x, X2);
    k_ln_bf<<<NB * LL / 4, 256, 0, stream>>>(X2, ln2g, ln2b, G);
    k_gemm2<<<dim3(512, 4), 256, 0, stream>>>(G, W2T, b2, Mb);
    k_gemm3<<<dim3(512, 2), 256, 0, stream>>>(Mb, W3T, b3, X2, (float*)d_out);
}

// Round 13
// 258.064 us; speedup vs baseline: 1.3616x; 1.1345x over previous
//
#include <hip/hip_runtime.h>
#include <hip/hip_bf16.h>

typedef __attribute__((ext_vector_type(8))) short bf16x8;
typedef __attribute__((ext_vector_type(4))) float f32x4;

#define Hdim 256
#define NM 32      // N2 modes
#define NB 16      // batch
#define LL 4096    // seq len
#define PCH 256    // chunk length
#define NCH 16     // chunks = LL/PCH
#define KBIG 384   // conv GEMM K: 256 u + 64 zf + 64 zb

// ---- workspace layout (bytes), total 186,122,240 ----
#define OFF_ABIG ((size_t)0)
#define OFF_WPM  ((size_t)50331648)
#define OFF_UT   ((size_t)67108864)    // U_T bf16 [B][H][L] 33554432
#define OFF_ZG   ((size_t)100663296)   // Zg fp32 [h][bc][128] ; then Yt bf16
#define OFF_M    ((size_t)67108864)    // M bf16 (spans UT+ZG, alive gemm2->gemm3)
#define OFF_ZP   ((size_t)134217728)   // Zpacked bf16 [h][bc][128]
#define OFF_G    ((size_t)150994944)   // G bf16 (b,l,h) ; reused as T2
#define OFF_WTAB ((size_t)185073664)
#define OFF_WPT  ((size_t)185139200)
#define OFF_CE   ((size_t)185204736)
#define OFF_W1T  ((size_t)185335808)
#define OFF_W2T  ((size_t)185597952)
#define OFF_W3T  ((size_t)185860096)

typedef const __attribute__((address_space(1))) void* gas_p;
typedef __attribute__((address_space(3))) void* las_p;

// fast gelu: tanh form via hardware exp + rcp (max abs err ~1e-3 vs erf form)
__device__ __forceinline__ float gelu_f(float v) {
    float u = 0.7978845608028654f * fmaf(0.044715f * v * v, v, v);
    float uc = fminf(fmaxf(u, -15.f), 15.f);
    float e = __expf(2.f * uc);
    return 0.5f * v * (1.f + (e - 1.f) * __builtin_amdgcn_rcpf(e + 1.f));
}
__device__ __forceinline__ unsigned short f2bf(float f) {  // RNE f32->bf16
    unsigned int u = __float_as_uint(f);
    u += 0x7fffu + ((u >> 16) & 1u);
    return (unsigned short)(u >> 16);
}
__device__ __forceinline__ float bf2f(unsigned short u) {
    return __uint_as_float((unsigned int)u << 16);
}

// swizzled fragment read from a [R][64] tile: XOR 16B-block index with (row&7).
__device__ __forceinline__ bf16x8 fr(const unsigned short* lds, int row, int kcol) {
    return *(const bf16x8*)(lds + row * 64 + ((((kcol >> 3) ^ (row & 7)) << 3)));
}

// stage ROWS x 64 bf16 tile (row-major, ld elems) into LDS [ROWS][64] (linear dest,
// inverse-swizzled source)
template<int ROWS, int THREADS>
__device__ __forceinline__ void stage64(const unsigned short* __restrict__ src, int ld, int k0,
                                        unsigned short* lds, int t) {
    constexpr int EPI = THREADS * 8;   // elems per iter
#pragma unroll
    for (int i = 0; i < (ROWS * 64) / EPI; i++) {
        int e = i * EPI + t * 8;
        int r = e >> 6;
        int k = (((e >> 3) & 7) ^ (r & 7)) << 3;
        const unsigned short* g = src + (size_t)r * ld + (k0 + k);
        unsigned short* l = lds + i * EPI + (t >> 6) * 512;   // wave-uniform base
        __builtin_amdgcn_global_load_lds((gas_p)g, (las_p)l, 16, 0, 0);
    }
}

// stage ROWS x 64 tile of UT (bc-rows) for head h, same swizzle
template<int ROWS, int THREADS>
__device__ __forceinline__ void stageUT(const unsigned short* __restrict__ UT, int h, int rbase,
                                        int k0, unsigned short* lds, int t) {
    constexpr int EPI = THREADS * 8;
#pragma unroll
    for (int i = 0; i < (ROWS * 64) / EPI; i++) {
        int e = i * EPI + t * 8;
        int r = e >> 6;
        int k = (((e >> 3) & 7) ^ (r & 7)) << 3;
        int row = rbase + r;
        const unsigned short* g = UT + ((size_t)((row >> 4) * Hdim + h)) * LL
                                  + (row & 15) * PCH + (k0 + k);
        unsigned short* l = lds + i * EPI + (t >> 6) * 512;
        __builtin_amdgcn_global_load_lds((gas_p)g, (las_p)l, 16, 0, 0);
    }
}

// ---------------- tables ----------------
__global__ void k_tab(const float* __restrict__ logdt, const float* __restrict__ Are,
                      const float* __restrict__ Aim, const float* __restrict__ Cre,
                      const float* __restrict__ Cim, float2* __restrict__ wtab,
                      float2* __restrict__ wptab, float2* __restrict__ ceff) {
    int idx = blockIdx.x * blockDim.x + threadIdx.x;
    if (idx >= Hdim * NM) return;
    int h = idx >> 5;
    float dt = expf(logdt[h]);
    double dar = (double)dt * (double)Are[idx];
    double dai = (double)dt * (double)Aim[idx];
    double wm = exp(dar);
    double wr = wm * cos(dai), wi = wm * sin(dai);
    wtab[idx] = make_float2((float)wr, (float)wi);
    double pm = exp(dar * (double)PCH);
    double pai = dai * (double)PCH;
    wptab[idx] = make_float2((float)(pm * cos(pai)), (float)(pm * sin(pai)));
    double are = (double)Are[idx], aim = (double)Aim[idx];
    double den = are * are + aim * aim;
    double nr = wr - 1.0, ni = wi;
    double qr = (nr * are + ni * aim) / den;
    double qi = (ni * are - nr * aim) / den;
    for (int ch = 0; ch < 2; ch++) {
        double cr = (double)Cre[ch * Hdim * NM + idx];
        double ci = (double)Cim[ch * Hdim * NM + idx];
        ceff[ch * Hdim * NM + idx] = make_float2((float)(cr * qr - ci * qi),
                                                 (float)(cr * qi + ci * qr));
    }
}

// ---------------- weight transpose + bf16 cast ----------------
__global__ void k_wt(const float* __restrict__ W1, const float* __restrict__ W2,
                     const float* __restrict__ W3, unsigned short* __restrict__ W1T,
                     unsigned short* __restrict__ W2T, unsigned short* __restrict__ W3T) {
    int t = blockIdx.x * 256 + threadIdx.x;  // 131072 threads
    int k = t >> 9, n = t & 511;             // W1,W2: [256][512]
    W1T[n * 256 + k] = f2bf(W1[t]);
    W2T[n * 256 + k] = f2bf(W2[t]);
    int k3 = t >> 8, n3 = t & 255;           // W3: [512][256]
    W3T[n3 * 512 + k3] = f2bf(W3[t]);
}

// ---------------- merged: wpow table -> kf/kb -> Abig rows -> Wp rows ----------------
__global__ __launch_bounds__(256) void k_abw(const float* __restrict__ logdt,
                                             const float* __restrict__ Are,
                                             const float* __restrict__ Aim,
                                             const float2* __restrict__ CE,
                                             const float* __restrict__ Dsk,
                                             unsigned short* __restrict__ AB,
                                             unsigned short* __restrict__ Wp) {
    __shared__ float2 wpow[32][257];   // w^j, j=0..256
    __shared__ float kf[256], kb[256];
    __shared__ float2 ce_s[64];        // [0..31] fwd, [32..63] bwd
    int h = blockIdx.x;
    int t = threadIdx.x;
    if (t < 64) ce_s[t] = CE[(t >> 5) * (Hdim * NM) + h * NM + (t & 31)];
    {   // build wpow: thread = n*8+seg, 32-step recurrence from w^(32*seg)
        int n = t >> 3, seg = t & 7;
        float dt = expf(logdt[h]);
        float dar = dt * Are[h * NM + n], dai = dt * Aim[h * NM + n];
        float em = expf(dar);
        float wr = em * cosf(dai), wi = em * sinf(dai);
        int j0 = seg * 32;
        float m = expf((float)j0 * dar), ang = (float)j0 * dai;
        float vr = m * cosf(ang), vi = m * sinf(ang);
        for (int q = 0; q < 32; q++) {
            wpow[n][j0 + q] = make_float2(vr, vi);
            float nr2 = vr * wr - vi * wi;
            float ni2 = vr * wi + vi * wr;
            vr = nr2; vi = ni2;
        }
        if (seg == 7) wpow[n][256] = make_float2(vr, vi);
    }
    __syncthreads();
    {   // conv kernels kf[d], kb[d] (lane = d)
        float kfv = 0.f, kbv = 0.f;
#pragma unroll
        for (int n = 0; n < NM; n++) {
            float2 wv = wpow[n][t];
            float2 cf = ce_s[n], cb = ce_s[32 + n];
            kfv = fmaf(cf.x, wv.x, fmaf(-cf.y, wv.y, kfv));
            kbv = fmaf(cb.x, wv.x, fmaf(-cb.y, wv.y, kbv));
        }
        kf[t] = 2.f * kfv;
        kb[t] = 2.f * kbv;
    }
    __syncthreads();
    float dsk = Dsk[h];
    for (int j = 0; j < 256; j++) {
        unsigned short* out = AB + ((size_t)h * 256 + j) * KBIG;
        float v = (t <= j) ? kf[j - t] : kb[t - j - 1];
        if (t == j) v += dsk;
        out[t] = f2bf(v);
        if (t < 128) {
            int n = (t & 63) >> 1, reim = t & 1;
            float2 c = (t < 64) ? ce_s[n] : ce_s[32 + n];
            float2 wv = (t < 64) ? wpow[n][j + 1] : wpow[n][255 - j];
            float re = c.x * wv.x - c.y * wv.y;
            float im = c.x * wv.y + c.y * wv.x;
            out[256 + t] = f2bf(reim ? -2.f * im : 2.f * re);
        }
    }
    for (int r = 0; r < 128; r++) {
        int n = (r & 63) >> 1, reim = r & 1, dir = r >> 6;
        float2 wv = wpow[n][dir ? t : 255 - t];
        Wp[((size_t)h * 128 + r) * 256 + t] = f2bf(reim ? wv.y : wv.x);
    }
}

// ---------------- fused layernorm + transpose: x (b,l,h) fp32 -> UT (b,h,l) bf16 ----------------
__global__ __launch_bounds__(256) void k_lntr(const float* __restrict__ x,
                                              const float* __restrict__ g,
                                              const float* __restrict__ bt,
                                              unsigned short* __restrict__ UT) {
    __shared__ unsigned short lds[256][65];
    int lt = blockIdx.x, b = blockIdx.y;
    int t = threadIdx.x;
    int lane = t & 63, w = t >> 6;
    float4 gg = ((const float4*)g)[lane];
    float4 bb = ((const float4*)bt)[lane];
#pragma unroll
    for (int q = 0; q < 16; q++) {
        int l = q * 4 + w;
        float4 v = ((const float4*)(x + ((size_t)(b * LL + lt * 64 + l)) * Hdim))[lane];
        float s = v.x + v.y + v.z + v.w;
        float ss = v.x * v.x + v.y * v.y + v.z * v.z + v.w * v.w;
#pragma unroll
        for (int o = 1; o < 64; o <<= 1) { s += __shfl_xor(s, o, 64); ss += __shfl_xor(ss, o, 64); }
        float mean = s * (1.0f / Hdim);
        float var = ss * (1.0f / Hdim) - mean * mean;
        float rstd = rsqrtf(var + 1e-5f);
        lds[lane * 4 + 0][l] = f2bf((v.x - mean) * rstd * gg.x + bb.x);
        lds[lane * 4 + 1][l] = f2bf((v.y - mean) * rstd * gg.y + bb.y);
        lds[lane * 4 + 2][l] = f2bf((v.z - mean) * rstd * gg.z + bb.z);
        lds[lane * 4 + 3][l] = f2bf((v.w - mean) * rstd * gg.w + bb.w);
    }
    __syncthreads();
    for (int q = 0; q < 64; q++) {
        int idx = q * 256 + t;
        int hh = idx >> 6, ll = idx & 63;
        UT[((size_t)(b * Hdim + hh)) * LL + lt * 64 + ll] = lds[hh][ll];
    }
}

// ---------------- layernorm (bf16 in, bf16 out): T2 = LN(X2) ----------------
__global__ void k_ln_bf(const unsigned short* __restrict__ x, const float* __restrict__ g,
                        const float* __restrict__ bt, unsigned short* __restrict__ out) {
    int row = blockIdx.x * 4 + (threadIdx.x >> 6);
    int lane = threadIdx.x & 63;
    ushort4 u4 = ((const ushort4*)(x + (size_t)row * Hdim))[lane];
    float vx = bf2f(u4.x), vy = bf2f(u4.y), vz = bf2f(u4.z), vw = bf2f(u4.w);
    float s = vx + vy + vz + vw;
    float ss = vx * vx + vy * vy + vz * vz + vw * vw;
#pragma unroll
    for (int o = 1; o < 64; o <<= 1) { s += __shfl_xor(s, o, 64); ss += __shfl_xor(ss, o, 64); }
    float mean = s * (1.0f / Hdim);
    float var = ss * (1.0f / Hdim) - mean * mean;
    float rstd = rsqrtf(var + 1e-5f);
    float4 gg = ((const float4*)g)[lane];
    float4 bb = ((const float4*)bt)[lane];
    ushort4 o;
    o.x = f2bf((vx - mean) * rstd * gg.x + bb.x);
    o.y = f2bf((vy - mean) * rstd * gg.y + bb.y);
    o.z = f2bf((vz - mean) * rstd * gg.z + bb.z);
    o.w = f2bf((vw - mean) * rstd * gg.w + bb.w);
    ((ushort4*)(out + (size_t)row * Hdim))[lane] = o;
}

// ---------------- state GEMM (LDS-staged, swizzled): Zg[h][bc][r], 256x128 per h ----------------
__global__ __launch_bounds__(512) void k_zgemm(const unsigned short* __restrict__ UT,
                                               const unsigned short* __restrict__ Wp,
                                               float* __restrict__ Zg) {
    __shared__ unsigned short As[256 * 64];
    __shared__ unsigned short Bs[128 * 64];
    int h = blockIdx.x;
    int t = threadIdx.x;
    int w = t >> 6, lane = t & 63;
    int m0 = (w & 3) * 64;     // 4 row groups
    int nb = (w >> 2) * 64;    // 2 col groups
    int lr = lane & 15, lk = (lane >> 4) * 8;
    f32x4 acc[4][4];
#pragma unroll
    for (int i = 0; i < 4; i++)
#pragma unroll
        for (int jx = 0; jx < 4; jx++) acc[i][jx] = (f32x4){0.f, 0.f, 0.f, 0.f};
    for (int k0 = 0; k0 < 256; k0 += 64) {
        stageUT<256, 512>(UT, h, 0, k0, As, t);
        stage64<128, 512>(Wp + (size_t)h * 128 * 256, 256, k0, Bs, t);
        __syncthreads();
#pragma unroll
        for (int kk = 0; kk < 64; kk += 32) {
            bf16x8 a[4], b[4];
#pragma unroll
            for (int mi = 0; mi < 4; mi++) a[mi] = fr(As, m0 + mi * 16 + lr, kk + lk);
#pragma unroll
            for (int nf = 0; nf < 4; nf++) b[nf] = fr(Bs, nb + nf * 16 + lr, kk + lk);
#pragma unroll
            for (int mi = 0; mi < 4; mi++)
#pragma unroll
                for (int nf = 0; nf < 4; nf++)
                    acc[mi][nf] = __builtin_amdgcn_mfma_f32_16x16x32_bf16(a[mi], b[nf], acc[mi][nf], 0, 0, 0);
        }
        __syncthreads();
    }
#pragma unroll
    for (int mi = 0; mi < 4; mi++)
#pragma unroll
        for (int nf = 0; nf < 4; nf++) {
            int col = nb + nf * 16 + lr;
#pragma unroll
            for (int r = 0; r < 4; r++) {
                int row = m0 + mi * 16 + (lane >> 4) * 4 + r;
                Zg[((size_t)h * 256 + row) * 128 + col] = acc[mi][nf][r];
            }
        }
}

// ---------------- prefix over chunks -> Zpacked bf16 [h][bc][128] ----------------
__global__ void k_prefix2(const float* __restrict__ Zg, const float2* __restrict__ wptab,
                          unsigned short* __restrict__ ZP) {
    int t = blockIdx.x * 256 + threadIdx.x;
    int n = t & 31;
    int h = (t >> 5) & 255;
    int b = (t >> 13) & 15;
    int dir = (t >> 17) & 1;
    float2 wp = wptab[h * NM + n];
    float sr = 0.f, si = 0.f;
    int ro = dir ? 64 + 2 * n : 2 * n;
    if (dir == 0) {
        for (int c = 0; c < NCH; c++) {
            size_t base = ((size_t)h * 256 + b * NCH + c) * 128;
            ZP[base + ro] = f2bf(sr);
            ZP[base + ro + 1] = f2bf(si);
            float zr = Zg[base + ro], zi = Zg[base + ro + 1];
            float nr = fmaf(wp.x, sr, fmaf(-wp.y, si, zr));
            float ni = fmaf(wp.y, sr, fmaf(wp.x, si, zi));
            sr = nr; si = ni;
        }
    } else {
        for (int c = NCH - 1; c >= 0; c--) {
            size_t base = ((size_t)h * 256 + b * NCH + c) * 128;
            ZP[base + ro] = f2bf(sr);
            ZP[base + ro + 1] = f2bf(si);
            float zr = Zg[base + ro], zi = Zg[base + ro + 1];
            float nr = fmaf(wp.x, sr, fmaf(-wp.y, si, zr));
            float ni = fmaf(wp.y, sr, fmaf(wp.x, si, zi));
            sr = nr; si = ni;
        }
    }
}

// ---------------- conv GEMM (LDS-staged, swizzled): Yt[h][bc][j], tile 128bc x 256j ----------------
__global__ __launch_bounds__(512) void k_conv(const unsigned short* __restrict__ UT,
                                              const unsigned short* __restrict__ ZP,
                                              const unsigned short* __restrict__ AB,
                                              unsigned short* __restrict__ Yt) {
    __shared__ unsigned short As[128 * 64];
    __shared__ unsigned short Bs[256 * 64];
    // XCD-chunked swizzle (512 blocks, 512%8==0 -> bijective)
    int wgid = ((int)blockIdx.x % 8) * 64 + (int)blockIdx.x / 8;
    int h = wgid >> 1;
    int mbase = (wgid & 1) * 128;
    int t = threadIdx.x;
    int w = t >> 6, lane = t & 63;
    int m0 = (w & 1) * 64;     // 2 row groups
    int nb = (w >> 1) * 64;    // 4 col groups (full 256 j)
    int lr = lane & 15, lk = (lane >> 4) * 8;
    const unsigned short* ABh = AB + (size_t)h * 256 * KBIG;
    f32x4 acc[4][4];
#pragma unroll
    for (int i = 0; i < 4; i++)
#pragma unroll
        for (int jx = 0; jx < 4; jx++) acc[i][jx] = (f32x4){0.f, 0.f, 0.f, 0.f};
    // u-part: K = 256
    for (int k0 = 0; k0 < 256; k0 += 64) {
        stageUT<128, 512>(UT, h, mbase, k0, As, t);
        stage64<256, 512>(ABh, KBIG, k0, Bs, t);
        __syncthreads();
#pragma unroll
        for (int kk = 0; kk < 64; kk += 32) {
            bf16x8 a[4], b[4];
#pragma unroll
            for (int mi = 0; mi < 4; mi++) a[mi] = fr(As, m0 + mi * 16 + lr, kk + lk);
#pragma unroll
            for (int nf = 0; nf < 4; nf++) b[nf] = fr(Bs, nb + nf * 16 + lr, kk + lk);
#pragma unroll
            for (int mi = 0; mi < 4; mi++)
#pragma unroll
                for (int nf = 0; nf < 4; nf++)
                    acc[mi][nf] = __builtin_amdgcn_mfma_f32_16x16x32_bf16(a[mi], b[nf], acc[mi][nf], 0, 0, 0);
        }
        __syncthreads();
    }
    // z-part: K = 128 from ZP, AB cols 256..383
    for (int k0 = 0; k0 < 128; k0 += 64) {
        stage64<128, 512>(ZP + ((size_t)h * 256 + mbase) * 128, 128, k0, As, t);
        stage64<256, 512>(ABh + 256, KBIG, k0, Bs, t);
        __syncthreads();
#pragma unroll
        for (int kk = 0; kk < 64; kk += 32) {
            bf16x8 a[4], b[4];
#pragma unroll
            for (int mi = 0; mi < 4; mi++) a[mi] = fr(As, m0 + mi * 16 + lr, kk + lk);
#pragma unroll
            for (int nf = 0; nf < 4; nf++) b[nf] = fr(Bs, nb + nf * 16 + lr, kk + lk);
#pragma unroll
            for (int mi = 0; mi < 4; mi++)
#pragma unroll
                for (int nf = 0; nf < 4; nf++)
                    acc[mi][nf] = __builtin_amdgcn_mfma_f32_16x16x32_bf16(a[mi], b[nf], acc[mi][nf], 0, 0, 0);
        }
        __syncthreads();
    }
#pragma unroll
    for (int mi = 0; mi < 4; mi++)
#pragma unroll
        for (int nf = 0; nf < 4; nf++) {
            int col = nb + nf * 16 + lr;
#pragma unroll
            for (int r = 0; r < 4; r++) {
                int row = mbase + m0 + mi * 16 + (lane >> 4) * 4 + r;
                Yt[(size_t)h * 65536 + row * 256 + col] = f2bf(gelu_f(acc[mi][nf][r]));
            }
        }
}

// ---------------- transpose Yt [h][bc][j] -> G (b, c*P+j, h) bf16 ----------------
__global__ void k_trg(const unsigned short* __restrict__ Yt, unsigned short* __restrict__ G) {
    __shared__ unsigned short lds[64][65];
    int bc = blockIdx.x;
    int h0 = blockIdx.y * 64, j0 = blockIdx.z * 64;
    int t = threadIdx.x;
#pragma unroll
    for (int q = 0; q < 16; q++) {
        int idx = q * 256 + t;
        int hh = idx >> 6, jj = idx & 63;
        lds[hh][jj] = Yt[(size_t)(h0 + hh) * 65536 + bc * 256 + j0 + jj];
    }
    __syncthreads();
    int b = bc >> 4, c = bc & 15;
#pragma unroll
    for (int q = 0; q < 16; q++) {
        int idx = q * 256 + t;
        int jj = idx >> 6, hh = idx & 63;
        G[((size_t)(b * LL + c * PCH + j0 + jj)) * Hdim + h0 + hh] = lds[hh][jj];
    }
}

// ---------------- GEMM1 (512 thr, 128 pairs/block): X2 = bf16(x + glu(G@Wout + bo)) ----------------
__global__ __launch_bounds__(512) void k_gemm1(const unsigned short* __restrict__ Gm,
                                               const unsigned short* __restrict__ W1T,
                                               const float* __restrict__ bo,
                                               const float* __restrict__ xin,
                                               unsigned short* __restrict__ X2) {
    __shared__ unsigned short As[128 * 64];
    __shared__ unsigned short BsA[128 * 64];
    __shared__ unsigned short BsB[128 * 64];
    int t = threadIdx.x;
    int w = t >> 6, lane = t & 63;
    int m0w = (w & 1) * 64;          // 2 row halves
    int n0w = (w >> 1) * 32;         // 4 pair-groups of 32 pairs
    int lr = lane & 15, lk = (lane >> 4) * 8;
    int mblk = blockIdx.x * 128, nblk = blockIdx.y * 128;   // pair base
    const unsigned short* Ab  = Gm + (size_t)mblk * 256;
    const unsigned short* BbA = W1T + (size_t)nblk * 256;
    const unsigned short* BbB = W1T + (size_t)(nblk + 256) * 256;
    f32x4 acc[4][4];
#pragma unroll
    for (int i = 0; i < 4; i++)
#pragma unroll
        for (int j = 0; j < 4; j++) acc[i][j] = (f32x4){0.f, 0.f, 0.f, 0.f};
    for (int k0 = 0; k0 < 256; k0 += 64) {
        stage64<128, 512>(Ab, 256, k0, As, t);
        stage64<128, 512>(BbA, 256, k0, BsA, t);
        stage64<128, 512>(BbB, 256, k0, BsB, t);
        __syncthreads();
#pragma unroll
        for (int kk = 0; kk < 64; kk += 32) {
            bf16x8 a[4], bA[2], bB[2];
#pragma unroll
            for (int mi = 0; mi < 4; mi++)
                a[mi] = fr(As, m0w + mi * 16 + lr, kk + lk);
#pragma unroll
            for (int nf = 0; nf < 2; nf++) {
                bA[nf] = fr(BsA, n0w + nf * 16 + lr, kk + lk);
                bB[nf] = fr(BsB, n0w + nf * 16 + lr, kk + lk);
            }
#pragma unroll
            for (int mi = 0; mi < 4; mi++)
#pragma unroll
                for (int nf = 0; nf < 2; nf++) {
                    acc[mi][nf] = __builtin_amdgcn_mfma_f32_16x16x32_bf16(a[mi], bA[nf], acc[mi][nf], 0, 0, 0);
                    acc[mi][nf + 2] = __builtin_amdgcn_mfma_f32_16x16x32_bf16(a[mi], bB[nf], acc[mi][nf + 2], 0, 0, 0);
                }
        }
        __syncthreads();
    }
#pragma unroll
    for (int mi = 0; mi < 4; mi++)
#pragma unroll
        for (int nf = 0; nf < 2; nf++) {
            int col = nblk + n0w + nf * 16 + lr;
            float biasA = bo[col], biasB = bo[col + 256];
#pragma unroll
            for (int r = 0; r < 4; r++) {
                int row = mblk + m0w + mi * 16 + (lane >> 4) * 4 + r;
                float zzA = acc[mi][nf][r] + biasA;
                float zzB = acc[mi][nf + 2][r] + biasB;
                float v = zzA * __builtin_amdgcn_rcpf(1.0f + __expf(-zzB));
                size_t idx = (size_t)row * 256 + col;
                X2[idx] = f2bf(xin[idx] + v);
            }
        }
}

// ---------------- GEMM2 (512 thr, 256 cols/block): M = gelu(T2@W2 + b2) bf16 ----------------
__global__ __launch_bounds__(512) void k_gemm2(const unsigned short* __restrict__ T2,
                                               const unsigned short* __restrict__ W2T,
                                               const float* __restrict__ b2,
                                               unsigned short* __restrict__ Mo) {
    __shared__ unsigned short As[128 * 64];
    __shared__ unsigned short Bs[256 * 64];
    int t = threadIdx.x;
    int w = t >> 6, lane = t & 63;
    int m0w = (w & 1) * 64;          // 2 row halves
    int n0w = (w >> 1) * 64;         // 4 col groups of 64
    int lr = lane & 15, lk = (lane >> 4) * 8;
    int mblk = blockIdx.x * 128, nblk = blockIdx.y * 256;
    const unsigned short* Ab = T2 + (size_t)mblk * 256;
    const unsigned short* Bb = W2T + (size_t)nblk * 256;
    f32x4 acc[4][4];
#pragma unroll
    for (int i = 0; i < 4; i++)
#pragma unroll
        for (int j = 0; j < 4; j++) acc[i][j] = (f32x4){0.f, 0.f, 0.f, 0.f};
    for (int k0 = 0; k0 < 256; k0 += 64) {
        stage64<128, 512>(Ab, 256, k0, As, t);
        stage64<256, 512>(Bb, 256, k0, Bs, t);
        __syncthreads();
#pragma unroll
        for (int kk = 0; kk < 64; kk += 32) {
            bf16x8 a[4], b[4];
#pragma unroll
            for (int mi = 0; mi < 4; mi++)
                a[mi] = fr(As, m0w + mi * 16 + lr, kk + lk);
#pragma unroll
            for (int nf = 0; nf < 4; nf++)
                b[nf] = fr(Bs, n0w + nf * 16 + lr, kk + lk);
#pragma unroll
            for (int mi = 0; mi < 4; mi++)
#pragma unroll
                for (int nf = 0; nf < 4; nf++)
                    acc[mi][nf] = __builtin_amdgcn_mfma_f32_16x16x32_bf16(a[mi], b[nf], acc[mi][nf], 0, 0, 0);
        }
        __syncthreads();
    }
#pragma unroll
    for (int mi = 0; mi < 4; mi++)
#pragma unroll
        for (int nf = 0; nf < 4; nf++) {
            int col = nblk + n0w + nf * 16 + lr;
            float bias = b2[col];
#pragma unroll
            for (int r = 0; r < 4; r++) {
                int row = mblk + m0w + mi * 16 + (lane >> 4) * 4 + r;
                Mo[(size_t)row * 512 + col] = f2bf(gelu_f(acc[mi][nf][r] + bias));
            }
        }
}

// ---------------- GEMM3 (512 thr, full 256 cols): out = X2 + M@W3 + b3 ----------------
__global__ __launch_bounds__(512) void k_gemm3(const unsigned short* __restrict__ Mb,
                                               const unsigned short* __restrict__ W3T,
                                               const float* __restrict__ b3,
                                               const unsigned short* __restrict__ X2,
                                               float* __restrict__ out) {
    __shared__ unsigned short As[128 * 64];
    __shared__ unsigned short Bs[256 * 64];
    int t = threadIdx.x;
    int w = t >> 6, lane = t & 63;
    int m0w = (w & 1) * 64;          // 2 row halves
    int n0w = (w >> 1) * 64;         // 4 col groups (full 256)
    int lr = lane & 15, lk = (lane >> 4) * 8;
    int mblk = blockIdx.x * 128;
    const unsigned short* Ab = Mb + (size_t)mblk * 512;
    f32x4 acc[4][4];
#pragma unroll
    for (int i = 0; i < 4; i++)
#pragma unroll
        for (int j = 0; j < 4; j++) acc[i][j] = (f32x4){0.f, 0.f, 0.f, 0.f};
    for (int k0 = 0; k0 < 512; k0 += 64) {
        stage64<128, 512>(Ab, 512, k0, As, t);
        stage64<256, 512>(W3T, 512, k0, Bs, t);
        __syncthreads();
#pragma unroll
        for (int kk = 0; kk < 64; kk += 32) {
            bf16x8 a[4], b[4];
#pragma unroll
            for (int mi = 0; mi < 4; mi++)
                a[mi] = fr(As, m0w + mi * 16 + lr, kk + lk);
#pragma unroll
            for (int nf = 0; nf < 4; nf++)
                b[nf] = fr(Bs, n0w + nf * 16 + lr, kk + lk);
#pragma unroll
            for (int mi = 0; mi < 4; mi++)
#pragma unroll
                for (int nf = 0; nf < 4; nf++)
                    acc[mi][nf] = __builtin_amdgcn_mfma_f32_16x16x32_bf16(a[mi], b[nf], acc[mi][nf], 0, 0, 0);
        }
        __syncthreads();
    }
#pragma unroll
    for (int mi = 0; mi < 4; mi++)
#pragma unroll
        for (int nf = 0; nf < 4; nf++) {
            int col = n0w + nf * 16 + lr;
            float bias = b3[col];
#pragma unroll
            for (int r = 0; r < 4; r++) {
                int row = mblk + m0w + mi * 16 + (lane >> 4) * 4 + r;
                size_t idx = (size_t)row * 256 + col;
                out[idx] = bf2f(X2[idx]) + acc[mi][nf][r] + bias;
            }
        }
}

extern "C" void kernel_launch(void* const* d_in, const int* in_sizes, int n_in,
                              void* d_out, int out_size, void* d_ws, size_t ws_size,
                              hipStream_t stream) {
    const float* x     = (const float*)d_in[0];
    const float* ln1g  = (const float*)d_in[1];
    const float* ln1b  = (const float*)d_in[2];
    const float* ln2g  = (const float*)d_in[3];
    const float* ln2b  = (const float*)d_in[4];
    const float* logdt = (const float*)d_in[5];
    const float* Are   = (const float*)d_in[6];
    const float* Aim   = (const float*)d_in[7];
    const float* Cre   = (const float*)d_in[8];
    const float* Cim   = (const float*)d_in[9];
    const float* Dsk   = (const float*)d_in[10];
    const float* Wout  = (const float*)d_in[11];
    const float* bo    = (const float*)d_in[12];
    const float* W2    = (const float*)d_in[13];
    const float* b2    = (const float*)d_in[14];
    const float* W3    = (const float*)d_in[15];
    const float* b3    = (const float*)d_in[16];

    char* ws = (char*)d_ws;
    unsigned short* AB   = (unsigned short*)(ws + OFF_ABIG);
    unsigned short* Wp   = (unsigned short*)(ws + OFF_WPM);
    unsigned short* X2   = (unsigned short*)(ws + OFF_ABIG);   // bf16, after AB is dead
    unsigned short* UT   = (unsigned short*)(ws + OFF_UT);
    float*          Zg   = (float*)(ws + OFF_ZG);
    unsigned short* Yt   = (unsigned short*)(ws + OFF_ZG);
    unsigned short* Mb   = (unsigned short*)(ws + OFF_M);
    unsigned short* ZP   = (unsigned short*)(ws + OFF_ZP);
    unsigned short* G    = (unsigned short*)(ws + OFF_G);
    float2*         WT   = (float2*)(ws + OFF_WTAB);
    float2*         WPT  = (float2*)(ws + OFF_WPT);
    float2*         CE   = (float2*)(ws + OFF_CE);
    unsigned short* W1T  = (unsigned short*)(ws + OFF_W1T);
    unsigned short* W2T  = (unsigned short*)(ws + OFF_W2T);
    unsigned short* W3T  = (unsigned short*)(ws + OFF_W3T);

    k_tab<<<32, 256, 0, stream>>>(logdt, Are, Aim, Cre, Cim, WT, WPT, CE);
    k_wt<<<512, 256, 0, stream>>>(Wout, W2, W3, W1T, W2T, W3T);
    k_lntr<<<dim3(64, 16), 256, 0, stream>>>(x, ln1g, ln1b, UT);
    k_abw<<<256, 256, 0, stream>>>(logdt, Are, Aim, CE, Dsk, AB, Wp);
    k_zgemm<<<256, 512, 0, stream>>>(UT, Wp, Zg);
    k_prefix2<<<1024, 256, 0, stream>>>(Zg, WPT, ZP);
    k_conv<<<512, 512, 0, stream>>>(UT, ZP, AB, Yt);
    k_trg<<<dim3(256, 4, 4), 256, 0, stream>>>(Yt, G);
    k_gemm1<<<dim3(512, 2), 512, 0, stream>>>(G, W1T, bo, x, X2);
    k_ln_bf<<<NB * LL / 4, 256, 0, stream>>>(X2, ln2g, ln2b, G);
    k_gemm2<<<dim3(512, 2), 512, 0, stream>>>(G, W2T, b2, Mb);
    k_gemm3<<<512, 512, 0, stream>>>(Mb, W3T, b3, X2, (float*)d_out);
}

// Round 14
// 254.140 us; speedup vs baseline: 1.3827x; 1.0154x over previous
//
#include <hip/hip_runtime.h>
#include <hip/hip_bf16.h>

typedef __attribute__((ext_vector_type(8))) short bf16x8;
typedef __attribute__((ext_vector_type(4))) float f32x4;

#define Hdim 256
#define NM 32      // N2 modes
#define NB 16      // batch
#define LL 4096    // seq len
#define PCH 256    // chunk length
#define NCH 16     // chunks = LL/PCH
#define KBIG 384   // conv GEMM K: 256 u + 64 zf + 64 zb

// ---- workspace layout (bytes), total 186,122,240 ----
#define OFF_ABIG ((size_t)0)
#define OFF_WPM  ((size_t)50331648)
#define OFF_UT   ((size_t)67108864)    // U_T bf16 [B][H][L] 33554432
#define OFF_ZG   ((size_t)100663296)   // Zg fp32 [h][bc][128] ; then Yt bf16
#define OFF_M    ((size_t)67108864)    // M bf16 (spans UT+ZG, alive gemm2->gemm3)
#define OFF_ZP   ((size_t)134217728)   // Zpacked bf16 [h][bc][128]
#define OFF_G    ((size_t)150994944)   // G bf16 (b,l,h) ; reused as T2
#define OFF_WTAB ((size_t)185073664)
#define OFF_WPT  ((size_t)185139200)
#define OFF_CE   ((size_t)185204736)
#define OFF_W1T  ((size_t)185335808)
#define OFF_W2T  ((size_t)185597952)
#define OFF_W3T  ((size_t)185860096)

typedef const __attribute__((address_space(1))) void* gas_p;
typedef __attribute__((address_space(3))) void* las_p;

// fast gelu: tanh form via hardware exp + rcp (max abs err ~1e-3 vs erf form)
__device__ __forceinline__ float gelu_f(float v) {
    float u = 0.7978845608028654f * fmaf(0.044715f * v * v, v, v);
    float uc = fminf(fmaxf(u, -15.f), 15.f);
    float e = __expf(2.f * uc);
    return 0.5f * v * (1.f + (e - 1.f) * __builtin_amdgcn_rcpf(e + 1.f));
}
__device__ __forceinline__ unsigned short f2bf(float f) {  // RNE f32->bf16
    unsigned int u = __float_as_uint(f);
    u += 0x7fffu + ((u >> 16) & 1u);
    return (unsigned short)(u >> 16);
}
__device__ __forceinline__ float bf2f(unsigned short u) {
    return __uint_as_float((unsigned int)u << 16);
}

// swizzled fragment read from a [R][64] tile: XOR 16B-block index with (row&7).
__device__ __forceinline__ bf16x8 fr(const unsigned short* lds, int row, int kcol) {
    return *(const bf16x8*)(lds + row * 64 + ((((kcol >> 3) ^ (row & 7)) << 3)));
}

// stage ROWS x 64 bf16 tile (row-major, ld elems) into LDS [ROWS][64] (linear dest,
// inverse-swizzled source)
template<int ROWS, int THREADS>
__device__ __forceinline__ void stage64(const unsigned short* __restrict__ src, int ld, int k0,
                                        unsigned short* lds, int t) {
    constexpr int EPI = THREADS * 8;   // elems per iter
#pragma unroll
    for (int i = 0; i < (ROWS * 64) / EPI; i++) {
        int e = i * EPI + t * 8;
        int r = e >> 6;
        int k = (((e >> 3) & 7) ^ (r & 7)) << 3;
        const unsigned short* g = src + (size_t)r * ld + (k0 + k);
        unsigned short* l = lds + i * EPI + (t >> 6) * 512;   // wave-uniform base
        __builtin_amdgcn_global_load_lds((gas_p)g, (las_p)l, 16, 0, 0);
    }
}

// stage ROWS x 64 tile of UT (bc-rows) for head h, same swizzle
template<int ROWS, int THREADS>
__device__ __forceinline__ void stageUT(const unsigned short* __restrict__ UT, int h, int rbase,
                                        int k0, unsigned short* lds, int t) {
    constexpr int EPI = THREADS * 8;
#pragma unroll
    for (int i = 0; i < (ROWS * 64) / EPI; i++) {
        int e = i * EPI + t * 8;
        int r = e >> 6;
        int k = (((e >> 3) & 7) ^ (r & 7)) << 3;
        int row = rbase + r;
        const unsigned short* g = UT + ((size_t)((row >> 4) * Hdim + h)) * LL
                                  + (row & 15) * PCH + (k0 + k);
        unsigned short* l = lds + i * EPI + (t >> 6) * 512;
        __builtin_amdgcn_global_load_lds((gas_p)g, (las_p)l, 16, 0, 0);
    }
}

// ---------------- tables ----------------
__global__ void k_tab(const float* __restrict__ logdt, const float* __restrict__ Are,
                      const float* __restrict__ Aim, const float* __restrict__ Cre,
                      const float* __restrict__ Cim, float2* __restrict__ wtab,
                      float2* __restrict__ wptab, float2* __restrict__ ceff) {
    int idx = blockIdx.x * blockDim.x + threadIdx.x;
    if (idx >= Hdim * NM) return;
    int h = idx >> 5;
    float dt = expf(logdt[h]);
    double dar = (double)dt * (double)Are[idx];
    double dai = (double)dt * (double)Aim[idx];
    double wm = exp(dar);
    double wr = wm * cos(dai), wi = wm * sin(dai);
    wtab[idx] = make_float2((float)wr, (float)wi);
    double pm = exp(dar * (double)PCH);
    double pai = dai * (double)PCH;
    wptab[idx] = make_float2((float)(pm * cos(pai)), (float)(pm * sin(pai)));
    double are = (double)Are[idx], aim = (double)Aim[idx];
    double den = are * are + aim * aim;
    double nr = wr - 1.0, ni = wi;
    double qr = (nr * are + ni * aim) / den;
    double qi = (ni * are - nr * aim) / den;
    for (int ch = 0; ch < 2; ch++) {
        double cr = (double)Cre[ch * Hdim * NM + idx];
        double ci = (double)Cim[ch * Hdim * NM + idx];
        ceff[ch * Hdim * NM + idx] = make_float2((float)(cr * qr - ci * qi),
                                                 (float)(cr * qi + ci * qr));
    }
}

// ---------------- weight transpose + bf16 cast ----------------
__global__ void k_wt(const float* __restrict__ W1, const float* __restrict__ W2,
                     const float* __restrict__ W3, unsigned short* __restrict__ W1T,
                     unsigned short* __restrict__ W2T, unsigned short* __restrict__ W3T) {
    int t = blockIdx.x * 256 + threadIdx.x;  // 131072 threads
    int k = t >> 9, n = t & 511;             // W1,W2: [256][512]
    W1T[n * 256 + k] = f2bf(W1[t]);
    W2T[n * 256 + k] = f2bf(W2[t]);
    int k3 = t >> 8, n3 = t & 255;           // W3: [512][256]
    W3T[n3 * 512 + k3] = f2bf(W3[t]);
}

// ---------------- merged table builder, split 5 ways per h ----------------
// part 0..3: AB j-tile of 64 rows ; part 4: Wp (128 rows)
__global__ __launch_bounds__(256) void k_abw(const float* __restrict__ logdt,
                                             const float* __restrict__ Are,
                                             const float* __restrict__ Aim,
                                             const float2* __restrict__ CE,
                                             const float* __restrict__ Dsk,
                                             unsigned short* __restrict__ AB,
                                             unsigned short* __restrict__ Wp) {
    __shared__ float2 wpow[32][257];   // w^j, j=0..256
    __shared__ float kf[256], kb[256];
    __shared__ float2 ce_s[64];        // [0..31] fwd, [32..63] bwd
    int h = blockIdx.x;
    int part = blockIdx.y;             // 0..3 AB tiles, 4 = Wp
    int t = threadIdx.x;
    if (t < 64) ce_s[t] = CE[(t >> 5) * (Hdim * NM) + h * NM + (t & 31)];
    {   // build wpow: thread = n*8+seg, 32-step recurrence from w^(32*seg)
        int n = t >> 3, seg = t & 7;
        float dt = expf(logdt[h]);
        float dar = dt * Are[h * NM + n], dai = dt * Aim[h * NM + n];
        float em = expf(dar);
        float wr = em * cosf(dai), wi = em * sinf(dai);
        int j0 = seg * 32;
        float m = expf((float)j0 * dar), ang = (float)j0 * dai;
        float vr = m * cosf(ang), vi = m * sinf(ang);
        for (int q = 0; q < 32; q++) {
            wpow[n][j0 + q] = make_float2(vr, vi);
            float nr2 = vr * wr - vi * wi;
            float ni2 = vr * wi + vi * wr;
            vr = nr2; vi = ni2;
        }
        if (seg == 7) wpow[n][256] = make_float2(vr, vi);
    }
    __syncthreads();
    if (part == 4) {   // Wp rows: row r, lane = column i
        for (int r = 0; r < 128; r++) {
            int n = (r & 63) >> 1, reim = r & 1, dir = r >> 6;
            float2 wv = wpow[n][dir ? t : 255 - t];
            Wp[((size_t)h * 128 + r) * 256 + t] = f2bf(reim ? wv.y : wv.x);
        }
        return;
    }
    {   // conv kernels kf[d], kb[d] (lane = d)
        float kfv = 0.f, kbv = 0.f;
#pragma unroll
        for (int n = 0; n < NM; n++) {
            float2 wv = wpow[n][t];
            float2 cf = ce_s[n], cb = ce_s[32 + n];
            kfv = fmaf(cf.x, wv.x, fmaf(-cf.y, wv.y, kfv));
            kbv = fmaf(cb.x, wv.x, fmaf(-cb.y, wv.y, kbv));
        }
        kf[t] = 2.f * kfv;
        kb[t] = 2.f * kbv;
    }
    __syncthreads();
    float dsk = Dsk[h];
    int j0 = part * 64;
    for (int j = j0; j < j0 + 64; j++) {
        unsigned short* out = AB + ((size_t)h * 256 + j) * KBIG;
        float v = (t <= j) ? kf[j - t] : kb[t - j - 1];
        if (t == j) v += dsk;
        out[t] = f2bf(v);
        if (t < 128) {
            int n = (t & 63) >> 1, reim = t & 1;
            float2 c = (t < 64) ? ce_s[n] : ce_s[32 + n];
            float2 wv = (t < 64) ? wpow[n][j + 1] : wpow[n][255 - j];
            float re = c.x * wv.x - c.y * wv.y;
            float im = c.x * wv.y + c.y * wv.x;
            out[256 + t] = f2bf(reim ? -2.f * im : 2.f * re);
        }
    }
}

// ---------------- fused layernorm + transpose: x (b,l,h) fp32 -> UT (b,h,l) bf16 ----------------
__global__ __launch_bounds__(256) void k_lntr(const float* __restrict__ x,
                                              const float* __restrict__ g,
                                              const float* __restrict__ bt,
                                              unsigned short* __restrict__ UT) {
    __shared__ unsigned short lds[256][65];
    int lt = blockIdx.x, b = blockIdx.y;
    int t = threadIdx.x;
    int lane = t & 63, w = t >> 6;
    float4 gg = ((const float4*)g)[lane];
    float4 bb = ((const float4*)bt)[lane];
#pragma unroll
    for (int q = 0; q < 16; q++) {
        int l = q * 4 + w;
        float4 v = ((const float4*)(x + ((size_t)(b * LL + lt * 64 + l)) * Hdim))[lane];
        float s = v.x + v.y + v.z + v.w;
        float ss = v.x * v.x + v.y * v.y + v.z * v.z + v.w * v.w;
#pragma unroll
        for (int o = 1; o < 64; o <<= 1) { s += __shfl_xor(s, o, 64); ss += __shfl_xor(ss, o, 64); }
        float mean = s * (1.0f / Hdim);
        float var = ss * (1.0f / Hdim) - mean * mean;
        float rstd = rsqrtf(var + 1e-5f);
        lds[lane * 4 + 0][l] = f2bf((v.x - mean) * rstd * gg.x + bb.x);
        lds[lane * 4 + 1][l] = f2bf((v.y - mean) * rstd * gg.y + bb.y);
        lds[lane * 4 + 2][l] = f2bf((v.z - mean) * rstd * gg.z + bb.z);
        lds[lane * 4 + 3][l] = f2bf((v.w - mean) * rstd * gg.w + bb.w);
    }
    __syncthreads();
    for (int q = 0; q < 64; q++) {
        int idx = q * 256 + t;
        int hh = idx >> 6, ll = idx & 63;
        UT[((size_t)(b * Hdim + hh)) * LL + lt * 64 + ll] = lds[hh][ll];
    }
}

// ---------------- layernorm (bf16 in, bf16 out): T2 = LN(X2) ----------------
__global__ void k_ln_bf(const unsigned short* __restrict__ x, const float* __restrict__ g,
                        const float* __restrict__ bt, unsigned short* __restrict__ out) {
    int row = blockIdx.x * 4 + (threadIdx.x >> 6);
    int lane = threadIdx.x & 63;
    ushort4 u4 = ((const ushort4*)(x + (size_t)row * Hdim))[lane];
    float vx = bf2f(u4.x), vy = bf2f(u4.y), vz = bf2f(u4.z), vw = bf2f(u4.w);
    float s = vx + vy + vz + vw;
    float ss = vx * vx + vy * vy + vz * vz + vw * vw;
#pragma unroll
    for (int o = 1; o < 64; o <<= 1) { s += __shfl_xor(s, o, 64); ss += __shfl_xor(ss, o, 64); }
    float mean = s * (1.0f / Hdim);
    float var = ss * (1.0f / Hdim) - mean * mean;
    float rstd = rsqrtf(var + 1e-5f);
    float4 gg = ((const float4*)g)[lane];
    float4 bb = ((const float4*)bt)[lane];
    ushort4 o;
    o.x = f2bf((vx - mean) * rstd * gg.x + bb.x);
    o.y = f2bf((vy - mean) * rstd * gg.y + bb.y);
    o.z = f2bf((vz - mean) * rstd * gg.z + bb.z);
    o.w = f2bf((vw - mean) * rstd * gg.w + bb.w);
    ((ushort4*)(out + (size_t)row * Hdim))[lane] = o;
}

// ---------------- state GEMM (LDS-staged, swizzled): Zg[h][bc][r], 256x128 per h ----------------
__global__ __launch_bounds__(512) void k_zgemm(const unsigned short* __restrict__ UT,
                                               const unsigned short* __restrict__ Wp,
                                               float* __restrict__ Zg) {
    __shared__ unsigned short As[256 * 64];
    __shared__ unsigned short Bs[128 * 64];
    int h = blockIdx.x;
    int t = threadIdx.x;
    int w = t >> 6, lane = t & 63;
    int m0 = (w & 3) * 64;     // 4 row groups
    int nb = (w >> 2) * 64;    // 2 col groups
    int lr = lane & 15, lk = (lane >> 4) * 8;
    f32x4 acc[4][4];
#pragma unroll
    for (int i = 0; i < 4; i++)
#pragma unroll
        for (int jx = 0; jx < 4; jx++) acc[i][jx] = (f32x4){0.f, 0.f, 0.f, 0.f};
    for (int k0 = 0; k0 < 256; k0 += 64) {
        stageUT<256, 512>(UT, h, 0, k0, As, t);
        stage64<128, 512>(Wp + (size_t)h * 128 * 256, 256, k0, Bs, t);
        __syncthreads();
#pragma unroll
        for (int kk = 0; kk < 64; kk += 32) {
            bf16x8 a[4], b[4];
#pragma unroll
            for (int mi = 0; mi < 4; mi++) a[mi] = fr(As, m0 + mi * 16 + lr, kk + lk);
#pragma unroll
            for (int nf = 0; nf < 4; nf++) b[nf] = fr(Bs, nb + nf * 16 + lr, kk + lk);
#pragma unroll
            for (int mi = 0; mi < 4; mi++)
#pragma unroll
                for (int nf = 0; nf < 4; nf++)
                    acc[mi][nf] = __builtin_amdgcn_mfma_f32_16x16x32_bf16(a[mi], b[nf], acc[mi][nf], 0, 0, 0);
        }
        __syncthreads();
    }
#pragma unroll
    for (int mi = 0; mi < 4; mi++)
#pragma unroll
        for (int nf = 0; nf < 4; nf++) {
            int col = nb + nf * 16 + lr;
#pragma unroll
            for (int r = 0; r < 4; r++) {
                int row = m0 + mi * 16 + (lane >> 4) * 4 + r;
                Zg[((size_t)h * 256 + row) * 128 + col] = acc[mi][nf][r];
            }
        }
}

// ---------------- prefix over chunks -> Zpacked bf16 [h][bc][128] ----------------
__global__ void k_prefix2(const float* __restrict__ Zg, const float2* __restrict__ wptab,
                          unsigned short* __restrict__ ZP) {
    int t = blockIdx.x * 256 + threadIdx.x;
    int n = t & 31;
    int h = (t >> 5) & 255;
    int b = (t >> 13) & 15;
    int dir = (t >> 17) & 1;
    float2 wp = wptab[h * NM + n];
    float sr = 0.f, si = 0.f;
    int ro = dir ? 64 + 2 * n : 2 * n;
    if (dir == 0) {
        for (int c = 0; c < NCH; c++) {
            size_t base = ((size_t)h * 256 + b * NCH + c) * 128;
            ZP[base + ro] = f2bf(sr);
            ZP[base + ro + 1] = f2bf(si);
            float zr = Zg[base + ro], zi = Zg[base + ro + 1];
            float nr = fmaf(wp.x, sr, fmaf(-wp.y, si, zr));
            float ni = fmaf(wp.y, sr, fmaf(wp.x, si, zi));
            sr = nr; si = ni;
        }
    } else {
        for (int c = NCH - 1; c >= 0; c--) {
            size_t base = ((size_t)h * 256 + b * NCH + c) * 128;
            ZP[base + ro] = f2bf(sr);
            ZP[base + ro + 1] = f2bf(si);
            float zr = Zg[base + ro], zi = Zg[base + ro + 1];
            float nr = fmaf(wp.x, sr, fmaf(-wp.y, si, zr));
            float ni = fmaf(wp.y, sr, fmaf(wp.x, si, zi));
            sr = nr; si = ni;
        }
    }
}

// ---------------- conv GEMM (LDS-staged, swizzled): Yt[h][bc][j], tile 128bc x 256j ----------------
__global__ __launch_bounds__(512) void k_conv(const unsigned short* __restrict__ UT,
                                              const unsigned short* __restrict__ ZP,
                                              const unsigned short* __restrict__ AB,
                                              unsigned short* __restrict__ Yt) {
    __shared__ unsigned short As[128 * 64];
    __shared__ unsigned short Bs[256 * 64];
    // XCD-chunked swizzle (512 blocks, 512%8==0 -> bijective)
    int wgid = ((int)blockIdx.x % 8) * 64 + (int)blockIdx.x / 8;
    int h = wgid >> 1;
    int mbase = (wgid & 1) * 128;
    int t = threadIdx.x;
    int w = t >> 6, lane = t & 63;
    int m0 = (w & 1) * 64;     // 2 row groups
    int nb = (w >> 1) * 64;    // 4 col groups (full 256 j)
    int lr = lane & 15, lk = (lane >> 4) * 8;
    const unsigned short* ABh = AB + (size_t)h * 256 * KBIG;
    f32x4 acc[4][4];
#pragma unroll
    for (int i = 0; i < 4; i++)
#pragma unroll
        for (int jx = 0; jx < 4; jx++) acc[i][jx] = (f32x4){0.f, 0.f, 0.f, 0.f};
    // u-part: K = 256
    for (int k0 = 0; k0 < 256; k0 += 64) {
        stageUT<128, 512>(UT, h, mbase, k0, As, t);
        stage64<256, 512>(ABh, KBIG, k0, Bs, t);
        __syncthreads();
#pragma unroll
        for (int kk = 0; kk < 64; kk += 32) {
            bf16x8 a[4], b[4];
#pragma unroll
            for (int mi = 0; mi < 4; mi++) a[mi] = fr(As, m0 + mi * 16 + lr, kk + lk);
#pragma unroll
            for (int nf = 0; nf < 4; nf++) b[nf] = fr(Bs, nb + nf * 16 + lr, kk + lk);
#pragma unroll
            for (int mi = 0; mi < 4; mi++)
#pragma unroll
                for (int nf = 0; nf < 4; nf++)
                    acc[mi][nf] = __builtin_amdgcn_mfma_f32_16x16x32_bf16(a[mi], b[nf], acc[mi][nf], 0, 0, 0);
        }
        __syncthreads();
    }
    // z-part: K = 128 from ZP, AB cols 256..383
    for (int k0 = 0; k0 < 128; k0 += 64) {
        stage64<128, 512>(ZP + ((size_t)h * 256 + mbase) * 128, 128, k0, As, t);
        stage64<256, 512>(ABh + 256, KBIG, k0, Bs, t);
        __syncthreads();
#pragma unroll
        for (int kk = 0; kk < 64; kk += 32) {
            bf16x8 a[4], b[4];
#pragma unroll
            for (int mi = 0; mi < 4; mi++) a[mi] = fr(As, m0 + mi * 16 + lr, kk + lk);
#pragma unroll
            for (int nf = 0; nf < 4; nf++) b[nf] = fr(Bs, nb + nf * 16 + lr, kk + lk);
#pragma unroll
            for (int mi = 0; mi < 4; mi++)
#pragma unroll
                for (int nf = 0; nf < 4; nf++)
                    acc[mi][nf] = __builtin_amdgcn_mfma_f32_16x16x32_bf16(a[mi], b[nf], acc[mi][nf], 0, 0, 0);
        }
        __syncthreads();
    }
#pragma unroll
    for (int mi = 0; mi < 4; mi++)
#pragma unroll
        for (int nf = 0; nf < 4; nf++) {
            int col = nb + nf * 16 + lr;
#pragma unroll
            for (int r = 0; r < 4; r++) {
                int row = mbase + m0 + mi * 16 + (lane >> 4) * 4 + r;
                Yt[(size_t)h * 65536 + row * 256 + col] = f2bf(gelu_f(acc[mi][nf][r]));
            }
        }
}

// ---------------- transpose Yt [h][bc][j] -> G (b, c*P+j, h) bf16 ----------------
__global__ void k_trg(const unsigned short* __restrict__ Yt, unsigned short* __restrict__ G) {
    __shared__ unsigned short lds[64][65];
    int bc = blockIdx.x;
    int h0 = blockIdx.y * 64, j0 = blockIdx.z * 64;
    int t = threadIdx.x;
#pragma unroll
    for (int q = 0; q < 16; q++) {
        int idx = q * 256 + t;
        int hh = idx >> 6, jj = idx & 63;
        lds[hh][jj] = Yt[(size_t)(h0 + hh) * 65536 + bc * 256 + j0 + jj];
    }
    __syncthreads();
    int b = bc >> 4, c = bc & 15;
#pragma unroll
    for (int q = 0; q < 16; q++) {
        int idx = q * 256 + t;
        int jj = idx >> 6, hh = idx & 63;
        G[((size_t)(b * LL + c * PCH + j0 + jj)) * Hdim + h0 + hh] = lds[hh][jj];
    }
}

// ---------------- GEMM1 (512 thr, 128 pairs/block): X2 = bf16(x + glu(G@Wout + bo)) ----------------
__global__ __launch_bounds__(512) void k_gemm1(const unsigned short* __restrict__ Gm,
                                               const unsigned short* __restrict__ W1T,
                                               const float* __restrict__ bo,
                                               const float* __restrict__ xin,
                                               unsigned short* __restrict__ X2) {
    __shared__ unsigned short As[128 * 64];
    __shared__ unsigned short BsA[128 * 64];
    __shared__ unsigned short BsB[128 * 64];
    int t = threadIdx.x;
    int w = t >> 6, lane = t & 63;
    int m0w = (w & 1) * 64;          // 2 row halves
    int n0w = (w >> 1) * 32;         // 4 pair-groups of 32 pairs
    int lr = lane & 15, lk = (lane >> 4) * 8;
    int mblk = blockIdx.x * 128, nblk = blockIdx.y * 128;   // pair base
    const unsigned short* Ab  = Gm + (size_t)mblk * 256;
    const unsigned short* BbA = W1T + (size_t)nblk * 256;
    const unsigned short* BbB = W1T + (size_t)(nblk + 256) * 256;
    f32x4 acc[4][4];
#pragma unroll
    for (int i = 0; i < 4; i++)
#pragma unroll
        for (int j = 0; j < 4; j++) acc[i][j] = (f32x4){0.f, 0.f, 0.f, 0.f};
    for (int k0 = 0; k0 < 256; k0 += 64) {
        stage64<128, 512>(Ab, 256, k0, As, t);
        stage64<128, 512>(BbA, 256, k0, BsA, t);
        stage64<128, 512>(BbB, 256, k0, BsB, t);
        __syncthreads();
#pragma unroll
        for (int kk = 0; kk < 64; kk += 32) {
            bf16x8 a[4], bA[2], bB[2];
#pragma unroll
            for (int mi = 0; mi < 4; mi++)
                a[mi] = fr(As, m0w + mi * 16 + lr, kk + lk);
#pragma unroll
            for (int nf = 0; nf < 2; nf++) {
                bA[nf] = fr(BsA, n0w + nf * 16 + lr, kk + lk);
                bB[nf] = fr(BsB, n0w + nf * 16 + lr, kk + lk);
            }
#pragma unroll
            for (int mi = 0; mi < 4; mi++)
#pragma unroll
                for (int nf = 0; nf < 2; nf++) {
                    acc[mi][nf] = __builtin_amdgcn_mfma_f32_16x16x32_bf16(a[mi], bA[nf], acc[mi][nf], 0, 0, 0);
                    acc[mi][nf + 2] = __builtin_amdgcn_mfma_f32_16x16x32_bf16(a[mi], bB[nf], acc[mi][nf + 2], 0, 0, 0);
                }
        }
        __syncthreads();
    }
#pragma unroll
    for (int mi = 0; mi < 4; mi++)
#pragma unroll
        for (int nf = 0; nf < 2; nf++) {
            int col = nblk + n0w + nf * 16 + lr;
            float biasA = bo[col], biasB = bo[col + 256];
#pragma unroll
            for (int r = 0; r < 4; r++) {
                int row = mblk + m0w + mi * 16 + (lane >> 4) * 4 + r;
                float zzA = acc[mi][nf][r] + biasA;
                float zzB = acc[mi][nf + 2][r] + biasB;
                float v = zzA * __builtin_amdgcn_rcpf(1.0f + __expf(-zzB));
                size_t idx = (size_t)row * 256 + col;
                X2[idx] = f2bf(xin[idx] + v);
            }
        }
}

// ---------------- GEMM2 (512 thr, 256 cols/block): M = gelu(T2@W2 + b2) bf16 ----------------
__global__ __launch_bounds__(512) void k_gemm2(const unsigned short* __restrict__ T2,
                                               const unsigned short* __restrict__ W2T,
                                               const float* __restrict__ b2,
                                               unsigned short* __restrict__ Mo) {
    __shared__ unsigned short As[128 * 64];
    __shared__ unsigned short Bs[256 * 64];
    int t = threadIdx.x;
    int w = t >> 6, lane = t & 63;
    int m0w = (w & 1) * 64;          // 2 row halves
    int n0w = (w >> 1) * 64;         // 4 col groups of 64
    int lr = lane & 15, lk = (lane >> 4) * 8;
    int mblk = blockIdx.x * 128, nblk = blockIdx.y * 256;
    const unsigned short* Ab = T2 + (size_t)mblk * 256;
    const unsigned short* Bb = W2T + (size_t)nblk * 256;
    f32x4 acc[4][4];
#pragma unroll
    for (int i = 0; i < 4; i++)
#pragma unroll
        for (int j = 0; j < 4; j++) acc[i][j] = (f32x4){0.f, 0.f, 0.f, 0.f};
    for (int k0 = 0; k0 < 256; k0 += 64) {
        stage64<128, 512>(Ab, 256, k0, As, t);
        stage64<256, 512>(Bb, 256, k0, Bs, t);
        __syncthreads();
#pragma unroll
        for (int kk = 0; kk < 64; kk += 32) {
            bf16x8 a[4], b[4];
#pragma unroll
            for (int mi = 0; mi < 4; mi++)
                a[mi] = fr(As, m0w + mi * 16 + lr, kk + lk);
#pragma unroll
            for (int nf = 0; nf < 4; nf++)
                b[nf] = fr(Bs, n0w + nf * 16 + lr, kk + lk);
#pragma unroll
            for (int mi = 0; mi < 4; mi++)
#pragma unroll
                for (int nf = 0; nf < 4; nf++)
                    acc[mi][nf] = __builtin_amdgcn_mfma_f32_16x16x32_bf16(a[mi], b[nf], acc[mi][nf], 0, 0, 0);
        }
        __syncthreads();
    }
#pragma unroll
    for (int mi = 0; mi < 4; mi++)
#pragma unroll
        for (int nf = 0; nf < 4; nf++) {
            int col = nblk + n0w + nf * 16 + lr;
            float bias = b2[col];
#pragma unroll
            for (int r = 0; r < 4; r++) {
                int row = mblk + m0w + mi * 16 + (lane >> 4) * 4 + r;
                Mo[(size_t)row * 512 + col] = f2bf(gelu_f(acc[mi][nf][r] + bias));
            }
        }
}

// ---------------- GEMM3 (512 thr, full 256 cols): out = X2 + M@W3 + b3 ----------------
__global__ __launch_bounds__(512) void k_gemm3(const unsigned short* __restrict__ Mb,
                                               const unsigned short* __restrict__ W3T,
                                               const float* __restrict__ b3,
                                               const unsigned short* __restrict__ X2,
                                               float* __restrict__ out) {
    __shared__ unsigned short As[128 * 64];
    __shared__ unsigned short Bs[256 * 64];
    int t = threadIdx.x;
    int w = t >> 6, lane = t & 63;
    int m0w = (w & 1) * 64;          // 2 row halves
    int n0w = (w >> 1) * 64;         // 4 col groups (full 256)
    int lr = lane & 15, lk = (lane >> 4) * 8;
    int mblk = blockIdx.x * 128;
    const unsigned short* Ab = Mb + (size_t)mblk * 512;
    f32x4 acc[4][4];
#pragma unroll
    for (int i = 0; i < 4; i++)
#pragma unroll
        for (int j = 0; j < 4; j++) acc[i][j] = (f32x4){0.f, 0.f, 0.f, 0.f};
    for (int k0 = 0; k0 < 512; k0 += 64) {
        stage64<128, 512>(Ab, 512, k0, As, t);
        stage64<256, 512>(W3T, 512, k0, Bs, t);
        __syncthreads();
#pragma unroll
        for (int kk = 0; kk < 64; kk += 32) {
            bf16x8 a[4], b[4];
#pragma unroll
            for (int mi = 0; mi < 4; mi++)
                a[mi] = fr(As, m0w + mi * 16 + lr, kk + lk);
#pragma unroll
            for (int nf = 0; nf < 4; nf++)
                b[nf] = fr(Bs, n0w + nf * 16 + lr, kk + lk);
#pragma unroll
            for (int mi = 0; mi < 4; mi++)
#pragma unroll
                for (int nf = 0; nf < 4; nf++)
                    acc[mi][nf] = __builtin_amdgcn_mfma_f32_16x16x32_bf16(a[mi], b[nf], acc[mi][nf], 0, 0, 0);
        }
        __syncthreads();
    }
#pragma unroll
    for (int mi = 0; mi < 4; mi++)
#pragma unroll
        for (int nf = 0; nf < 4; nf++) {
            int col = n0w + nf * 16 + lr;
            float bias = b3[col];
#pragma unroll
            for (int r = 0; r < 4; r++) {
                int row = mblk + m0w + mi * 16 + (lane >> 4) * 4 + r;
                size_t idx = (size_t)row * 256 + col;
                out[idx] = bf2f(X2[idx]) + acc[mi][nf][r] + bias;
            }
        }
}

extern "C" void kernel_launch(void* const* d_in, const int* in_sizes, int n_in,
                              void* d_out, int out_size, void* d_ws, size_t ws_size,
                              hipStream_t stream) {
    const float* x     = (const float*)d_in[0];
    const float* ln1g  = (const float*)d_in[1];
    const float* ln1b  = (const float*)d_in[2];
    const float* ln2g  = (const float*)d_in[3];
    const float* ln2b  = (const float*)d_in[4];
    const float* logdt = (const float*)d_in[5];
    const float* Are   = (const float*)d_in[6];
    const float* Aim   = (const float*)d_in[7];
    const float* Cre   = (const float*)d_in[8];
    const float* Cim   = (const float*)d_in[9];
    const float* Dsk   = (const float*)d_in[10];
    const float* Wout  = (const float*)d_in[11];
    const float* bo    = (const float*)d_in[12];
    const float* W2    = (const float*)d_in[13];
    const float* b2    = (const float*)d_in[14];
    const float* W3    = (const float*)d_in[15];
    const float* b3    = (const float*)d_in[16];

    char* ws = (char*)d_ws;
    unsigned short* AB   = (unsigned short*)(ws + OFF_ABIG);
    unsigned short* Wp   = (unsigned short*)(ws + OFF_WPM);
    unsigned short* X2   = (unsigned short*)(ws + OFF_ABIG);   // bf16, after AB is dead
    unsigned short* UT   = (unsigned short*)(ws + OFF_UT);
    float*          Zg   = (float*)(ws + OFF_ZG);
    unsigned short* Yt   = (unsigned short*)(ws + OFF_ZG);
    unsigned short* Mb   = (unsigned short*)(ws + OFF_M);
    unsigned short* ZP   = (unsigned short*)(ws + OFF_ZP);
    unsigned short* G    = (unsigned short*)(ws + OFF_G);
    float2*         WT   = (float2*)(ws + OFF_WTAB);
    float2*         WPT  = (float2*)(ws + OFF_WPT);
    float2*         CE   = (float2*)(ws + OFF_CE);
    unsigned short* W1T  = (unsigned short*)(ws + OFF_W1T);
    unsigned short* W2T  = (unsigned short*)(ws + OFF_W2T);
    unsigned short* W3T  = (unsigned short*)(ws + OFF_W3T);

    k_tab<<<32, 256, 0, stream>>>(logdt, Are, Aim, Cre, Cim, WT, WPT, CE);
    k_wt<<<512, 256, 0, stream>>>(Wout, W2, W3, W1T, W2T, W3T);
    k_lntr<<<dim3(64, 16), 256, 0, stream>>>(x, ln1g, ln1b, UT);
    k_abw<<<dim3(256, 5), 256, 0, stream>>>(logdt, Are, Aim, CE, Dsk, AB, Wp);
    k_zgemm<<<256, 512, 0, stream>>>(UT, Wp, Zg);
    k_prefix2<<<1024, 256, 0, stream>>>(Zg, WPT, ZP);
    k_conv<<<512, 512, 0, stream>>>(UT, ZP, AB, Yt);
    k_trg<<<dim3(256, 4, 4), 256, 0, stream>>>(Yt, G);
    k_gemm1<<<dim3(512, 2), 512, 0, stream>>>(G, W1T, bo, x, X2);
    k_ln_bf<<<NB * LL / 4, 256, 0, stream>>>(X2, ln2g, ln2b, G);
    k_gemm2<<<dim3(512, 2), 512, 0, stream>>>(G, W2T, b2, Mb);
    k_gemm3<<<512, 512, 0, stream>>>(Mb, W3T, b3, X2, (float*)d_out);
}

// Round 15
// 238.910 us; speedup vs baseline: 1.4708x; 1.0637x over previous
//
#include <hip/hip_runtime.h>
#include <hip/hip_bf16.h>

typedef __attribute__((ext_vector_type(8))) short bf16x8;
typedef __attribute__((ext_vector_type(4))) float f32x4;

#define Hdim 256
#define NM 32      // N2 modes
#define NB 16      // batch
#define LL 4096    // seq len
#define PCH 256    // chunk length
#define NCH 16     // chunks = LL/PCH

// ---- workspace layout (bytes) ----
// region0 [0,67108864): Q bf16 [h][256][128] 16,777,216 + Kcat fp32 [h][512] 524,288 ; later X2 bf16
#define OFF_Q    ((size_t)0)
#define OFF_KC   ((size_t)16777216)
#define OFF_WPM  ((size_t)50331648)    // Wp bf16 [h][128][256] 16,777,216
#define OFF_UT   ((size_t)67108864)    // U_T bf16 [B][H][L] 33554432
#define OFF_ZG   ((size_t)100663296)   // Zg fp32 [h][bc][128] ; then Yt bf16
#define OFF_M    ((size_t)67108864)    // M bf16 (spans UT+ZG, alive gemm2->gemm3)
#define OFF_ZP   ((size_t)134217728)   // Zpacked bf16 [h][bc][128]
#define OFF_G    ((size_t)150994944)   // G bf16 (b,l,h) ; reused as T2
#define OFF_WTAB ((size_t)185073664)
#define OFF_WPT  ((size_t)185139200)
#define OFF_CE   ((size_t)185204736)
#define OFF_W1T  ((size_t)185335808)
#define OFF_W2T  ((size_t)185597952)
#define OFF_W3T  ((size_t)185860096)

typedef const __attribute__((address_space(1))) void* gas_p;
typedef __attribute__((address_space(3))) void* las_p;

// fast gelu: tanh form via hardware exp + rcp (max abs err ~1e-3 vs erf form)
__device__ __forceinline__ float gelu_f(float v) {
    float u = 0.7978845608028654f * fmaf(0.044715f * v * v, v, v);
    float uc = fminf(fmaxf(u, -15.f), 15.f);
    float e = __expf(2.f * uc);
    return 0.5f * v * (1.f + (e - 1.f) * __builtin_amdgcn_rcpf(e + 1.f));
}
__device__ __forceinline__ unsigned short f2bf(float f) {  // RNE f32->bf16
    unsigned int u = __float_as_uint(f);
    u += 0x7fffu + ((u >> 16) & 1u);
    return (unsigned short)(u >> 16);
}
__device__ __forceinline__ float bf2f(unsigned short u) {
    return __uint_as_float((unsigned int)u << 16);
}

// swizzled fragment read from a [R][64] tile: XOR 16B-block index with (row&7).
__device__ __forceinline__ bf16x8 fr(const unsigned short* lds, int row, int kcol) {
    return *(const bf16x8*)(lds + row * 64 + ((((kcol >> 3) ^ (row & 7)) << 3)));
}

// stage ROWS x 64 bf16 tile (row-major, ld elems) into LDS [ROWS][64] (linear dest,
// inverse-swizzled source)
template<int ROWS, int THREADS>
__device__ __forceinline__ void stage64(const unsigned short* __restrict__ src, int ld, int k0,
                                        unsigned short* lds, int t) {
    constexpr int EPI = THREADS * 8;   // elems per iter
#pragma unroll
    for (int i = 0; i < (ROWS * 64) / EPI; i++) {
        int e = i * EPI + t * 8;
        int r = e >> 6;
        int k = (((e >> 3) & 7) ^ (r & 7)) << 3;
        const unsigned short* g = src + (size_t)r * ld + (k0 + k);
        unsigned short* l = lds + i * EPI + (t >> 6) * 512;   // wave-uniform base
        __builtin_amdgcn_global_load_lds((gas_p)g, (las_p)l, 16, 0, 0);
    }
}

// stage ROWS x 64 tile of UT (bc-rows) for head h, same swizzle
template<int ROWS, int THREADS>
__device__ __forceinline__ void stageUT(const unsigned short* __restrict__ UT, int h, int rbase,
                                        int k0, unsigned short* lds, int t) {
    constexpr int EPI = THREADS * 8;
#pragma unroll
    for (int i = 0; i < (ROWS * 64) / EPI; i++) {
        int e = i * EPI + t * 8;
        int r = e >> 6;
        int k = (((e >> 3) & 7) ^ (r & 7)) << 3;
        int row = rbase + r;
        const unsigned short* g = UT + ((size_t)((row >> 4) * Hdim + h)) * LL
                                  + (row & 15) * PCH + (k0 + k);
        unsigned short* l = lds + i * EPI + (t >> 6) * 512;
        __builtin_amdgcn_global_load_lds((gas_p)g, (las_p)l, 16, 0, 0);
    }
}

// ---------------- tables ----------------
__global__ void k_tab(const float* __restrict__ logdt, const float* __restrict__ Are,
                      const float* __restrict__ Aim, const float* __restrict__ Cre,
                      const float* __restrict__ Cim, float2* __restrict__ wtab,
                      float2* __restrict__ wptab, float2* __restrict__ ceff) {
    int idx = blockIdx.x * blockDim.x + threadIdx.x;
    if (idx >= Hdim * NM) return;
    int h = idx >> 5;
    float dt = expf(logdt[h]);
    double dar = (double)dt * (double)Are[idx];
    double dai = (double)dt * (double)Aim[idx];
    double wm = exp(dar);
    double wr = wm * cos(dai), wi = wm * sin(dai);
    wtab[idx] = make_float2((float)wr, (float)wi);
    double pm = exp(dar * (double)PCH);
    double pai = dai * (double)PCH;
    wptab[idx] = make_float2((float)(pm * cos(pai)), (float)(pm * sin(pai)));
    double are = (double)Are[idx], aim = (double)Aim[idx];
    double den = are * are + aim * aim;
    double nr = wr - 1.0, ni = wi;
    double qr = (nr * are + ni * aim) / den;
    double qi = (ni * are - nr * aim) / den;
    for (int ch = 0; ch < 2; ch++) {
        double cr = (double)Cre[ch * Hdim * NM + idx];
        double ci = (double)Cim[ch * Hdim * NM + idx];
        ceff[ch * Hdim * NM + idx] = make_float2((float)(cr * qr - ci * qi),
                                                 (float)(cr * qi + ci * qr));
    }
}

// ---------------- weight transpose + bf16 cast ----------------
__global__ void k_wt(const float* __restrict__ W1, const float* __restrict__ W2,
                     const float* __restrict__ W3, unsigned short* __restrict__ W1T,
                     unsigned short* __restrict__ W2T, unsigned short* __restrict__ W3T) {
    int t = blockIdx.x * 256 + threadIdx.x;  // 131072 threads
    int k = t >> 9, n = t & 511;             // W1,W2: [256][512]
    W1T[n * 256 + k] = f2bf(W1[t]);
    W2T[n * 256 + k] = f2bf(W2[t]);
    int k3 = t >> 8, n3 = t & 255;           // W3: [512][256]
    W3T[n3 * 512 + k3] = f2bf(W3[t]);
}

// ---------------- table builder: Q tiles + Wp slices (parts 0-3), Kcat (part 4) ----------------
__global__ __launch_bounds__(256) void k_abw(const float* __restrict__ logdt,
                                             const float* __restrict__ Are,
                                             const float* __restrict__ Aim,
                                             const float2* __restrict__ CE,
                                             unsigned short* __restrict__ Q,
                                             unsigned short* __restrict__ Wp,
                                             float* __restrict__ Kcat) {
    __shared__ float2 wpow[32][258];   // w^j, j=0..256 (padded row to break bank collisions)
    __shared__ float2 ce_s[64];        // [0..31] fwd, [32..63] bwd
    int h = blockIdx.x;
    int part = blockIdx.y;             // 0..3: Q tile + Wp slice ; 4: Kcat
    int t = threadIdx.x;
    if (t < 64) ce_s[t] = CE[(t >> 5) * (Hdim * NM) + h * NM + (t & 31)];
    {   // build wpow: thread = n*8+seg; j = seg + 8q, stepping by w^8
        int n = t >> 3, seg = t & 7;
        float dt = expf(logdt[h]);
        float dar = dt * Are[h * NM + n], dai = dt * Aim[h * NM + n];
        float em = expf(dar);
        float wr = em * cosf(dai), wi = em * sinf(dai);
        float ar = wr, ai = wi;            // w^8 by squaring thrice
#pragma unroll
        for (int s = 0; s < 3; s++) { float nr = ar * ar - ai * ai, ni = 2.f * ar * ai; ar = nr; ai = ni; }
        float m = expf((float)seg * dar), ang = (float)seg * dai;
        float vr = m * cosf(ang), vi = m * sinf(ang);
        for (int q = 0; q < 32; q++) {
            wpow[n][seg + 8 * q] = make_float2(vr, vi);
            float nr2 = vr * ar - vi * ai;
            float ni2 = vr * ai + vi * ar;
            vr = nr2; vi = ni2;
        }
        if (seg == 0) wpow[n][256] = make_float2(vr, vi);   // w^256
    }
    __syncthreads();
    if (part == 4) {   // Kcat: kcat[255+d]=kf[d], kcat[254-m]=kb[m]
        float kfv = 0.f, kbv = 0.f;
#pragma unroll
        for (int n = 0; n < NM; n++) {
            float2 wv = wpow[n][t];
            float2 cf = ce_s[n], cb = ce_s[32 + n];
            kfv = fmaf(cf.x, wv.x, fmaf(-cf.y, wv.y, kfv));
            kbv = fmaf(cb.x, wv.x, fmaf(-cb.y, wv.y, kbv));
        }
        Kcat[(size_t)h * 512 + 255 + t] = 2.f * kfv;
        if (t < 255) Kcat[(size_t)h * 512 + 254 - t] = 2.f * kbv;
        if (t == 255) Kcat[(size_t)h * 512 + 511] = 0.f;
        return;
    }
    // Q tile: j in [part*64, part*64+64), 2 rows per iter
    for (int jj = 0; jj < 32; jj++) {
        int j = part * 64 + jj * 2 + (t >> 7);
        int tq = t & 127;
        int n = (tq & 63) >> 1, reim = tq & 1;
        float2 c = (tq < 64) ? ce_s[n] : ce_s[32 + n];
        float2 wv = (tq < 64) ? wpow[n][j + 1] : wpow[n][255 - j];
        float re = c.x * wv.x - c.y * wv.y;
        float im = c.x * wv.y + c.y * wv.x;
        Q[((size_t)h * 256 + j) * 128 + tq] = f2bf(reim ? -2.f * im : 2.f * re);
    }
    // Wp slice: rows [part*32, part*32+32)
    for (int rr = 0; rr < 32; rr++) {
        int r = part * 32 + rr;
        int n = (r & 63) >> 1, reim = r & 1, dir = r >> 6;
        float2 wv = wpow[n][dir ? t : 255 - t];
        Wp[((size_t)h * 128 + r) * 256 + t] = f2bf(reim ? wv.y : wv.x);
    }
}

// ---------------- fused layernorm + transpose: x (b,l,h) fp32 -> UT (b,h,l) bf16 ----------------
__global__ __launch_bounds__(256) void k_lntr(const float* __restrict__ x,
                                              const float* __restrict__ g,
                                              const float* __restrict__ bt,
                                              unsigned short* __restrict__ UT) {
    __shared__ unsigned short lds[256][65];
    int lt = blockIdx.x, b = blockIdx.y;
    int t = threadIdx.x;
    int lane = t & 63, w = t >> 6;
    float4 gg = ((const float4*)g)[lane];
    float4 bb = ((const float4*)bt)[lane];
#pragma unroll
    for (int q = 0; q < 16; q++) {
        int l = q * 4 + w;
        float4 v = ((const float4*)(x + ((size_t)(b * LL + lt * 64 + l)) * Hdim))[lane];
        float s = v.x + v.y + v.z + v.w;
        float ss = v.x * v.x + v.y * v.y + v.z * v.z + v.w * v.w;
#pragma unroll
        for (int o = 1; o < 64; o <<= 1) { s += __shfl_xor(s, o, 64); ss += __shfl_xor(ss, o, 64); }
        float mean = s * (1.0f / Hdim);
        float var = ss * (1.0f / Hdim) - mean * mean;
        float rstd = rsqrtf(var + 1e-5f);
        lds[lane * 4 + 0][l] = f2bf((v.x - mean) * rstd * gg.x + bb.x);
        lds[lane * 4 + 1][l] = f2bf((v.y - mean) * rstd * gg.y + bb.y);
        lds[lane * 4 + 2][l] = f2bf((v.z - mean) * rstd * gg.z + bb.z);
        lds[lane * 4 + 3][l] = f2bf((v.w - mean) * rstd * gg.w + bb.w);
    }
    __syncthreads();
    for (int q = 0; q < 64; q++) {
        int idx = q * 256 + t;
        int hh = idx >> 6, ll = idx & 63;
        UT[((size_t)(b * Hdim + hh)) * LL + lt * 64 + ll] = lds[hh][ll];
    }
}

// ---------------- layernorm (bf16 in, bf16 out): T2 = LN(X2) ----------------
__global__ void k_ln_bf(const unsigned short* __restrict__ x, const float* __restrict__ g,
                        const float* __restrict__ bt, unsigned short* __restrict__ out) {
    int row = blockIdx.x * 4 + (threadIdx.x >> 6);
    int lane = threadIdx.x & 63;
    ushort4 u4 = ((const ushort4*)(x + (size_t)row * Hdim))[lane];
    float vx = bf2f(u4.x), vy = bf2f(u4.y), vz = bf2f(u4.z), vw = bf2f(u4.w);
    float s = vx + vy + vz + vw;
    float ss = vx * vx + vy * vy + vz * vz + vw * vw;
#pragma unroll
    for (int o = 1; o < 64; o <<= 1) { s += __shfl_xor(s, o, 64); ss += __shfl_xor(ss, o, 64); }
    float mean = s * (1.0f / Hdim);
    float var = ss * (1.0f / Hdim) - mean * mean;
    float rstd = rsqrtf(var + 1e-5f);
    float4 gg = ((const float4*)g)[lane];
    float4 bb = ((const float4*)bt)[lane];
    ushort4 o;
    o.x = f2bf((vx - mean) * rstd * gg.x + bb.x);
    o.y = f2bf((vy - mean) * rstd * gg.y + bb.y);
    o.z = f2bf((vz - mean) * rstd * gg.z + bb.z);
    o.w = f2bf((vw - mean) * rstd * gg.w + bb.w);
    ((ushort4*)(out + (size_t)row * Hdim))[lane] = o;
}

// ---------------- state GEMM (LDS-staged, swizzled): Zg[h][bc][r], 256x128 per h ----------------
__global__ __launch_bounds__(512) void k_zgemm(const unsigned short* __restrict__ UT,
                                               const unsigned short* __restrict__ Wp,
                                               float* __restrict__ Zg) {
    __shared__ unsigned short As[256 * 64];
    __shared__ unsigned short Bs[128 * 64];
    int h = blockIdx.x;
    int t = threadIdx.x;
    int w = t >> 6, lane = t & 63;
    int m0 = (w & 3) * 64;     // 4 row groups
    int nb = (w >> 2) * 64;    // 2 col groups
    int lr = lane & 15, lk = (lane >> 4) * 8;
    f32x4 acc[4][4];
#pragma unroll
    for (int i = 0; i < 4; i++)
#pragma unroll
        for (int jx = 0; jx < 4; jx++) acc[i][jx] = (f32x4){0.f, 0.f, 0.f, 0.f};
    for (int k0 = 0; k0 < 256; k0 += 64) {
        stageUT<256, 512>(UT, h, 0, k0, As, t);
        stage64<128, 512>(Wp + (size_t)h * 128 * 256, 256, k0, Bs, t);
        __syncthreads();
#pragma unroll
        for (int kk = 0; kk < 64; kk += 32) {
            bf16x8 a[4], b[4];
#pragma unroll
            for (int mi = 0; mi < 4; mi++) a[mi] = fr(As, m0 + mi * 16 + lr, kk + lk);
#pragma unroll
            for (int nf = 0; nf < 4; nf++) b[nf] = fr(Bs, nb + nf * 16 + lr, kk + lk);
#pragma unroll
            for (int mi = 0; mi < 4; mi++)
#pragma unroll
                for (int nf = 0; nf < 4; nf++)
                    acc[mi][nf] = __builtin_amdgcn_mfma_f32_16x16x32_bf16(a[mi], b[nf], acc[mi][nf], 0, 0, 0);
        }
        __syncthreads();
    }
#pragma unroll
    for (int mi = 0; mi < 4; mi++)
#pragma unroll
        for (int nf = 0; nf < 4; nf++) {
            int col = nb + nf * 16 + lr;
#pragma unroll
            for (int r = 0; r < 4; r++) {
                int row = m0 + mi * 16 + (lane >> 4) * 4 + r;
                Zg[((size_t)h * 256 + row) * 128 + col] = acc[mi][nf][r];
            }
        }
}

// ---------------- prefix over chunks -> Zpacked bf16 [h][bc][128] ----------------
__global__ void k_prefix2(const float* __restrict__ Zg, const float2* __restrict__ wptab,
                          unsigned short* __restrict__ ZP) {
    int t = blockIdx.x * 256 + threadIdx.x;
    int n = t & 31;
    int h = (t >> 5) & 255;
    int b = (t >> 13) & 15;
    int dir = (t >> 17) & 1;
    float2 wp = wptab[h * NM + n];
    float sr = 0.f, si = 0.f;
    int ro = dir ? 64 + 2 * n : 2 * n;
    if (dir == 0) {
        for (int c = 0; c < NCH; c++) {
            size_t base = ((size_t)h * 256 + b * NCH + c) * 128;
            ZP[base + ro] = f2bf(sr);
            ZP[base + ro + 1] = f2bf(si);
            float zr = Zg[base + ro], zi = Zg[base + ro + 1];
            float nr = fmaf(wp.x, sr, fmaf(-wp.y, si, zr));
            float ni = fmaf(wp.y, sr, fmaf(wp.x, si, zi));
            sr = nr; si = ni;
        }
    } else {
        for (int c = NCH - 1; c >= 0; c--) {
            size_t base = ((size_t)h * 256 + b * NCH + c) * 128;
            ZP[base + ro] = f2bf(sr);
            ZP[base + ro + 1] = f2bf(si);
            float zr = Zg[base + ro], zi = Zg[base + ro + 1];
            float nr = fmaf(wp.x, sr, fmaf(-wp.y, si, zr));
            float ni = fmaf(wp.y, sr, fmaf(wp.x, si, zi));
            sr = nr; si = ni;
        }
    }
}

// ---------------- conv GEMM: u-part B-tiles built in-LDS from Kcat; z-part staged from Q ----------------
__global__ __launch_bounds__(512) void k_conv(const unsigned short* __restrict__ UT,
                                              const unsigned short* __restrict__ ZP,
                                              const unsigned short* __restrict__ Q,
                                              const float* __restrict__ Kcat,
                                              const float* __restrict__ Dsk,
                                              unsigned short* __restrict__ Yt) {
    __shared__ unsigned short As[128 * 64];
    __shared__ unsigned short Bs[256 * 64];
    __shared__ float kcs[512];
    // XCD-chunked swizzle (512 blocks, 512%8==0 -> bijective)
    int wgid = ((int)blockIdx.x % 8) * 64 + (int)blockIdx.x / 8;
    int h = wgid >> 1;
    int mbase = (wgid & 1) * 128;
    int t = threadIdx.x;
    int w = t >> 6, lane = t & 63;
    int m0 = (w & 1) * 64;     // 2 row groups
    int nb = (w >> 1) * 64;    // 4 col groups (full 256 j)
    int lr = lane & 15, lk = (lane >> 4) * 8;
    float dsk = Dsk[h];
    kcs[t] = Kcat[(size_t)h * 512 + t];   // 512 threads, one each
    __syncthreads();
    f32x4 acc[4][4];
#pragma unroll
    for (int i = 0; i < 4; i++)
#pragma unroll
        for (int jx = 0; jx < 4; jx++) acc[i][jx] = (f32x4){0.f, 0.f, 0.f, 0.f};
    // u-part: K = 256; B-tile built from kcat (Toeplitz + diag)
    for (int k0 = 0; k0 < 256; k0 += 64) {
        stageUT<128, 512>(UT, h, mbase, k0, As, t);
#pragma unroll
        for (int gq = 0; gq < 4; gq++) {   // 256x64 tile, 8 elems/thread/iter
            int e = gq * 4096 + t * 8;
            int j = e >> 6;
            int i0 = k0 + (e & 63);
            union { bf16x8 v; unsigned short u[8]; } pk;
#pragma unroll
            for (int q = 0; q < 8; q++) {
                int i = i0 + q;
                float f = kcs[255 + j - i];
                if (i == j) f += dsk;
                pk.u[q] = f2bf(f);
            }
            *(bf16x8*)(Bs + j * 64 + (((((e & 63) >> 3)) ^ (j & 7)) << 3)) = pk.v;
        }
        __syncthreads();
#pragma unroll
        for (int kk = 0; kk < 64; kk += 32) {
            bf16x8 a[4], b[4];
#pragma unroll
            for (int mi = 0; mi < 4; mi++) a[mi] = fr(As, m0 + mi * 16 + lr, kk + lk);
#pragma unroll
            for (int nf = 0; nf < 4; nf++) b[nf] = fr(Bs, nb + nf * 16 + lr, kk + lk);
#pragma unroll
            for (int mi = 0; mi < 4; mi++)
#pragma unroll
                for (int nf = 0; nf < 4; nf++)
                    acc[mi][nf] = __builtin_amdgcn_mfma_f32_16x16x32_bf16(a[mi], b[nf], acc[mi][nf], 0, 0, 0);
        }
        __syncthreads();
    }
    // z-part: K = 128 from ZP (A) and Q (B)
    for (int k0 = 0; k0 < 128; k0 += 64) {
        stage64<128, 512>(ZP + ((size_t)h * 256 + mbase) * 128, 128, k0, As, t);
        stage64<256, 512>(Q + (size_t)h * 256 * 128, 128, k0, Bs, t);
        __syncthreads();
#pragma unroll
        for (int kk = 0; kk < 64; kk += 32) {
            bf16x8 a[4], b[4];
#pragma unroll
            for (int mi = 0; mi < 4; mi++) a[mi] = fr(As, m0 + mi * 16 + lr, kk + lk);
#pragma unroll
            for (int nf = 0; nf < 4; nf++) b[nf] = fr(Bs, nb + nf * 16 + lr, kk + lk);
#pragma unroll
            for (int mi = 0; mi < 4; mi++)
#pragma unroll
                for (int nf = 0; nf < 4; nf++)
                    acc[mi][nf] = __builtin_amdgcn_mfma_f32_16x16x32_bf16(a[mi], b[nf], acc[mi][nf], 0, 0, 0);
        }
        __syncthreads();
    }
#pragma unroll
    for (int mi = 0; mi < 4; mi++)
#pragma unroll
        for (int nf = 0; nf < 4; nf++) {
            int col = nb + nf * 16 + lr;
#pragma unroll
            for (int r = 0; r < 4; r++) {
                int row = mbase + m0 + mi * 16 + (lane >> 4) * 4 + r;
                Yt[(size_t)h * 65536 + row * 256 + col] = f2bf(gelu_f(acc[mi][nf][r]));
            }
        }
}

// ---------------- transpose Yt [h][bc][j] -> G (b, c*P+j, h) bf16 ----------------
__global__ void k_trg(const unsigned short* __restrict__ Yt, unsigned short* __restrict__ G) {
    __shared__ unsigned short lds[64][65];
    int bc = blockIdx.x;
    int h0 = blockIdx.y * 64, j0 = blockIdx.z * 64;
    int t = threadIdx.x;
#pragma unroll
    for (int q = 0; q < 16; q++) {
        int idx = q * 256 + t;
        int hh = idx >> 6, jj = idx & 63;
        lds[hh][jj] = Yt[(size_t)(h0 + hh) * 65536 + bc * 256 + j0 + jj];
    }
    __syncthreads();
    int b = bc >> 4, c = bc & 15;
#pragma unroll
    for (int q = 0; q < 16; q++) {
        int idx = q * 256 + t;
        int jj = idx >> 6, hh = idx & 63;
        G[((size_t)(b * LL + c * PCH + j0 + jj)) * Hdim + h0 + hh] = lds[hh][jj];
    }
}

// ---------------- GEMM1 (512 thr, 128 pairs/block): X2 = bf16(x + glu(G@Wout + bo)) ----------------
__global__ __launch_bounds__(512) void k_gemm1(const unsigned short* __restrict__ Gm,
                                               const unsigned short* __restrict__ W1T,
                                               const float* __restrict__ bo,
                                               const float* __restrict__ xin,
                                               unsigned short* __restrict__ X2) {
    __shared__ unsigned short As[128 * 64];
    __shared__ unsigned short BsA[128 * 64];
    __shared__ unsigned short BsB[128 * 64];
    int t = threadIdx.x;
    int w = t >> 6, lane = t & 63;
    int m0w = (w & 1) * 64;          // 2 row halves
    int n0w = (w >> 1) * 32;         // 4 pair-groups of 32 pairs
    int lr = lane & 15, lk = (lane >> 4) * 8;
    int mblk = blockIdx.x * 128, nblk = blockIdx.y * 128;   // pair base
    const unsigned short* Ab  = Gm + (size_t)mblk * 256;
    const unsigned short* BbA = W1T + (size_t)nblk * 256;
    const unsigned short* BbB = W1T + (size_t)(nblk + 256) * 256;
    f32x4 acc[4][4];
#pragma unroll
    for (int i = 0; i < 4; i++)
#pragma unroll
        for (int j = 0; j < 4; j++) acc[i][j] = (f32x4){0.f, 0.f, 0.f, 0.f};
    for (int k0 = 0; k0 < 256; k0 += 64) {
        stage64<128, 512>(Ab, 256, k0, As, t);
        stage64<128, 512>(BbA, 256, k0, BsA, t);
        stage64<128, 512>(BbB, 256, k0, BsB, t);
        __syncthreads();
#pragma unroll
        for (int kk = 0; kk < 64; kk += 32) {
            bf16x8 a[4], bA[2], bB[2];
#pragma unroll
            for (int mi = 0; mi < 4; mi++)
                a[mi] = fr(As, m0w + mi * 16 + lr, kk + lk);
#pragma unroll
            for (int nf = 0; nf < 2; nf++) {
                bA[nf] = fr(BsA, n0w + nf * 16 + lr, kk + lk);
                bB[nf] = fr(BsB, n0w + nf * 16 + lr, kk + lk);
            }
#pragma unroll
            for (int mi = 0; mi < 4; mi++)
#pragma unroll
                for (int nf = 0; nf < 2; nf++) {
                    acc[mi][nf] = __builtin_amdgcn_mfma_f32_16x16x32_bf16(a[mi], bA[nf], acc[mi][nf], 0, 0, 0);
                    acc[mi][nf + 2] = __builtin_amdgcn_mfma_f32_16x16x32_bf16(a[mi], bB[nf], acc[mi][nf + 2], 0, 0, 0);
                }
        }
        __syncthreads();
    }
#pragma unroll
    for (int mi = 0; mi < 4; mi++)
#pragma unroll
        for (int nf = 0; nf < 2; nf++) {
            int col = nblk + n0w + nf * 16 + lr;
            float biasA = bo[col], biasB = bo[col + 256];
#pragma unroll
            for (int r = 0; r < 4; r++) {
                int row = mblk + m0w + mi * 16 + (lane >> 4) * 4 + r;
                float zzA = acc[mi][nf][r] + biasA;
                float zzB = acc[mi][nf + 2][r] + biasB;
                float v = zzA * __builtin_amdgcn_rcpf(1.0f + __expf(-zzB));
                size_t idx = (size_t)row * 256 + col;
                X2[idx] = f2bf(xin[idx] + v);
            }
        }
}

// ---------------- GEMM2 (512 thr, 256 cols/block): M = gelu(T2@W2 + b2) bf16 ----------------
__global__ __launch_bounds__(512) void k_gemm2(const unsigned short* __restrict__ T2,
                                               const unsigned short* __restrict__ W2T,
                                               const float* __restrict__ b2,
                                               unsigned short* __restrict__ Mo) {
    __shared__ unsigned short As[128 * 64];
    __shared__ unsigned short Bs[256 * 64];
    int t = threadIdx.x;
    int w = t >> 6, lane = t & 63;
    int m0w = (w & 1) * 64;          // 2 row halves
    int n0w = (w >> 1) * 64;         // 4 col groups of 64
    int lr = lane & 15, lk = (lane >> 4) * 8;
    int mblk = blockIdx.x * 128, nblk = blockIdx.y * 256;
    const unsigned short* Ab = T2 + (size_t)mblk * 256;
    const unsigned short* Bb = W2T + (size_t)nblk * 256;
    f32x4 acc[4][4];
#pragma unroll
    for (int i = 0; i < 4; i++)
#pragma unroll
        for (int j = 0; j < 4; j++) acc[i][j] = (f32x4){0.f, 0.f, 0.f, 0.f};
    for (int k0 = 0; k0 < 256; k0 += 64) {
        stage64<128, 512>(Ab, 256, k0, As, t);
        stage64<256, 512>(Bb, 256, k0, Bs, t);
        __syncthreads();
#pragma unroll
        for (int kk = 0; kk < 64; kk += 32) {
            bf16x8 a[4], b[4];
#pragma unroll
            for (int mi = 0; mi < 4; mi++)
                a[mi] = fr(As, m0w + mi * 16 + lr, kk + lk);
#pragma unroll
            for (int nf = 0; nf < 4; nf++)
                b[nf] = fr(Bs, n0w + nf * 16 + lr, kk + lk);
#pragma unroll
            for (int mi = 0; mi < 4; mi++)
#pragma unroll
                for (int nf = 0; nf < 4; nf++)
                    acc[mi][nf] = __builtin_amdgcn_mfma_f32_16x16x32_bf16(a[mi], b[nf], acc[mi][nf], 0, 0, 0);
        }
        __syncthreads();
    }
#pragma unroll
    for (int mi = 0; mi < 4; mi++)
#pragma unroll
        for (int nf = 0; nf < 4; nf++) {
            int col = nblk + n0w + nf * 16 + lr;
            float bias = b2[col];
#pragma unroll
            for (int r = 0; r < 4; r++) {
                int row = mblk + m0w + mi * 16 + (lane >> 4) * 4 + r;
                Mo[(size_t)row * 512 + col] = f2bf(gelu_f(acc[mi][nf][r] + bias));
            }
        }
}

// ---------------- GEMM3 (512 thr, full 256 cols): out = X2 + M@W3 + b3 ----------------
__global__ __launch_bounds__(512) void k_gemm3(const unsigned short* __restrict__ Mb,
                                               const unsigned short* __restrict__ W3T,
                                               const float* __restrict__ b3,
                                               const unsigned short* __restrict__ X2,
                                               float* __restrict__ out) {
    __shared__ unsigned short As[128 * 64];
    __shared__ unsigned short Bs[256 * 64];
    int t = threadIdx.x;
    int w = t >> 6, lane = t & 63;
    int m0w = (w & 1) * 64;          // 2 row halves
    int n0w = (w >> 1) * 64;         // 4 col groups (full 256)
    int lr = lane & 15, lk = (lane >> 4) * 8;
    int mblk = blockIdx.x * 128;
    const unsigned short* Ab = Mb + (size_t)mblk * 512;
    f32x4 acc[4][4];
#pragma unroll
    for (int i = 0; i < 4; i++)
#pragma unroll
        for (int j = 0; j < 4; j++) acc[i][j] = (f32x4){0.f, 0.f, 0.f, 0.f};
    for (int k0 = 0; k0 < 512; k0 += 64) {
        stage64<128, 512>(Ab, 512, k0, As, t);
        stage64<256, 512>(W3T, 512, k0, Bs, t);
        __syncthreads();
#pragma unroll
        for (int kk = 0; kk < 64; kk += 32) {
            bf16x8 a[4], b[4];
#pragma unroll
            for (int mi = 0; mi < 4; mi++)
                a[mi] = fr(As, m0w + mi * 16 + lr, kk + lk);
#pragma unroll
            for (int nf = 0; nf < 4; nf++)
                b[nf] = fr(Bs, n0w + nf * 16 + lr, kk + lk);
#pragma unroll
            for (int mi = 0; mi < 4; mi++)
#pragma unroll
                for (int nf = 0; nf < 4; nf++)
                    acc[mi][nf] = __builtin_amdgcn_mfma_f32_16x16x32_bf16(a[mi], b[nf], acc[mi][nf], 0, 0, 0);
        }
        __syncthreads();
    }
#pragma unroll
    for (int mi = 0; mi < 4; mi++)
#pragma unroll
        for (int nf = 0; nf < 4; nf++) {
            int col = n0w + nf * 16 + lr;
            float bias = b3[col];
#pragma unroll
            for (int r = 0; r < 4; r++) {
                int row = mblk + m0w + mi * 16 + (lane >> 4) * 4 + r;
                size_t idx = (size_t)row * 256 + col;
                out[idx] = bf2f(X2[idx]) + acc[mi][nf][r] + bias;
            }
        }
}

extern "C" void kernel_launch(void* const* d_in, const int* in_sizes, int n_in,
                              void* d_out, int out_size, void* d_ws, size_t ws_size,
                              hipStream_t stream) {
    const float* x     = (const float*)d_in[0];
    const float* ln1g  = (const float*)d_in[1];
    const float* ln1b  = (const float*)d_in[2];
    const float* ln2g  = (const float*)d_in[3];
    const float* ln2b  = (const float*)d_in[4];
    const float* logdt = (const float*)d_in[5];
    const float* Are   = (const float*)d_in[6];
    const float* Aim   = (const float*)d_in[7];
    const float* Cre   = (const float*)d_in[8];
    const float* Cim   = (const float*)d_in[9];
    const float* Dsk   = (const float*)d_in[10];
    const float* Wout  = (const float*)d_in[11];
    const float* bo    = (const float*)d_in[12];
    const float* W2    = (const float*)d_in[13];
    const float* b2    = (const float*)d_in[14];
    const float* W3    = (const float*)d_in[15];
    const float* b3    = (const float*)d_in[16];

    char* ws = (char*)d_ws;
    unsigned short* Q    = (unsigned short*)(ws + OFF_Q);
    float*          Kc   = (float*)(ws + OFF_KC);
    unsigned short* Wp   = (unsigned short*)(ws + OFF_WPM);
    unsigned short* X2   = (unsigned short*)(ws + OFF_Q);      // bf16, after Q/Kcat dead
    unsigned short* UT   = (unsigned short*)(ws + OFF_UT);
    float*          Zg   = (float*)(ws + OFF_ZG);
    unsigned short* Yt   = (unsigned short*)(ws + OFF_ZG);
    unsigned short* Mb   = (unsigned short*)(ws + OFF_M);
    unsigned short* ZP   = (unsigned short*)(ws + OFF_ZP);
    unsigned short* G    = (unsigned short*)(ws + OFF_G);
    float2*         WT   = (float2*)(ws + OFF_WTAB);
    float2*         WPT  = (float2*)(ws + OFF_WPT);
    float2*         CE   = (float2*)(ws + OFF_CE);
    unsigned short* W1T  = (unsigned short*)(ws + OFF_W1T);
    unsigned short* W2T  = (unsigned short*)(ws + OFF_W2T);
    unsigned short* W3T  = (unsigned short*)(ws + OFF_W3T);

    k_tab<<<32, 256, 0, stream>>>(logdt, Are, Aim, Cre, Cim, WT, WPT, CE);
    k_wt<<<512, 256, 0, stream>>>(Wout, W2, W3, W1T, W2T, W3T);
    k_lntr<<<dim3(64, 16), 256, 0, stream>>>(x, ln1g, ln1b, UT);
    k_abw<<<dim3(256, 5), 256, 0, stream>>>(logdt, Are, Aim, CE, Q, Wp, Kc);
    k_zgemm<<<256, 512, 0, stream>>>(UT, Wp, Zg);
    k_prefix2<<<1024, 256, 0, stream>>>(Zg, WPT, ZP);
    k_conv<<<512, 512, 0, stream>>>(UT, ZP, Q, Kc, Dsk, Yt);
    k_trg<<<dim3(256, 4, 4), 256, 0, stream>>>(Yt, G);
    k_gemm1<<<dim3(512, 2), 512, 0, stream>>>(G, W1T, bo, x, X2);
    k_ln_bf<<<NB * LL / 4, 256, 0, stream>>>(X2, ln2g, ln2b, G);
    k_gemm2<<<dim3(512, 2), 512, 0, stream>>>(G, W2T, b2, Mb);
    k_gemm3<<<512, 512, 0, stream>>>(Mb, W3T, b3, X2, (float*)d_out);
}

// Round 16
// 234.653 us; speedup vs baseline: 1.4975x; 1.0181x over previous
//
#include <hip/hip_runtime.h>
#include <hip/hip_bf16.h>

typedef __attribute__((ext_vector_type(8))) short bf16x8;
typedef __attribute__((ext_vector_type(4))) float f32x4;

#define Hdim 256
#define NM 32      // N2 modes
#define NB 16      // batch
#define LL 4096    // seq len
#define PCH 256    // chunk length
#define NCH 16     // chunks = LL/PCH

// ---- workspace layout (bytes) ----
#define OFF_Q    ((size_t)0)
#define OFF_KC   ((size_t)16777216)
#define OFF_WPM  ((size_t)50331648)    // Wp bf16 [h][128][256] 16,777,216
#define OFF_UT   ((size_t)67108864)    // U_T bf16 [B][H][L] 33554432
#define OFF_ZG   ((size_t)100663296)   // Zg bf16 [h][bc][128] ; then Yt bf16
#define OFF_M    ((size_t)67108864)    // M bf16 (spans UT+ZG, alive gemm2->gemm3)
#define OFF_ZP   ((size_t)134217728)   // Zpacked bf16 [h][bc][128]
#define OFF_G    ((size_t)150994944)   // G bf16 (b,l,h) ; reused as T2
#define OFF_WTAB ((size_t)185073664)
#define OFF_WPT  ((size_t)185139200)
#define OFF_CE   ((size_t)185204736)
#define OFF_W1T  ((size_t)185335808)
#define OFF_W2T  ((size_t)185597952)
#define OFF_W3T  ((size_t)185860096)

typedef const __attribute__((address_space(1))) void* gas_p;
typedef __attribute__((address_space(3))) void* las_p;

// fast gelu: tanh form via hardware exp + rcp (max abs err ~1e-3 vs erf form)
__device__ __forceinline__ float gelu_f(float v) {
    float u = 0.7978845608028654f * fmaf(0.044715f * v * v, v, v);
    float uc = fminf(fmaxf(u, -15.f), 15.f);
    float e = __expf(2.f * uc);
    return 0.5f * v * (1.f + (e - 1.f) * __builtin_amdgcn_rcpf(e + 1.f));
}
__device__ __forceinline__ unsigned short f2bf(float f) {  // RNE f32->bf16
    unsigned int u = __float_as_uint(f);
    u += 0x7fffu + ((u >> 16) & 1u);
    return (unsigned short)(u >> 16);
}
__device__ __forceinline__ float bf2f(unsigned short u) {
    return __uint_as_float((unsigned int)u << 16);
}

// swizzled fragment read from a [R][64] tile: XOR 16B-block index with (row&7).
__device__ __forceinline__ bf16x8 fr(const unsigned short* lds, int row, int kcol) {
    return *(const bf16x8*)(lds + row * 64 + ((((kcol >> 3) ^ (row & 7)) << 3)));
}

// stage ROWS x 64 bf16 tile (row-major, ld elems) into LDS [ROWS][64] (linear dest,
// inverse-swizzled source)
template<int ROWS, int THREADS>
__device__ __forceinline__ void stage64(const unsigned short* __restrict__ src, int ld, int k0,
                                        unsigned short* lds, int t) {
    constexpr int EPI = THREADS * 8;   // elems per iter
#pragma unroll
    for (int i = 0; i < (ROWS * 64) / EPI; i++) {
        int e = i * EPI + t * 8;
        int r = e >> 6;
        int k = (((e >> 3) & 7) ^ (r & 7)) << 3;
        const unsigned short* g = src + (size_t)r * ld + (k0 + k);
        unsigned short* l = lds + i * EPI + (t >> 6) * 512;   // wave-uniform base
        __builtin_amdgcn_global_load_lds((gas_p)g, (las_p)l, 16, 0, 0);
    }
}

// stage ROWS x 64 tile of UT (bc-rows) for head h, same swizzle
template<int ROWS, int THREADS>
__device__ __forceinline__ void stageUT(const unsigned short* __restrict__ UT, int h, int rbase,
                                        int k0, unsigned short* lds, int t) {
    constexpr int EPI = THREADS * 8;
#pragma unroll
    for (int i = 0; i < (ROWS * 64) / EPI; i++) {
        int e = i * EPI + t * 8;
        int r = e >> 6;
        int k = (((e >> 3) & 7) ^ (r & 7)) << 3;
        int row = rbase + r;
        const unsigned short* g = UT + ((size_t)((row >> 4) * Hdim + h)) * LL
                                  + (row & 15) * PCH + (k0 + k);
        unsigned short* l = lds + i * EPI + (t >> 6) * 512;
        __builtin_amdgcn_global_load_lds((gas_p)g, (las_p)l, 16, 0, 0);
    }
}

// ---------------- tables ----------------
__global__ void k_tab(const float* __restrict__ logdt, const float* __restrict__ Are,
                      const float* __restrict__ Aim, const float* __restrict__ Cre,
                      const float* __restrict__ Cim, float2* __restrict__ wtab,
                      float2* __restrict__ wptab, float2* __restrict__ ceff) {
    int idx = blockIdx.x * blockDim.x + threadIdx.x;
    if (idx >= Hdim * NM) return;
    int h = idx >> 5;
    float dt = expf(logdt[h]);
    double dar = (double)dt * (double)Are[idx];
    double dai = (double)dt * (double)Aim[idx];
    double wm = exp(dar);
    double wr = wm * cos(dai), wi = wm * sin(dai);
    wtab[idx] = make_float2((float)wr, (float)wi);
    double pm = exp(dar * (double)PCH);
    double pai = dai * (double)PCH;
    wptab[idx] = make_float2((float)(pm * cos(pai)), (float)(pm * sin(pai)));
    double are = (double)Are[idx], aim = (double)Aim[idx];
    double den = are * are + aim * aim;
    double nr = wr - 1.0, ni = wi;
    double qr = (nr * are + ni * aim) / den;
    double qi = (ni * are - nr * aim) / den;
    for (int ch = 0; ch < 2; ch++) {
        double cr = (double)Cre[ch * Hdim * NM + idx];
        double ci = (double)Cim[ch * Hdim * NM + idx];
        ceff[ch * Hdim * NM + idx] = make_float2((float)(cr * qr - ci * qi),
                                                 (float)(cr * qi + ci * qr));
    }
}

// ---------------- weight transpose + bf16 cast ----------------
__global__ void k_wt(const float* __restrict__ W1, const float* __restrict__ W2,
                     const float* __restrict__ W3, unsigned short* __restrict__ W1T,
                     unsigned short* __restrict__ W2T, unsigned short* __restrict__ W3T) {
    int t = blockIdx.x * 256 + threadIdx.x;  // 131072 threads
    int k = t >> 9, n = t & 511;             // W1,W2: [256][512]
    W1T[n * 256 + k] = f2bf(W1[t]);
    W2T[n * 256 + k] = f2bf(W2[t]);
    int k3 = t >> 8, n3 = t & 255;           // W3: [512][256]
    W3T[n3 * 512 + k3] = f2bf(W3[t]);
}

// ---------------- table builder: Q tiles + Wp slices (parts 0-3), Kcat (part 4) ----------------
__global__ __launch_bounds__(256) void k_abw(const float* __restrict__ logdt,
                                             const float* __restrict__ Are,
                                             const float* __restrict__ Aim,
                                             const float2* __restrict__ CE,
                                             unsigned short* __restrict__ Q,
                                             unsigned short* __restrict__ Wp,
                                             float* __restrict__ Kcat) {
    __shared__ float2 wpow[32][258];   // w^j, j=0..256 (padded row)
    __shared__ float2 ce_s[64];        // [0..31] fwd, [32..63] bwd
    int h = blockIdx.x;
    int part = blockIdx.y;             // 0..3: Q tile + Wp slice ; 4: Kcat
    int t = threadIdx.x;
    if (t < 64) ce_s[t] = CE[(t >> 5) * (Hdim * NM) + h * NM + (t & 31)];
    {   // build wpow: thread = n*8+seg; j = seg + 8q, stepping by w^8
        int n = t >> 3, seg = t & 7;
        float dt = expf(logdt[h]);
        float dar = dt * Are[h * NM + n], dai = dt * Aim[h * NM + n];
        float em = expf(dar);
        float wr = em * cosf(dai), wi = em * sinf(dai);
        float ar = wr, ai = wi;
#pragma unroll
        for (int s = 0; s < 3; s++) { float nr = ar * ar - ai * ai, ni = 2.f * ar * ai; ar = nr; ai = ni; }
        float m = expf((float)seg * dar), ang = (float)seg * dai;
        float vr = m * cosf(ang), vi = m * sinf(ang);
        for (int q = 0; q < 32; q++) {
            wpow[n][seg + 8 * q] = make_float2(vr, vi);
            float nr2 = vr * ar - vi * ai;
            float ni2 = vr * ai + vi * ar;
            vr = nr2; vi = ni2;
        }
        if (seg == 0) wpow[n][256] = make_float2(vr, vi);
    }
    __syncthreads();
    if (part == 4) {   // Kcat: kcat[255+d]=kf[d], kcat[254-m]=kb[m]
        float kfv = 0.f, kbv = 0.f;
#pragma unroll
        for (int n = 0; n < NM; n++) {
            float2 wv = wpow[n][t];
            float2 cf = ce_s[n], cb = ce_s[32 + n];
            kfv = fmaf(cf.x, wv.x, fmaf(-cf.y, wv.y, kfv));
            kbv = fmaf(cb.x, wv.x, fmaf(-cb.y, wv.y, kbv));
        }
        Kcat[(size_t)h * 512 + 255 + t] = 2.f * kfv;
        if (t < 255) Kcat[(size_t)h * 512 + 254 - t] = 2.f * kbv;
        if (t == 255) Kcat[(size_t)h * 512 + 511] = 0.f;
        return;
    }
    for (int jj = 0; jj < 32; jj++) {
        int j = part * 64 + jj * 2 + (t >> 7);
        int tq = t & 127;
        int n = (tq & 63) >> 1, reim = tq & 1;
        float2 c = (tq < 64) ? ce_s[n] : ce_s[32 + n];
        float2 wv = (tq < 64) ? wpow[n][j + 1] : wpow[n][255 - j];
        float re = c.x * wv.x - c.y * wv.y;
        float im = c.x * wv.y + c.y * wv.x;
        Q[((size_t)h * 256 + j) * 128 + tq] = f2bf(reim ? -2.f * im : 2.f * re);
    }
    for (int rr = 0; rr < 32; rr++) {
        int r = part * 32 + rr;
        int n = (r & 63) >> 1, reim = r & 1, dir = r >> 6;
        float2 wv = wpow[n][dir ? t : 255 - t];
        Wp[((size_t)h * 128 + r) * 256 + t] = f2bf(reim ? wv.y : wv.x);
    }
}

// ---------------- fused layernorm + transpose: x (b,l,h) fp32 -> UT (b,h,l) bf16 ----------------
__global__ __launch_bounds__(256) void k_lntr(const float* __restrict__ x,
                                              const float* __restrict__ g,
                                              const float* __restrict__ bt,
                                              unsigned short* __restrict__ UT) {
    __shared__ unsigned short lds[256][65];
    int lt = blockIdx.x, b = blockIdx.y;
    int t = threadIdx.x;
    int lane = t & 63, w = t >> 6;
    float4 gg = ((const float4*)g)[lane];
    float4 bb = ((const float4*)bt)[lane];
#pragma unroll
    for (int q = 0; q < 16; q++) {
        int l = q * 4 + w;
        float4 v = ((const float4*)(x + ((size_t)(b * LL + lt * 64 + l)) * Hdim))[lane];
        float s = v.x + v.y + v.z + v.w;
        float ss = v.x * v.x + v.y * v.y + v.z * v.z + v.w * v.w;
#pragma unroll
        for (int o = 1; o < 64; o <<= 1) { s += __shfl_xor(s, o, 64); ss += __shfl_xor(ss, o, 64); }
        float mean = s * (1.0f / Hdim);
        float var = ss * (1.0f / Hdim) - mean * mean;
        float rstd = rsqrtf(var + 1e-5f);
        lds[lane * 4 + 0][l] = f2bf((v.x - mean) * rstd * gg.x + bb.x);
        lds[lane * 4 + 1][l] = f2bf((v.y - mean) * rstd * gg.y + bb.y);
        lds[lane * 4 + 2][l] = f2bf((v.z - mean) * rstd * gg.z + bb.z);
        lds[lane * 4 + 3][l] = f2bf((v.w - mean) * rstd * gg.w + bb.w);
    }
    __syncthreads();
    for (int q = 0; q < 64; q++) {
        int idx = q * 256 + t;
        int hh = idx >> 6, ll = idx & 63;
        UT[((size_t)(b * Hdim + hh)) * LL + lt * 64 + ll] = lds[hh][ll];
    }
}

// ---------------- layernorm (bf16 in, bf16 out): T2 = LN(X2) ----------------
__global__ void k_ln_bf(const unsigned short* __restrict__ x, const float* __restrict__ g,
                        const float* __restrict__ bt, unsigned short* __restrict__ out) {
    int row = blockIdx.x * 4 + (threadIdx.x >> 6);
    int lane = threadIdx.x & 63;
    ushort4 u4 = ((const ushort4*)(x + (size_t)row * Hdim))[lane];
    float vx = bf2f(u4.x), vy = bf2f(u4.y), vz = bf2f(u4.z), vw = bf2f(u4.w);
    float s = vx + vy + vz + vw;
    float ss = vx * vx + vy * vy + vz * vz + vw * vw;
#pragma unroll
    for (int o = 1; o < 64; o <<= 1) { s += __shfl_xor(s, o, 64); ss += __shfl_xor(ss, o, 64); }
    float mean = s * (1.0f / Hdim);
    float var = ss * (1.0f / Hdim) - mean * mean;
    float rstd = rsqrtf(var + 1e-5f);
    float4 gg = ((const float4*)g)[lane];
    float4 bb = ((const float4*)bt)[lane];
    ushort4 o;
    o.x = f2bf((vx - mean) * rstd * gg.x + bb.x);
    o.y = f2bf((vy - mean) * rstd * gg.y + bb.y);
    o.z = f2bf((vz - mean) * rstd * gg.z + bb.z);
    o.w = f2bf((vw - mean) * rstd * gg.w + bb.w);
    ((ushort4*)(out + (size_t)row * Hdim))[lane] = o;
}

// ---------------- state GEMM: Zg[h][bc][r] bf16, 256x128 per h ----------------
__global__ __launch_bounds__(512) void k_zgemm(const unsigned short* __restrict__ UT,
                                               const unsigned short* __restrict__ Wp,
                                               unsigned short* __restrict__ Zg) {
    __shared__ unsigned short As[256 * 64];
    __shared__ unsigned short Bs[128 * 64];
    int h = blockIdx.x;
    int t = threadIdx.x;
    int w = t >> 6, lane = t & 63;
    int m0 = (w & 3) * 64;     // 4 row groups
    int nb = (w >> 2) * 64;    // 2 col groups
    int lr = lane & 15, lk = (lane >> 4) * 8;
    f32x4 acc[4][4];
#pragma unroll
    for (int i = 0; i < 4; i++)
#pragma unroll
        for (int jx = 0; jx < 4; jx++) acc[i][jx] = (f32x4){0.f, 0.f, 0.f, 0.f};
    for (int k0 = 0; k0 < 256; k0 += 64) {
        stageUT<256, 512>(UT, h, 0, k0, As, t);
        stage64<128, 512>(Wp + (size_t)h * 128 * 256, 256, k0, Bs, t);
        __syncthreads();
#pragma unroll
        for (int kk = 0; kk < 64; kk += 32) {
            bf16x8 a[4], b[4];
#pragma unroll
            for (int mi = 0; mi < 4; mi++) a[mi] = fr(As, m0 + mi * 16 + lr, kk + lk);
#pragma unroll
            for (int nf = 0; nf < 4; nf++) b[nf] = fr(Bs, nb + nf * 16 + lr, kk + lk);
#pragma unroll
            for (int mi = 0; mi < 4; mi++)
#pragma unroll
                for (int nf = 0; nf < 4; nf++)
                    acc[mi][nf] = __builtin_amdgcn_mfma_f32_16x16x32_bf16(a[mi], b[nf], acc[mi][nf], 0, 0, 0);
        }
        __syncthreads();
    }
#pragma unroll
    for (int mi = 0; mi < 4; mi++)
#pragma unroll
        for (int nf = 0; nf < 4; nf++) {
            int col = nb + nf * 16 + lr;
#pragma unroll
            for (int r = 0; r < 4; r++) {
                int row = m0 + mi * 16 + (lane >> 4) * 4 + r;
                Zg[((size_t)h * 256 + row) * 128 + col] = f2bf(acc[mi][nf][r]);
            }
        }
}

// ---------------- prefix over chunks (bf16 Zg) -> Zpacked bf16 [h][bc][128] ----------------
__global__ void k_prefix2(const unsigned short* __restrict__ Zg, const float2* __restrict__ wptab,
                          unsigned short* __restrict__ ZP) {
    int t = blockIdx.x * 256 + threadIdx.x;
    int n = t & 31;
    int h = (t >> 5) & 255;
    int b = (t >> 13) & 15;
    int dir = (t >> 17) & 1;
    float2 wp = wptab[h * NM + n];
    float sr = 0.f, si = 0.f;
    int ro = dir ? 64 + 2 * n : 2 * n;
    if (dir == 0) {
        for (int c = 0; c < NCH; c++) {
            size_t base = ((size_t)h * 256 + b * NCH + c) * 128;
            ZP[base + ro] = f2bf(sr);
            ZP[base + ro + 1] = f2bf(si);
            float zr = bf2f(Zg[base + ro]), zi = bf2f(Zg[base + ro + 1]);
            float nr = fmaf(wp.x, sr, fmaf(-wp.y, si, zr));
            float ni = fmaf(wp.y, sr, fmaf(wp.x, si, zi));
            sr = nr; si = ni;
        }
    } else {
        for (int c = NCH - 1; c >= 0; c--) {
            size_t base = ((size_t)h * 256 + b * NCH + c) * 128;
            ZP[base + ro] = f2bf(sr);
            ZP[base + ro + 1] = f2bf(si);
            float zr = bf2f(Zg[base + ro]), zi = bf2f(Zg[base + ro + 1]);
            float nr = fmaf(wp.x, sr, fmaf(-wp.y, si, zr));
            float ni = fmaf(wp.y, sr, fmaf(wp.x, si, zi));
            sr = nr; si = ni;
        }
    }
}

// ---------------- conv GEMM: u-part B-tiles built in-LDS from Kcat; z-part staged from Q ----------------
__global__ __launch_bounds__(512) void k_conv(const unsigned short* __restrict__ UT,
                                              const unsigned short* __restrict__ ZP,
                                              const unsigned short* __restrict__ Q,
                                              const float* __restrict__ Kcat,
                                              const float* __restrict__ Dsk,
                                              unsigned short* __restrict__ Yt) {
    __shared__ unsigned short As[128 * 64];
    __shared__ unsigned short Bs[256 * 64];
    __shared__ float kcs[512];
    int wgid = ((int)blockIdx.x % 8) * 64 + (int)blockIdx.x / 8;
    int h = wgid >> 1;
    int mbase = (wgid & 1) * 128;
    int t = threadIdx.x;
    int w = t >> 6, lane = t & 63;
    int m0 = (w & 1) * 64;
    int nb = (w >> 1) * 64;
    int lr = lane & 15, lk = (lane >> 4) * 8;
    float dsk = Dsk[h];
    kcs[t] = Kcat[(size_t)h * 512 + t];
    __syncthreads();
    f32x4 acc[4][4];
#pragma unroll
    for (int i = 0; i < 4; i++)
#pragma unroll
        for (int jx = 0; jx < 4; jx++) acc[i][jx] = (f32x4){0.f, 0.f, 0.f, 0.f};
    for (int k0 = 0; k0 < 256; k0 += 64) {
        stageUT<128, 512>(UT, h, mbase, k0, As, t);
#pragma unroll
        for (int gq = 0; gq < 4; gq++) {
            int e = gq * 4096 + t * 8;
            int j = e >> 6;
            int i0 = k0 + (e & 63);
            union { bf16x8 v; unsigned short u[8]; } pk;
#pragma unroll
            for (int q = 0; q < 8; q++) {
                int i = i0 + q;
                float f = kcs[255 + j - i];
                if (i == j) f += dsk;
                pk.u[q] = f2bf(f);
            }
            *(bf16x8*)(Bs + j * 64 + (((((e & 63) >> 3)) ^ (j & 7)) << 3)) = pk.v;
        }
        __syncthreads();
#pragma unroll
        for (int kk = 0; kk < 64; kk += 32) {
            bf16x8 a[4], b[4];
#pragma unroll
            for (int mi = 0; mi < 4; mi++) a[mi] = fr(As, m0 + mi * 16 + lr, kk + lk);
#pragma unroll
            for (int nf = 0; nf < 4; nf++) b[nf] = fr(Bs, nb + nf * 16 + lr, kk + lk);
#pragma unroll
            for (int mi = 0; mi < 4; mi++)
#pragma unroll
                for (int nf = 0; nf < 4; nf++)
                    acc[mi][nf] = __builtin_amdgcn_mfma_f32_16x16x32_bf16(a[mi], b[nf], acc[mi][nf], 0, 0, 0);
        }
        __syncthreads();
    }
    for (int k0 = 0; k0 < 128; k0 += 64) {
        stage64<128, 512>(ZP + ((size_t)h * 256 + mbase) * 128, 128, k0, As, t);
        stage64<256, 512>(Q + (size_t)h * 256 * 128, 128, k0, Bs, t);
        __syncthreads();
#pragma unroll
        for (int kk = 0; kk < 64; kk += 32) {
            bf16x8 a[4], b[4];
#pragma unroll
            for (int mi = 0; mi < 4; mi++) a[mi] = fr(As, m0 + mi * 16 + lr, kk + lk);
#pragma unroll
            for (int nf = 0; nf < 4; nf++) b[nf] = fr(Bs, nb + nf * 16 + lr, kk + lk);
#pragma unroll
            for (int mi = 0; mi < 4; mi++)
#pragma unroll
                for (int nf = 0; nf < 4; nf++)
                    acc[mi][nf] = __builtin_amdgcn_mfma_f32_16x16x32_bf16(a[mi], b[nf], acc[mi][nf], 0, 0, 0);
        }
        __syncthreads();
    }
#pragma unroll
    for (int mi = 0; mi < 4; mi++)
#pragma unroll
        for (int nf = 0; nf < 4; nf++) {
            int col = nb + nf * 16 + lr;
#pragma unroll
            for (int r = 0; r < 4; r++) {
                int row = mbase + m0 + mi * 16 + (lane >> 4) * 4 + r;
                Yt[(size_t)h * 65536 + row * 256 + col] = f2bf(gelu_f(acc[mi][nf][r]));
            }
        }
}

// ---------------- transpose Yt [h][bc][j] -> G (b, c*P+j, h) bf16 ----------------
__global__ void k_trg(const unsigned short* __restrict__ Yt, unsigned short* __restrict__ G) {
    __shared__ unsigned short lds[64][65];
    int bc = blockIdx.x;
    int h0 = blockIdx.y * 64, j0 = blockIdx.z * 64;
    int t = threadIdx.x;
#pragma unroll
    for (int q = 0; q < 16; q++) {
        int idx = q * 256 + t;
        int hh = idx >> 6, jj = idx & 63;
        lds[hh][jj] = Yt[(size_t)(h0 + hh) * 65536 + bc * 256 + j0 + jj];
    }
    __syncthreads();
    int b = bc >> 4, c = bc & 15;
#pragma unroll
    for (int q = 0; q < 16; q++) {
        int idx = q * 256 + t;
        int jj = idx >> 6, hh = idx & 63;
        G[((size_t)(b * LL + c * PCH + j0 + jj)) * Hdim + h0 + hh] = lds[hh][jj];
    }
}

// ---------------- GEMM1 (1024 thr, full 256 pairs/block): X2 = bf16(x + glu(G@Wout + bo)) ----------------
__global__ __launch_bounds__(1024) void k_gemm1(const unsigned short* __restrict__ Gm,
                                                const unsigned short* __restrict__ W1T,
                                                const float* __restrict__ bo,
                                                const float* __restrict__ xin,
                                                unsigned short* __restrict__ X2) {
    __shared__ unsigned short As[128 * 64];
    __shared__ unsigned short BsA[256 * 64];
    __shared__ unsigned short BsB[256 * 64];
    int t = threadIdx.x;
    int w = t >> 6, lane = t & 63;
    int m0w = (w & 1) * 64;          // 2 row halves
    int n0w = (w >> 1) * 32;         // 8 pair-groups of 32 pairs (full 256)
    int lr = lane & 15, lk = (lane >> 4) * 8;
    int mblk = blockIdx.x * 128;
    const unsigned short* Ab  = Gm + (size_t)mblk * 256;
    f32x4 acc[4][4];
#pragma unroll
    for (int i = 0; i < 4; i++)
#pragma unroll
        for (int j = 0; j < 4; j++) acc[i][j] = (f32x4){0.f, 0.f, 0.f, 0.f};
    for (int k0 = 0; k0 < 256; k0 += 64) {
        stage64<128, 1024>(Ab, 256, k0, As, t);
        stage64<256, 1024>(W1T, 256, k0, BsA, t);
        stage64<256, 1024>(W1T + (size_t)256 * 256, 256, k0, BsB, t);
        __syncthreads();
#pragma unroll
        for (int kk = 0; kk < 64; kk += 32) {
            bf16x8 a[4], bA[2], bB[2];
#pragma unroll
            for (int mi = 0; mi < 4; mi++)
                a[mi] = fr(As, m0w + mi * 16 + lr, kk + lk);
#pragma unroll
            for (int nf = 0; nf < 2; nf++) {
                bA[nf] = fr(BsA, n0w + nf * 16 + lr, kk + lk);
                bB[nf] = fr(BsB, n0w + nf * 16 + lr, kk + lk);
            }
#pragma unroll
            for (int mi = 0; mi < 4; mi++)
#pragma unroll
                for (int nf = 0; nf < 2; nf++) {
                    acc[mi][nf] = __builtin_amdgcn_mfma_f32_16x16x32_bf16(a[mi], bA[nf], acc[mi][nf], 0, 0, 0);
                    acc[mi][nf + 2] = __builtin_amdgcn_mfma_f32_16x16x32_bf16(a[mi], bB[nf], acc[mi][nf + 2], 0, 0, 0);
                }
        }
        __syncthreads();
    }
#pragma unroll
    for (int mi = 0; mi < 4; mi++)
#pragma unroll
        for (int nf = 0; nf < 2; nf++) {
            int col = n0w + nf * 16 + lr;
            float biasA = bo[col], biasB = bo[col + 256];
#pragma unroll
            for (int r = 0; r < 4; r++) {
                int row = mblk + m0w + mi * 16 + (lane >> 4) * 4 + r;
                float zzA = acc[mi][nf][r] + biasA;
                float zzB = acc[mi][nf + 2][r] + biasB;
                float v = zzA * __builtin_amdgcn_rcpf(1.0f + __expf(-zzB));
                size_t idx = (size_t)row * 256 + col;
                X2[idx] = f2bf(xin[idx] + v);
            }
        }
}

// ---------------- GEMM2 (1024 thr, full 512 cols/block): M = gelu(T2@W2 + b2) bf16 ----------------
__global__ __launch_bounds__(1024) void k_gemm2(const unsigned short* __restrict__ T2,
                                                const unsigned short* __restrict__ W2T,
                                                const float* __restrict__ b2,
                                                unsigned short* __restrict__ Mo) {
    __shared__ unsigned short As[128 * 64];
    __shared__ unsigned short Bs[512 * 64];
    int t = threadIdx.x;
    int w = t >> 6, lane = t & 63;
    int m0w = (w & 1) * 64;          // 2 row halves
    int n0w = (w >> 1) * 64;         // 8 col groups of 64 (full 512)
    int lr = lane & 15, lk = (lane >> 4) * 8;
    int mblk = blockIdx.x * 128;
    const unsigned short* Ab = T2 + (size_t)mblk * 256;
    f32x4 acc[4][4];
#pragma unroll
    for (int i = 0; i < 4; i++)
#pragma unroll
        for (int j = 0; j < 4; j++) acc[i][j] = (f32x4){0.f, 0.f, 0.f, 0.f};
    for (int k0 = 0; k0 < 256; k0 += 64) {
        stage64<128, 1024>(Ab, 256, k0, As, t);
        stage64<512, 1024>(W2T, 256, k0, Bs, t);
        __syncthreads();
#pragma unroll
        for (int kk = 0; kk < 64; kk += 32) {
            bf16x8 a[4], b[4];
#pragma unroll
            for (int mi = 0; mi < 4; mi++)
                a[mi] = fr(As, m0w + mi * 16 + lr, kk + lk);
#pragma unroll
            for (int nf = 0; nf < 4; nf++)
                b[nf] = fr(Bs, n0w + nf * 16 + lr, kk + lk);
#pragma unroll
            for (int mi = 0; mi < 4; mi++)
#pragma unroll
                for (int nf = 0; nf < 4; nf++)
                    acc[mi][nf] = __builtin_amdgcn_mfma_f32_16x16x32_bf16(a[mi], b[nf], acc[mi][nf], 0, 0, 0);
        }
        __syncthreads();
    }
#pragma unroll
    for (int mi = 0; mi < 4; mi++)
#pragma unroll
        for (int nf = 0; nf < 4; nf++) {
            int col = n0w + nf * 16 + lr;
            float bias = b2[col];
#pragma unroll
            for (int r = 0; r < 4; r++) {
                int row = mblk + m0w + mi * 16 + (lane >> 4) * 4 + r;
                Mo[(size_t)row * 512 + col] = f2bf(gelu_f(acc[mi][nf][r] + bias));
            }
        }
}

// ---------------- GEMM3 (1024 thr, full 256 cols): out = X2 + M@W3 + b3 ----------------
__global__ __launch_bounds__(1024) void k_gemm3(const unsigned short* __restrict__ Mb,
                                                const unsigned short* __restrict__ W3T,
                                                const float* __restrict__ b3,
                                                const unsigned short* __restrict__ X2,
                                                float* __restrict__ out) {
    __shared__ unsigned short As[128 * 64];
    __shared__ unsigned short Bs[256 * 64];
    int t = threadIdx.x;
    int w = t >> 6, lane = t & 63;
    int m0w = (w & 1) * 64;          // 2 row halves
    int n0w = (w >> 1) * 32;         // 8 col groups of 32 (full 256)
    int lr = lane & 15, lk = (lane >> 4) * 8;
    int mblk = blockIdx.x * 128;
    const unsigned short* Ab = Mb + (size_t)mblk * 512;
    f32x4 acc[4][2];
#pragma unroll
    for (int i = 0; i < 4; i++) { acc[i][0] = (f32x4){0.f,0.f,0.f,0.f}; acc[i][1] = (f32x4){0.f,0.f,0.f,0.f}; }
    for (int k0 = 0; k0 < 512; k0 += 64) {
        stage64<128, 1024>(Ab, 512, k0, As, t);
        stage64<256, 1024>(W3T, 512, k0, Bs, t);
        __syncthreads();
#pragma unroll
        for (int kk = 0; kk < 64; kk += 32) {
            bf16x8 a[4], b[2];
#pragma unroll
            for (int mi = 0; mi < 4; mi++)
                a[mi] = fr(As, m0w + mi * 16 + lr, kk + lk);
#pragma unroll
            for (int nf = 0; nf < 2; nf++)
                b[nf] = fr(Bs, n0w + nf * 16 + lr, kk + lk);
#pragma unroll
            for (int mi = 0; mi < 4; mi++)
#pragma unroll
                for (int nf = 0; nf < 2; nf++)
                    acc[mi][nf] = __builtin_amdgcn_mfma_f32_16x16x32_bf16(a[mi], b[nf], acc[mi][nf], 0, 0, 0);
        }
        __syncthreads();
    }
#pragma unroll
    for (int mi = 0; mi < 4; mi++)
#pragma unroll
        for (int nf = 0; nf < 2; nf++) {
            int col = n0w + nf * 16 + lr;
            float bias = b3[col];
#pragma unroll
            for (int r = 0; r < 4; r++) {
                int row = mblk + m0w + mi * 16 + (lane >> 4) * 4 + r;
                size_t idx = (size_t)row * 256 + col;
                out[idx] = bf2f(X2[idx]) + acc[mi][nf][r] + bias;
            }
        }
}

extern "C" void kernel_launch(void* const* d_in, const int* in_sizes, int n_in,
                              void* d_out, int out_size, void* d_ws, size_t ws_size,
                              hipStream_t stream) {
    const float* x     = (const float*)d_in[0];
    const float* ln1g  = (const float*)d_in[1];
    const float* ln1b  = (const float*)d_in[2];
    const float* ln2g  = (const float*)d_in[3];
    const float* ln2b  = (const float*)d_in[4];
    const float* logdt = (const float*)d_in[5];
    const float* Are   = (const float*)d_in[6];
    const float* Aim   = (const float*)d_in[7];
    const float* Cre   = (const float*)d_in[8];
    const float* Cim   = (const float*)d_in[9];
    const float* Dsk   = (const float*)d_in[10];
    const float* Wout  = (const float*)d_in[11];
    const float* bo    = (const float*)d_in[12];
    const float* W2    = (const float*)d_in[13];
    const float* b2    = (const float*)d_in[14];
    const float* W3    = (const float*)d_in[15];
    const float* b3    = (const float*)d_in[16];

    char* ws = (char*)d_ws;
    unsigned short* Q    = (unsigned short*)(ws + OFF_Q);
    float*          Kc   = (float*)(ws + OFF_KC);
    unsigned short* Wp   = (unsigned short*)(ws + OFF_WPM);
    unsigned short* X2   = (unsigned short*)(ws + OFF_Q);      // bf16, after Q/Kcat dead
    unsigned short* UT   = (unsigned short*)(ws + OFF_UT);
    unsigned short* Zg   = (unsigned short*)(ws + OFF_ZG);     // bf16
    unsigned short* Yt   = (unsigned short*)(ws + OFF_ZG);
    unsigned short* Mb   = (unsigned short*)(ws + OFF_M);
    unsigned short* ZP   = (unsigned short*)(ws + OFF_ZP);
    unsigned short* G    = (unsigned short*)(ws + OFF_G);
    float2*         WT   = (float2*)(ws + OFF_WTAB);
    float2*         WPT  = (float2*)(ws + OFF_WPT);
    float2*         CE   = (float2*)(ws + OFF_CE);
    unsigned short* W1T  = (unsigned short*)(ws + OFF_W1T);
    unsigned short* W2T  = (unsigned short*)(ws + OFF_W2T);
    unsigned short* W3T  = (unsigned short*)(ws + OFF_W3T);

    k_tab<<<32, 256, 0, stream>>>(logdt, Are, Aim, Cre, Cim, WT, WPT, CE);
    k_wt<<<512, 256, 0, stream>>>(Wout, W2, W3, W1T, W2T, W3T);
    k_lntr<<<dim3(64, 16), 256, 0, stream>>>(x, ln1g, ln1b, UT);
    k_abw<<<dim3(256, 5), 256, 0, stream>>>(logdt, Are, Aim, CE, Q, Wp, Kc);
    k_zgemm<<<256, 512, 0, stream>>>(UT, Wp, Zg);
    k_prefix2<<<1024, 256, 0, stream>>>(Zg, WPT, ZP);
    k_conv<<<512, 512, 0, stream>>>(UT, ZP, Q, Kc, Dsk, Yt);
    k_trg<<<dim3(256, 4, 4), 256, 0, stream>>>(Yt, G);
    k_gemm1<<<512, 1024, 0, stream>>>(G, W1T, bo, x, X2);
    k_ln_bf<<<NB * LL / 4, 256, 0, stream>>>(X2, ln2g, ln2b, G);
    k_gemm2<<<512, 1024, 0, stream>>>(G, W2T, b2, Mb);
    k_gemm3<<<512, 1024, 0, stream>>>(Mb, W3T, b3, X2, (float*)d_out);
}